// Round 2
// baseline (3381.670 us; speedup 1.0000x reference)
//
#include <hip/hip_runtime.h>
#include <hip/hip_bf16.h>

typedef __hip_bfloat16 bf16;

#define HD 16
#define TK 128

__device__ __forceinline__ float b2f(bf16 v){ return __bfloat162float(v); }
__device__ __forceinline__ float gelu_f(float x){ return 0.5f*x*(1.0f+erff(x*0.70710678118654752f)); }
// read scalar from either bf16 or fp32 array depending on flag
__device__ __forceinline__ float rdv(const void* p, size_t i, bool bf){
  return bf ? b2f(((const bf16*)p)[i]) : ((const float*)p)[i];
}

// ---------------- dtype detector: writes 1.0 if inputs are bf16, else 0.0 ----------------
__global__ void detect_k(const void* __restrict__ x, float* __restrict__ flag){
  if (threadIdx.x == 0 && blockIdx.x == 0){
    const float* xf = (const float*)x;
    const bf16*  xb = (const bf16*)x;
    double sF = 0.0, sB = 0.0;
    for (int i = 0; i < 512; i++){ float v = fabsf(xf[i]);     if (!(v < 1e30f)) v = 1e30f; sF += v; }
    for (int i = 0; i < 1024; i++){ float v = fabsf(b2f(xb[i])); if (!(v < 1e30f)) v = 1e30f; sB += v; }
    float mF = (float)(sF/512.0), mB = (float)(sB/1024.0);
    float dF = fabsf(logf(fmaxf(mF, 1e-30f)));
    float dB = fabsf(logf(fmaxf(mB, 1e-30f)));
    *flag = (dB <= dF) ? 1.0f : 0.0f;
  }
}

// ---------------- input -> fp32 convert ----------------
__global__ void cvt_k(const void* __restrict__ in, float* __restrict__ out, int n,
                      const float* __restrict__ flagp){
  bool bf = *flagp > 0.5f;
  int i = blockIdx.x*blockDim.x + threadIdx.x;
  if (i < n) out[i] = rdv(in, i, bf);
}

// ---------------- LayerNorm over channel dim, per pixel ----------------
__global__ void ln2d_k(const float* __restrict__ x, const void* __restrict__ g,
                       const void* __restrict__ b, float* __restrict__ y,
                       int C, int HW, const float* __restrict__ flagp){
  bool bf = *flagp > 0.5f;
  int p  = blockIdx.x*blockDim.x + threadIdx.x;
  int bb = blockIdx.y;
  if (p >= HW) return;
  const float* xb = x + (size_t)bb*C*HW + p;
  float s = 0.f, s2 = 0.f;
  for (int c = 0; c < C; c++){ float v = xb[(size_t)c*HW]; s += v; s2 += v*v; }
  float mu  = s  / (float)C;
  float var = fmaxf(s2 / (float)C - mu*mu, 0.f);
  float inv = rsqrtf(var + 1e-5f);
  float* yb = y + (size_t)bb*C*HW + p;
  for (int c = 0; c < C; c++){
    yb[(size_t)c*HW] = (xb[(size_t)c*HW] - mu)*inv*rdv(g,c,bf) + rdv(b,c,bf);
  }
}

// ---------------- generic 1x1 conv (channel-mixing) ----------------
// out[b,o,p] = act( bias[o] + sum_c w[o,c]*in1[b,c,p] + sum_c w[o,C1+c]*in2[b,c,p] ) + res[b,o,p]
// to_out: 0 => out is float*; 1 => out dtype follows flag (bf16 or fp32)
__global__ void conv1x1_k(const float* __restrict__ in1, long in1_bs, int C1,
                          const float* __restrict__ in2, long in2_bs, int C2,
                          const void* __restrict__ w, const void* __restrict__ bias,
                          const float* __restrict__ res,
                          void* __restrict__ out, int to_out, int O, int NP, int act,
                          const float* __restrict__ flagp){
  bool bf = *flagp > 0.5f;
  int p = blockIdx.x*blockDim.x + threadIdx.x;
  if (p >= NP) return;
  int o = blockIdx.y, bb = blockIdx.z;
  size_t wrow = (size_t)o*(C1 + C2);
  float acc = bias ? rdv(bias, o, bf) : 0.f;
  const float* i1 = in1 + (size_t)bb*in1_bs + p;
  for (int c = 0; c < C1; c++) acc += rdv(w, wrow + c, bf) * i1[(size_t)c*NP];
  if (in2){
    const float* i2 = in2 + (size_t)bb*in2_bs + p;
    for (int c = 0; c < C2; c++) acc += rdv(w, wrow + C1 + c, bf) * i2[(size_t)c*NP];
  }
  if (act == 1) acc = gelu_f(acc);
  if (res) acc += res[((size_t)bb*O + o)*NP + p];
  size_t oi = ((size_t)bb*O + o)*NP + p;
  if (to_out){
    if (bf) ((bf16*)out)[oi] = __float2bfloat16(acc);
    else    ((float*)out)[oi] = acc;
  } else {
    ((float*)out)[oi] = acc;
  }
}

// ---------------- cosine attention, flash-style online softmax ----------------
// Q: (B,CQ,NQ) fp32, q chan for head h dim d = qoff+h*16+d
// KV: (B,CKV,NK) fp32, k chan = koff+h*16+d, v chan = voff+h*16+d
// Out: (B,C,NQ) fp32 chan h*16+d. logits = (q/|q|)(k/|k|)*scale
__global__ void cosattn_k(const float* __restrict__ Q, long qbs, int qoff,
                          const float* __restrict__ KV, long kbs, int koff, int voff,
                          float* __restrict__ Out, long obs,
                          int NQ, int NK, float scale){
  __shared__ float Ks[HD*TK];
  __shared__ float Vs[HD*TK];
  __shared__ float KnI[TK];
  int tid = threadIdx.x;
  int h  = blockIdx.y, bb = blockIdx.z;
  int qi = blockIdx.x*blockDim.x + tid;
  bool qv = qi < NQ;
  float qn[HD], acc[HD];
  float m = -INFINITY, l = 0.f;
  if (qv){
    float s = 0.f;
    #pragma unroll
    for (int d = 0; d < HD; d++){
      qn[d] = Q[(size_t)bb*qbs + (size_t)(qoff + h*HD + d)*NQ + qi];
      s += qn[d]*qn[d];
    }
    float inv = scale / fmaxf(sqrtf(s), 1e-12f);
    #pragma unroll
    for (int d = 0; d < HD; d++){ qn[d] *= inv; acc[d] = 0.f; }
  }
  for (int k0 = 0; k0 < NK; k0 += TK){
    int lim = min(TK, NK - k0);
    for (int i = tid; i < HD*TK; i += blockDim.x){
      int pos = i % TK, d = i / TK;
      if (pos < lim){
        Ks[d*TK + pos] = KV[(size_t)bb*kbs + (size_t)(koff + h*HD + d)*NK + k0 + pos];
        Vs[d*TK + pos] = KV[(size_t)bb*kbs + (size_t)(voff + h*HD + d)*NK + k0 + pos];
      }
    }
    __syncthreads();
    if (tid < lim){
      float s = 0.f;
      #pragma unroll
      for (int d = 0; d < HD; d++){ float v = Ks[d*TK + tid]; s += v*v; }
      KnI[tid] = 1.f / fmaxf(sqrtf(s), 1e-12f);
    }
    __syncthreads();
    if (qv){
      for (int pos = 0; pos < lim; pos++){
        float dot = 0.f;
        #pragma unroll
        for (int d = 0; d < HD; d++) dot += qn[d]*Ks[d*TK + pos];
        float logit = dot * KnI[pos];
        float mn = fmaxf(m, logit);
        float r  = __expf(m - mn);       // exp(-inf)=0 handles first iter
        float pp = __expf(logit - mn);
        l = l*r + pp;
        #pragma unroll
        for (int d = 0; d < HD; d++) acc[d] = acc[d]*r + pp*Vs[d*TK + pos];
        m = mn;
      }
    }
    __syncthreads();
  }
  if (qv){
    float li = 1.f / fmaxf(l, 1e-30f);
    #pragma unroll
    for (int d = 0; d < HD; d++)
      Out[(size_t)bb*obs + (size_t)(h*HD + d)*NQ + qi] = acc[d]*li;
  }
}

// ---------------- 4x4 mean pool: (B,C,48,48)->(B,C,12,12) ----------------
__global__ void pool4_k(const float* __restrict__ xn, float* __restrict__ xc){
  int i = blockIdx.x*blockDim.x + threadIdx.x;
  if (i >= 2*128*144) return;
  int pc = i % 144; int bc = i / 144;
  int hc = pc / 12, wc = pc % 12;
  const float* s = xn + (size_t)bc*2304 + hc*4*48 + wc*4;
  float acc = 0.f;
  #pragma unroll
  for (int r = 0; r < 4; r++)
    #pragma unroll
    for (int c2 = 0; c2 < 4; c2++) acc += s[r*48 + c2];
  xc[i] = acc * 0.0625f;
}

// ---------------- bilinear upsample 12x12 -> 48x48 (align_corners=False, edge clamp) ----------------
__global__ void ups_k(const float* __restrict__ g, float* __restrict__ out){
  int i = blockIdx.x*blockDim.x + threadIdx.x;
  if (i >= 2*128*2304) return;
  int p = i % 2304; int bc = i / 2304;
  int h = p / 48, w = p % 48;
  float sh = h*0.25f - 0.375f;
  float sw = w*0.25f - 0.375f;
  float fh0 = floorf(sh), fw0 = floorf(sw);
  float fh = sh - fh0, fw = sw - fw0;
  int h0 = (int)fh0, w0 = (int)fw0;
  int h0c = min(11, max(0, h0)),   h1c = min(11, max(0, h0+1));
  int w0c = min(11, max(0, w0)),   w1c = min(11, max(0, w0+1));
  const float* s = g + (size_t)bc*144;
  float v00 = s[h0c*12 + w0c], v01 = s[h0c*12 + w1c];
  float v10 = s[h1c*12 + w0c], v11 = s[h1c*12 + w1c];
  out[i] = (1.f-fh)*((1.f-fw)*v00 + fw*v01) + fh*((1.f-fw)*v10 + fw*v11);
}

extern "C" void kernel_launch(void* const* d_in, const int* in_sizes, int n_in,
                              void* d_out, int out_size, void* d_ws, size_t ws_size,
                              hipStream_t stream){
  const int B = 2, C = 128, HW = 2304;
  const void* x_in        = d_in[0];
  const void* g1          = d_in[1];
  const void* b1          = d_in[2];
  const void* loc_qkv_w   = d_in[3];
  const void* loc_proj_w  = d_in[4];
  const void* loc_proj_b  = d_in[5];
  const void* glob_qkv_w  = d_in[6];
  const void* glob_proj_w = d_in[7];
  const void* glob_proj_b = d_in[8];
  const void* fuse_w1     = d_in[9];
  const void* fuse_b1     = d_in[10];
  const void* fuse_w2     = d_in[11];
  const void* fuse_b2     = d_in[12];
  const void* glat        = d_in[13];
  const void* blat        = d_in[14];
  const void* latents     = d_in[15];
  const void* qlat_w      = d_in[16];
  const void* kvx_w       = d_in[17];
  const void* qx_w        = d_in[18];
  const void* kvlat_w     = d_in[19];
  const void* lat_proj_w  = d_in[20];
  const void* lat_proj_b  = d_in[21];
  const void* g2          = d_in[22];
  const void* b2          = d_in[23];
  const void* ffn_w1      = d_in[24];
  const void* ffn_b1      = d_in[25];
  const void* ffn_w2      = d_in[26];
  const void* ffn_b2      = d_in[27];

  // ---- compact aliased workspace layout (floats), total 4,128,769 < 16 MiB ----
  float* ws = (float*)d_ws;
  float* P  = ws + 0;        // persistent residual accumulator (x -> x1 -> x2)
  float* N  = ws + 589824;   // LN output / f1 / xw
  float* A  = ws + 1179648;  // att / gup / qx
  float* Q  = ws + 1769472;  // big region, 2,359,296 floats
  float* FLAG = ws + 4128768;

  // branch-1 aliases inside Q
  float* qkv   = Q;                 // 1,769,472
  float* L     = Q + 1769472;       // local, 589,824
  float* xc    = Q;                 // after qkv dead: 36,864
  float* qkvc  = Q + 36864;         // 110,592
  float* gatt  = Q + 147456;        // 36,864
  float* gproj = Q + 184320;        // 36,864
  // branch-2 aliases inside Q
  float* kvx   = Q;                 // 1,179,648
  float* latf  = Q + 1179648;       // 2,048
  float* qlat  = Q + 1181696;       // 4,096
  float* latr  = Q + 1185792;       // 4,096
  float* kvlat = Q + 1189888;       // 8,192
  // branch-3 alias
  float* ffh   = Q;                 // 2,359,296

  dim3 blk(256);

  detect_k<<<1, 64, 0, stream>>>(x_in, FLAG);
  cvt_k<<<2304, blk, 0, stream>>>(x_in, P, 589824, FLAG);

  // ---- BioAttentionFusion branch ----
  ln2d_k<<<dim3(9,B), blk, 0, stream>>>(P, g1, b1, N, C, HW, FLAG);
  conv1x1_k<<<dim3(9,384,B), blk, 0, stream>>>(N,(long)C*HW,C, nullptr,0,0, loc_qkv_w,nullptr,nullptr, qkv,0,384,HW,0, FLAG);
  cosattn_k<<<dim3(9,8,B), blk, 0, stream>>>(qkv,(long)384*HW,0, qkv,(long)384*HW,128,256, A,(long)C*HW, HW,HW,0.25f);
  conv1x1_k<<<dim3(9,128,B), blk, 0, stream>>>(A,(long)C*HW,C, nullptr,0,0, loc_proj_w,loc_proj_b,nullptr, L,0,C,HW,0, FLAG);
  pool4_k<<<144, blk, 0, stream>>>(N, xc);
  conv1x1_k<<<dim3(1,384,B), blk, 0, stream>>>(xc,(long)C*144,C, nullptr,0,0, glob_qkv_w,nullptr,nullptr, qkvc,0,384,144,0, FLAG);
  cosattn_k<<<dim3(1,8,B), blk, 0, stream>>>(qkvc,(long)384*144,0, qkvc,(long)384*144,128,256, gatt,(long)C*144, 144,144,0.25f);
  conv1x1_k<<<dim3(1,128,B), blk, 0, stream>>>(gatt,(long)C*144,C, nullptr,0,0, glob_proj_w,glob_proj_b,nullptr, gproj,0,C,144,0, FLAG);
  ups_k<<<2304, blk, 0, stream>>>(gproj, A);                                          // A = upsampled global
  conv1x1_k<<<dim3(9,128,B), blk, 0, stream>>>(L,(long)C*HW,C, A,(long)C*HW,C, fuse_w1,fuse_b1,nullptr, N,0,C,HW,1, FLAG);  // N = gelu(fuse1)
  conv1x1_k<<<dim3(9,128,B), blk, 0, stream>>>(N,(long)C*HW,C, nullptr,0,0, fuse_w2,fuse_b2,P, P,0,C,HW,0, FLAG);           // P = x + f

  // ---- LatentMixer branch ----
  ln2d_k<<<dim3(9,B), blk, 0, stream>>>(P, glat, blat, N, C, HW, FLAG);
  conv1x1_k<<<dim3(9,256,B), blk, 0, stream>>>(N,(long)C*HW,C, nullptr,0,0, kvx_w,nullptr,nullptr, kvx,0,256,HW,0, FLAG);
  conv1x1_k<<<dim3(9,128,B), blk, 0, stream>>>(N,(long)C*HW,C, nullptr,0,0, qx_w,nullptr,nullptr, A,0,C,HW,0, FLAG);        // A = qx
  cvt_k<<<8, blk, 0, stream>>>(latents, latf, 2048, FLAG);
  conv1x1_k<<<dim3(1,128,B), blk, 0, stream>>>(latf,0L,C, nullptr,0,0, qlat_w,nullptr,nullptr, qlat,0,C,16,0, FLAG);
  cosattn_k<<<dim3(1,8,B), blk, 0, stream>>>(qlat,(long)C*16,0, kvx,(long)256*HW,0,128, latr,(long)C*16, 16,HW,0.25f);
  conv1x1_k<<<dim3(1,256,B), blk, 0, stream>>>(latr,(long)C*16,C, nullptr,0,0, kvlat_w,nullptr,nullptr, kvlat,0,256,16,0, FLAG);
  cosattn_k<<<dim3(9,8,B), blk, 0, stream>>>(A,(long)C*HW,0, kvlat,(long)256*16,0,128, N,(long)C*HW, HW,16,0.25f);          // N = xw
  conv1x1_k<<<dim3(9,128,B), blk, 0, stream>>>(N,(long)C*HW,C, nullptr,0,0, lat_proj_w,lat_proj_b,P, P,0,C,HW,0, FLAG);     // P = x2

  // ---- FFN branch ----
  ln2d_k<<<dim3(9,B), blk, 0, stream>>>(P, g2, b2, N, C, HW, FLAG);
  conv1x1_k<<<dim3(9,512,B), blk, 0, stream>>>(N,(long)C*HW,C, nullptr,0,0, ffn_w1,ffn_b1,nullptr, ffh,0,512,HW,1, FLAG);
  conv1x1_k<<<dim3(9,128,B), blk, 0, stream>>>(ffh,(long)512*HW,512, nullptr,0,0, ffn_w2,ffn_b2,P, d_out,1,C,HW,0, FLAG);
}

// Round 7
// 3378.925 us; speedup vs baseline: 1.0008x; 1.0008x over previous
//
#include <hip/hip_runtime.h>
#include <hip/hip_bf16.h>

typedef __hip_bfloat16 bf16;

#define HD 16
#define TK 128

__device__ __forceinline__ float b2f(bf16 v){ return __bfloat162float(v); }
__device__ __forceinline__ float gelu_f(float x){ return 0.5f*x*(1.0f+erff(x*0.70710678118654752f)); }
// read scalar from either bf16 or fp32 array depending on flag
__device__ __forceinline__ float rdv(const void* p, size_t i, bool bf){
  return bf ? b2f(((const bf16*)p)[i]) : ((const float*)p)[i];
}

// ---------------- dtype detector: writes 1.0 if inputs are bf16, else 0.0 ----------------
__global__ void detect_k(const void* __restrict__ x, float* __restrict__ flag){
  if (threadIdx.x == 0 && blockIdx.x == 0){
    const float* xf = (const float*)x;
    const bf16*  xb = (const bf16*)x;
    double sF = 0.0, sB = 0.0;
    for (int i = 0; i < 512; i++){ float v = fabsf(xf[i]);     if (!(v < 1e30f)) v = 1e30f; sF += v; }
    for (int i = 0; i < 1024; i++){ float v = fabsf(b2f(xb[i])); if (!(v < 1e30f)) v = 1e30f; sB += v; }
    float mF = (float)(sF/512.0), mB = (float)(sB/1024.0);
    float dF = fabsf(logf(fmaxf(mF, 1e-30f)));
    float dB = fabsf(logf(fmaxf(mB, 1e-30f)));
    *flag = (dB <= dF) ? 1.0f : 0.0f;
  }
}

// ---------------- input -> fp32 convert ----------------
__global__ void cvt_k(const void* __restrict__ in, float* __restrict__ out, int n,
                      const float* __restrict__ flagp){
  bool bf = *flagp > 0.5f;
  int i = blockIdx.x*blockDim.x + threadIdx.x;
  if (i < n) out[i] = rdv(in, i, bf);
}

// ---------------- LayerNorm over channel dim, per pixel ----------------
__global__ void ln2d_k(const float* __restrict__ x, const void* __restrict__ g,
                       const void* __restrict__ b, float* __restrict__ y,
                       int C, int HW, const float* __restrict__ flagp){
  bool bf = *flagp > 0.5f;
  int p  = blockIdx.x*blockDim.x + threadIdx.x;
  int bb = blockIdx.y;
  if (p >= HW) return;
  const float* xb = x + (size_t)bb*C*HW + p;
  float s = 0.f, s2 = 0.f;
  for (int c = 0; c < C; c++){ float v = xb[(size_t)c*HW]; s += v; s2 += v*v; }
  float mu  = s  / (float)C;
  float var = fmaxf(s2 / (float)C - mu*mu, 0.f);
  float inv = rsqrtf(var + 1e-5f);
  float* yb = y + (size_t)bb*C*HW + p;
  for (int c = 0; c < C; c++){
    yb[(size_t)c*HW] = (xb[(size_t)c*HW] - mu)*inv*rdv(g,c,bf) + rdv(b,c,bf);
  }
}

// ---------------- generic 1x1 conv (channel-mixing) ----------------
// out[b,o,p] = act( bias[o] + sum_c w[o,c]*in1[b,c,p] + sum_c w[o,C1+c]*in2[b,c,p] ) + res[b,o,p]
// to_out: 0 => out is float*; 1 => out dtype follows flag (bf16 or fp32)
__global__ void conv1x1_k(const float* __restrict__ in1, long in1_bs, int C1,
                          const float* __restrict__ in2, long in2_bs, int C2,
                          const void* __restrict__ w, const void* __restrict__ bias,
                          const float* __restrict__ res,
                          void* __restrict__ out, int to_out, int O, int NP, int act,
                          const float* __restrict__ flagp){
  bool bf = *flagp > 0.5f;
  int p = blockIdx.x*blockDim.x + threadIdx.x;
  if (p >= NP) return;
  int o = blockIdx.y, bb = blockIdx.z;
  size_t wrow = (size_t)o*(C1 + C2);
  float acc = bias ? rdv(bias, o, bf) : 0.f;
  const float* i1 = in1 + (size_t)bb*in1_bs + p;
  for (int c = 0; c < C1; c++) acc += rdv(w, wrow + c, bf) * i1[(size_t)c*NP];
  if (in2){
    const float* i2 = in2 + (size_t)bb*in2_bs + p;
    for (int c = 0; c < C2; c++) acc += rdv(w, wrow + C1 + c, bf) * i2[(size_t)c*NP];
  }
  if (act == 1) acc = gelu_f(acc);
  if (res) acc += res[((size_t)bb*O + o)*NP + p];
  size_t oi = ((size_t)bb*O + o)*NP + p;
  if (to_out){
    if (bf) ((bf16*)out)[oi] = __float2bfloat16(acc);
    else    ((float*)out)[oi] = acc;
  } else {
    ((float*)out)[oi] = acc;
  }
}

// ---------------- cosine attention, flash-style online softmax ----------------
// Q: (B,CQ,NQ) fp32, q chan for head h dim d = qoff+h*16+d
// KV: (B,CKV,NK) fp32, k chan = koff+h*16+d, v chan = voff+h*16+d
// Out: (B,C,NQ) fp32 chan h*16+d. logits = (q/|q|)(k/|k|)*scale
__global__ void cosattn_k(const float* __restrict__ Q, long qbs, int qoff,
                          const float* __restrict__ KV, long kbs, int koff, int voff,
                          float* __restrict__ Out, long obs,
                          int NQ, int NK, float scale){
  __shared__ float Ks[HD*TK];
  __shared__ float Vs[HD*TK];
  __shared__ float KnI[TK];
  int tid = threadIdx.x;
  int h  = blockIdx.y, bb = blockIdx.z;
  int qi = blockIdx.x*blockDim.x + tid;
  bool qv = qi < NQ;
  float qn[HD], acc[HD];
  float m = -INFINITY, l = 0.f;
  if (qv){
    float s = 0.f;
    #pragma unroll
    for (int d = 0; d < HD; d++){
      qn[d] = Q[(size_t)bb*qbs + (size_t)(qoff + h*HD + d)*NQ + qi];
      s += qn[d]*qn[d];
    }
    float inv = scale / fmaxf(sqrtf(s), 1e-12f);
    #pragma unroll
    for (int d = 0; d < HD; d++){ qn[d] *= inv; acc[d] = 0.f; }
  }
  for (int k0 = 0; k0 < NK; k0 += TK){
    int lim = min(TK, NK - k0);
    for (int i = tid; i < HD*TK; i += blockDim.x){
      int pos = i % TK, d = i / TK;
      if (pos < lim){
        Ks[d*TK + pos] = KV[(size_t)bb*kbs + (size_t)(koff + h*HD + d)*NK + k0 + pos];
        Vs[d*TK + pos] = KV[(size_t)bb*kbs + (size_t)(voff + h*HD + d)*NK + k0 + pos];
      }
    }
    __syncthreads();
    if (tid < lim){
      float s = 0.f;
      #pragma unroll
      for (int d = 0; d < HD; d++){ float v = Ks[d*TK + tid]; s += v*v; }
      KnI[tid] = 1.f / fmaxf(sqrtf(s), 1e-12f);
    }
    __syncthreads();
    if (qv){
      for (int pos = 0; pos < lim; pos++){
        float dot = 0.f;
        #pragma unroll
        for (int d = 0; d < HD; d++) dot += qn[d]*Ks[d*TK + pos];
        float logit = dot * KnI[pos];
        float mn = fmaxf(m, logit);
        float r  = __expf(m - mn);       // exp(-inf)=0 handles first iter
        float pp = __expf(logit - mn);
        l = l*r + pp;
        #pragma unroll
        for (int d = 0; d < HD; d++) acc[d] = acc[d]*r + pp*Vs[d*TK + pos];
        m = mn;
      }
    }
    __syncthreads();
  }
  if (qv){
    float li = 1.f / fmaxf(l, 1e-30f);
    #pragma unroll
    for (int d = 0; d < HD; d++)
      Out[(size_t)bb*obs + (size_t)(h*HD + d)*NQ + qi] = acc[d]*li;
  }
}

// ---------------- 4x4 mean pool: (B,C,48,48)->(B,C,12,12) ----------------
__global__ void pool4_k(const float* __restrict__ xn, float* __restrict__ xc){
  int i = blockIdx.x*blockDim.x + threadIdx.x;
  if (i >= 2*128*144) return;
  int pc = i % 144; int bc = i / 144;
  int hc = pc / 12, wc = pc % 12;
  const float* s = xn + (size_t)bc*2304 + hc*4*48 + wc*4;
  float acc = 0.f;
  #pragma unroll
  for (int r = 0; r < 4; r++)
    #pragma unroll
    for (int c2 = 0; c2 < 4; c2++) acc += s[r*48 + c2];
  xc[i] = acc * 0.0625f;
}

// ---------------- bilinear upsample 12x12 -> 48x48 (align_corners=False, edge clamp) ----------------
__global__ void ups_k(const float* __restrict__ g, float* __restrict__ out){
  int i = blockIdx.x*blockDim.x + threadIdx.x;
  if (i >= 2*128*2304) return;
  int p = i % 2304; int bc = i / 2304;
  int h = p / 48, w = p % 48;
  float sh = h*0.25f - 0.375f;
  float sw = w*0.25f - 0.375f;
  float fh0 = floorf(sh), fw0 = floorf(sw);
  float fh = sh - fh0, fw = sw - fw0;
  int h0 = (int)fh0, w0 = (int)fw0;
  int h0c = min(11, max(0, h0)),   h1c = min(11, max(0, h0+1));
  int w0c = min(11, max(0, w0)),   w1c = min(11, max(0, w0+1));
  const float* s = g + (size_t)bc*144;
  float v00 = s[h0c*12 + w0c], v01 = s[h0c*12 + w1c];
  float v10 = s[h1c*12 + w0c], v11 = s[h1c*12 + w1c];
  out[i] = (1.f-fh)*((1.f-fw)*v00 + fw*v01) + fh*((1.f-fw)*v10 + fw*v11);
}

extern "C" void kernel_launch(void* const* d_in, const int* in_sizes, int n_in,
                              void* d_out, int out_size, void* d_ws, size_t ws_size,
                              hipStream_t stream){
  const int B = 2, C = 128, HW = 2304;
  const void* x_in        = d_in[0];
  const void* g1          = d_in[1];
  const void* b1          = d_in[2];
  const void* loc_qkv_w   = d_in[3];
  const void* loc_proj_w  = d_in[4];
  const void* loc_proj_b  = d_in[5];
  const void* glob_qkv_w  = d_in[6];
  const void* glob_proj_w = d_in[7];
  const void* glob_proj_b = d_in[8];
  const void* fuse_w1     = d_in[9];
  const void* fuse_b1     = d_in[10];
  const void* fuse_w2     = d_in[11];
  const void* fuse_b2     = d_in[12];
  const void* glat        = d_in[13];
  const void* blat        = d_in[14];
  const void* latents     = d_in[15];
  const void* qlat_w      = d_in[16];
  const void* kvx_w       = d_in[17];
  const void* qx_w        = d_in[18];
  const void* kvlat_w     = d_in[19];
  const void* lat_proj_w  = d_in[20];
  const void* lat_proj_b  = d_in[21];
  const void* g2          = d_in[22];
  const void* b2          = d_in[23];
  const void* ffn_w1      = d_in[24];
  const void* ffn_b1      = d_in[25];
  const void* ffn_w2      = d_in[26];
  const void* ffn_b2      = d_in[27];

  // ---- compact aliased workspace layout (floats), total 4,128,769 < 16 MiB ----
  float* ws = (float*)d_ws;
  float* P  = ws + 0;        // persistent residual accumulator (x -> x1 -> x2)
  float* N  = ws + 589824;   // LN output / f1 / xw
  float* A  = ws + 1179648;  // att / gup / qx
  float* Q  = ws + 1769472;  // big region, 2,359,296 floats
  float* FLAG = ws + 4128768;

  // branch-1 aliases inside Q
  float* qkv   = Q;                 // 1,769,472
  float* L     = Q + 1769472;       // local, 589,824
  float* xc    = Q;                 // after qkv dead: 36,864
  float* qkvc  = Q + 36864;         // 110,592
  float* gatt  = Q + 147456;        // 36,864
  float* gproj = Q + 184320;        // 36,864
  // branch-2 aliases inside Q
  float* kvx   = Q;                 // 1,179,648
  float* latf  = Q + 1179648;       // 2,048
  float* qlat  = Q + 1181696;       // 4,096
  float* latr  = Q + 1185792;       // 4,096
  float* kvlat = Q + 1189888;       // 8,192
  // branch-3 alias
  float* ffh   = Q;                 // 2,359,296

  dim3 blk(256);

  detect_k<<<1, 64, 0, stream>>>(x_in, FLAG);
  cvt_k<<<2304, blk, 0, stream>>>(x_in, P, 589824, FLAG);

  // ---- BioAttentionFusion branch ----
  ln2d_k<<<dim3(9,B), blk, 0, stream>>>(P, g1, b1, N, C, HW, FLAG);
  conv1x1_k<<<dim3(9,384,B), blk, 0, stream>>>(N,(long)C*HW,C, nullptr,0,0, loc_qkv_w,nullptr,nullptr, qkv,0,384,HW,0, FLAG);
  cosattn_k<<<dim3(9,8,B), blk, 0, stream>>>(qkv,(long)384*HW,0, qkv,(long)384*HW,128,256, A,(long)C*HW, HW,HW,0.25f);
  conv1x1_k<<<dim3(9,128,B), blk, 0, stream>>>(A,(long)C*HW,C, nullptr,0,0, loc_proj_w,loc_proj_b,nullptr, L,0,C,HW,0, FLAG);
  pool4_k<<<144, blk, 0, stream>>>(N, xc);
  conv1x1_k<<<dim3(1,384,B), blk, 0, stream>>>(xc,(long)C*144,C, nullptr,0,0, glob_qkv_w,nullptr,nullptr, qkvc,0,384,144,0, FLAG);
  cosattn_k<<<dim3(1,8,B), blk, 0, stream>>>(qkvc,(long)384*144,0, qkvc,(long)384*144,128,256, gatt,(long)C*144, 144,144,0.25f);
  conv1x1_k<<<dim3(1,128,B), blk, 0, stream>>>(gatt,(long)C*144,C, nullptr,0,0, glob_proj_w,glob_proj_b,nullptr, gproj,0,C,144,0, FLAG);
  ups_k<<<2304, blk, 0, stream>>>(gproj, A);                                          // A = upsampled global
  conv1x1_k<<<dim3(9,128,B), blk, 0, stream>>>(L,(long)C*HW,C, A,(long)C*HW,C, fuse_w1,fuse_b1,nullptr, N,0,C,HW,1, FLAG);  // N = gelu(fuse1)
  conv1x1_k<<<dim3(9,128,B), blk, 0, stream>>>(N,(long)C*HW,C, nullptr,0,0, fuse_w2,fuse_b2,P, P,0,C,HW,0, FLAG);           // P = x + f

  // ---- LatentMixer branch ----
  ln2d_k<<<dim3(9,B), blk, 0, stream>>>(P, glat, blat, N, C, HW, FLAG);
  conv1x1_k<<<dim3(9,256,B), blk, 0, stream>>>(N,(long)C*HW,C, nullptr,0,0, kvx_w,nullptr,nullptr, kvx,0,256,HW,0, FLAG);
  conv1x1_k<<<dim3(9,128,B), blk, 0, stream>>>(N,(long)C*HW,C, nullptr,0,0, qx_w,nullptr,nullptr, A,0,C,HW,0, FLAG);        // A = qx
  cvt_k<<<8, blk, 0, stream>>>(latents, latf, 2048, FLAG);
  conv1x1_k<<<dim3(1,128,B), blk, 0, stream>>>(latf,0L,C, nullptr,0,0, qlat_w,nullptr,nullptr, qlat,0,C,16,0, FLAG);
  cosattn_k<<<dim3(1,8,B), blk, 0, stream>>>(qlat,(long)C*16,0, kvx,(long)256*HW,0,128, latr,(long)C*16, 16,HW,0.25f);
  conv1x1_k<<<dim3(1,256,B), blk, 0, stream>>>(latr,(long)C*16,C, nullptr,0,0, kvlat_w,nullptr,nullptr, kvlat,0,256,16,0, FLAG);
  cosattn_k<<<dim3(9,8,B), blk, 0, stream>>>(A,(long)C*HW,0, kvlat,(long)256*16,0,128, N,(long)C*HW, HW,16,0.25f);          // N = xw
  conv1x1_k<<<dim3(9,128,B), blk, 0, stream>>>(N,(long)C*HW,C, nullptr,0,0, lat_proj_w,lat_proj_b,P, P,0,C,HW,0, FLAG);     // P = x2

  // ---- FFN branch ----
  ln2d_k<<<dim3(9,B), blk, 0, stream>>>(P, g2, b2, N, C, HW, FLAG);
  conv1x1_k<<<dim3(9,512,B), blk, 0, stream>>>(N,(long)C*HW,C, nullptr,0,0, ffn_w1,ffn_b1,nullptr, ffh,0,512,HW,1, FLAG);
  conv1x1_k<<<dim3(9,128,B), blk, 0, stream>>>(ffh,(long)512*HW,512, nullptr,0,0, ffn_w2,ffn_b2,P, d_out,1,C,HW,0, FLAG);
}

// Round 8
// 2046.489 us; speedup vs baseline: 1.6524x; 1.6511x over previous
//
#include <hip/hip_runtime.h>
#include <hip/hip_bf16.h>

typedef __hip_bfloat16 bf16;

#define HD 16
#define TK 128
#define KP 20            // attn4 LDS pitch: 16 dims + 4 pad, keeps float4 16B-aligned
#define MINIT (-1e30f)   // finite softmax init: logits bounded by scale=0.25, exp underflows to 0

__device__ __forceinline__ float b2f(bf16 v){ return __bfloat162float(v); }
__device__ __forceinline__ float gelu_f(float x){ return 0.5f*x*(1.0f+erff(x*0.70710678118654752f)); }
__device__ __forceinline__ float rdv(const void* p, size_t i, bool bf){
  return bf ? b2f(((const bf16*)p)[i]) : ((const float*)p)[i];
}

// ---------------- dtype detector (proven): 1.0 if bf16 ----------------
__global__ void detect_k(const void* __restrict__ x, float* __restrict__ flag){
  if (threadIdx.x == 0 && blockIdx.x == 0){
    const float* xf = (const float*)x;
    const bf16*  xb = (const bf16*)x;
    double sF = 0.0, sB = 0.0;
    for (int i = 0; i < 512; i++){ float v = fabsf(xf[i]);     if (!(v < 1e30f)) v = 1e30f; sF += v; }
    for (int i = 0; i < 1024; i++){ float v = fabsf(b2f(xb[i])); if (!(v < 1e30f)) v = 1e30f; sB += v; }
    float mF = (float)(sF/512.0), mB = (float)(sB/1024.0);
    float dF = fabsf(logf(fmaxf(mF, 1e-30f)));
    float dB = fabsf(logf(fmaxf(mB, 1e-30f)));
    *flag = (dB <= dF) ? 1.0f : 0.0f;
  }
}

// ---------------- input -> fp32 convert (proven) ----------------
__global__ void cvt_k(const void* __restrict__ in, float* __restrict__ out, int n,
                      const float* __restrict__ flagp){
  bool bf = *flagp > 0.5f;
  int i = blockIdx.x*blockDim.x + threadIdx.x;
  if (i < n) out[i] = rdv(in, i, bf);
}

// ---------------- LayerNorm over channels, per pixel (proven) ----------------
__global__ void ln2d_k(const float* __restrict__ x, const void* __restrict__ g,
                       const void* __restrict__ b, float* __restrict__ y,
                       int C, int HW, const float* __restrict__ flagp){
  bool bf = *flagp > 0.5f;
  int p  = blockIdx.x*blockDim.x + threadIdx.x;
  int bb = blockIdx.y;
  if (p >= HW) return;
  const float* xb = x + (size_t)bb*C*HW + p;
  float s = 0.f, s2 = 0.f;
  for (int c = 0; c < C; c++){ float v = xb[(size_t)c*HW]; s += v; s2 += v*v; }
  float mu  = s  / (float)C;
  float var = fmaxf(s2 / (float)C - mu*mu, 0.f);
  float inv = rsqrtf(var + 1e-5f);
  float* yb = y + (size_t)bb*C*HW + p;
  for (int c = 0; c < C; c++){
    yb[(size_t)c*HW] = (xb[(size_t)c*HW] - mu)*inv*rdv(g,c,bf) + rdv(b,c,bf);
  }
}

// ---------------- generic 1x1 conv, scalar (proven — convf4 is convicted, not used) ----------------
__global__ void conv1x1_k(const float* __restrict__ in1, long in1_bs, int C1,
                          const float* __restrict__ in2, long in2_bs, int C2,
                          const void* __restrict__ w, const void* __restrict__ bias,
                          const float* __restrict__ res,
                          void* __restrict__ out, int to_out, int O, int NP, int act,
                          const float* __restrict__ flagp){
  bool bf = *flagp > 0.5f;
  int p = blockIdx.x*blockDim.x + threadIdx.x;
  if (p >= NP) return;
  int o = blockIdx.y, bb = blockIdx.z;
  size_t wrow = (size_t)o*(C1 + C2);
  float acc = bias ? rdv(bias, o, bf) : 0.f;
  const float* i1 = in1 + (size_t)bb*in1_bs + p;
  for (int c = 0; c < C1; c++) acc += rdv(w, wrow + c, bf) * i1[(size_t)c*NP];
  if (in2){
    const float* i2 = in2 + (size_t)bb*in2_bs + p;
    for (int c = 0; c < C2; c++) acc += rdv(w, wrow + C1 + c, bf) * i2[(size_t)c*NP];
  }
  if (act == 1) acc = gelu_f(acc);
  if (res) acc += res[((size_t)bb*O + o)*NP + p];
  size_t oi = ((size_t)bb*O + o)*NP + p;
  if (to_out){
    if (bf) ((bf16*)out)[oi] = __float2bfloat16(acc);
    else    ((float*)out)[oi] = acc;
  } else {
    ((float*)out)[oi] = acc;
  }
}

// ---------------- cosine attention, proven round-2 kernel (kept for small NK=144 case) ----------------
__global__ void cosattn_k(const float* __restrict__ Q, long qbs, int qoff,
                          const float* __restrict__ KV, long kbs, int koff, int voff,
                          float* __restrict__ Out, long obs,
                          int NQ, int NK, float scale){
  __shared__ float Ks[HD*TK];
  __shared__ float Vs[HD*TK];
  __shared__ float KnI[TK];
  int tid = threadIdx.x;
  int h  = blockIdx.y, bb = blockIdx.z;
  int qi = blockIdx.x*blockDim.x + tid;
  bool qv = qi < NQ;
  float qn[HD], acc[HD];
  float m = -INFINITY, l = 0.f;
  if (qv){
    float s = 0.f;
    #pragma unroll
    for (int d = 0; d < HD; d++){
      qn[d] = Q[(size_t)bb*qbs + (size_t)(qoff + h*HD + d)*NQ + qi];
      s += qn[d]*qn[d];
    }
    float inv = scale / fmaxf(sqrtf(s), 1e-12f);
    #pragma unroll
    for (int d = 0; d < HD; d++){ qn[d] *= inv; acc[d] = 0.f; }
  }
  for (int k0 = 0; k0 < NK; k0 += TK){
    int lim = min(TK, NK - k0);
    for (int i = tid; i < HD*TK; i += blockDim.x){
      int pos = i % TK, d = i / TK;
      if (pos < lim){
        Ks[d*TK + pos] = KV[(size_t)bb*kbs + (size_t)(koff + h*HD + d)*NK + k0 + pos];
        Vs[d*TK + pos] = KV[(size_t)bb*kbs + (size_t)(voff + h*HD + d)*NK + k0 + pos];
      }
    }
    __syncthreads();
    if (tid < lim){
      float s = 0.f;
      #pragma unroll
      for (int d = 0; d < HD; d++){ float v = Ks[d*TK + tid]; s += v*v; }
      KnI[tid] = 1.f / fmaxf(sqrtf(s), 1e-12f);
    }
    __syncthreads();
    if (qv){
      for (int pos = 0; pos < lim; pos++){
        float dot = 0.f;
        #pragma unroll
        for (int d = 0; d < HD; d++) dot += qn[d]*Ks[d*TK + pos];
        float logit = dot * KnI[pos];
        float mn = fmaxf(m, logit);
        float r  = __expf(m - mn);
        float pp = __expf(logit - mn);
        l = l*r + pp;
        #pragma unroll
        for (int d = 0; d < HD; d++) acc[d] = acc[d]*r + pp*Vs[d*TK + pos];
        m = mn;
      }
    }
    __syncthreads();
  }
  if (qv){
    float li = 1.f / fmaxf(l, 1e-30f);
    #pragma unroll
    for (int d = 0; d < HD; d++)
      Out[(size_t)bb*obs + (size_t)(h*HD + d)*NQ + qi] = acc[d]*li;
  }
}

// ---------------- cosine attention: 4 lanes per query, float4 LDS, online softmax ----------------
// Q:(B,CQ,NQ) chan qoff+h*16+d; KV:(B,CKV,NK) k chan koff+h*16+d, v chan voff+h*16+d
// Out:(B,C,NQ) chan h*16+d. 64 queries/block; lanes 4q..4q+3 own dims 4*sub..4*sub+3.
__global__ __launch_bounds__(256) void attn4_k(
    const float* __restrict__ Q, long qbs, int qoff,
    const float* __restrict__ KV, long kbs, int koff, int voff,
    float* __restrict__ Out, long obs, int NQ, int NK, float scale)
{
  __shared__ __align__(16) float Ks[TK*KP];
  __shared__ __align__(16) float Vs[TK*KP];
  __shared__ float KnI[TK];
  int tid = threadIdx.x;
  int sub = tid & 3;
  int h = blockIdx.y, bb = blockIdx.z;
  int qi = blockIdx.x*64 + (tid >> 2);      // quad-uniform
  bool qv = qi < NQ;                        // quad-uniform => shfl inside is safe
  float qn[4] = {0,0,0,0}, acc[4] = {0,0,0,0};
  float m = MINIT, l = 0.f;
  if (qv){
    float s = 0.f;
    #pragma unroll
    for (int j = 0; j < 4; j++){
      qn[j] = Q[(size_t)bb*qbs + (size_t)(qoff + h*16 + sub*4 + j)*NQ + qi];
      s += qn[j]*qn[j];
    }
    s += __shfl_xor(s, 1); s += __shfl_xor(s, 2);
    float inv = scale / fmaxf(sqrtf(s), 1e-12f);
    #pragma unroll
    for (int j = 0; j < 4; j++) qn[j] *= inv;
  }
  for (int k0 = 0; k0 < NK; k0 += TK){
    int lim = min(TK, NK - k0);
    for (int i = tid; i < 16*TK; i += 256){
      int pos = i & (TK-1), d = i >> 7;     // i = d*128+pos, bijective
      if (pos < lim){
        Ks[pos*KP + d] = KV[(size_t)bb*kbs + (size_t)(koff + h*16 + d)*NK + k0 + pos];
        Vs[pos*KP + d] = KV[(size_t)bb*kbs + (size_t)(voff + h*16 + d)*NK + k0 + pos];
      }
    }
    __syncthreads();
    if (tid < lim){
      float s = 0.f;
      #pragma unroll
      for (int d = 0; d < 16; d++){ float v = Ks[tid*KP + d]; s += v*v; }
      KnI[tid] = 1.f / fmaxf(sqrtf(s), 1e-12f);
    }
    __syncthreads();
    for (int pos = 0; pos < lim; pos++){
      float4 k4 = *(const float4*)&Ks[pos*KP + sub*4];   // (pos*20+sub*4)*4 bytes % 16 == 0
      float dd = qn[0]*k4.x + qn[1]*k4.y + qn[2]*k4.z + qn[3]*k4.w;
      dd += __shfl_xor(dd, 1); dd += __shfl_xor(dd, 2);
      float logit = dd * KnI[pos];
      float mn = fmaxf(m, logit);
      float r  = __expf(m - mn);            // finite m => never NaN; 0 on first iter
      float pp = __expf(logit - mn);
      l = l*r + pp; m = mn;
      float4 v4 = *(const float4*)&Vs[pos*KP + sub*4];
      acc[0] = acc[0]*r + pp*v4.x;
      acc[1] = acc[1]*r + pp*v4.y;
      acc[2] = acc[2]*r + pp*v4.z;
      acc[3] = acc[3]*r + pp*v4.w;
    }
    __syncthreads();
  }
  if (qv){
    float li = 1.f / fmaxf(l, 1e-30f);
    #pragma unroll
    for (int j = 0; j < 4; j++)
      Out[(size_t)bb*obs + (size_t)(h*16 + sub*4 + j)*NQ + qi] = acc[j]*li;
  }
}

// ---------------- latent-read attention, split-K partials ----------------
// ql:(B,128,16); kvx:(B,256,NK) batch stride kbs; k chan h*16+d, v chan 128+h*16+d
// part[(((bb*8+h)*16+q)*S+s)*18] = {m, l, acc[16]}
__global__ void latpart_k(const float* __restrict__ ql, const float* __restrict__ kvx,
                          long kbs, float* __restrict__ part, int NK, int S){
  int s = blockIdx.x, h = blockIdx.y, bb = blockIdx.z;
  int q = threadIdx.x;
  if (q >= 16) return;
  float qn[16]; float ss = 0.f;
  #pragma unroll
  for (int d = 0; d < 16; d++){
    qn[d] = ql[(size_t)bb*2048 + (size_t)(h*16+d)*16 + q];
    ss += qn[d]*qn[d];
  }
  float inv = 0.25f / fmaxf(sqrtf(ss), 1e-12f);
  #pragma unroll
  for (int d = 0; d < 16; d++) qn[d] *= inv;
  float m = MINIT, l = 0.f, acc[16];
  #pragma unroll
  for (int d = 0; d < 16; d++) acc[d] = 0.f;
  int chunk = NK / S;
  int k0 = s*chunk, k1 = k0 + chunk;
  const float* kb = kvx + (size_t)bb*kbs;
  for (int pos = k0; pos < k1; pos++){
    float kd[16]; float ks = 0.f;
    #pragma unroll
    for (int d = 0; d < 16; d++){
      kd[d] = kb[(size_t)(h*16+d)*NK + pos];
      ks += kd[d]*kd[d];
    }
    float kin = 1.f / fmaxf(sqrtf(ks), 1e-12f);
    float dot = 0.f;
    #pragma unroll
    for (int d = 0; d < 16; d++) dot += qn[d]*kd[d];
    float logit = dot * kin;
    float mn = fmaxf(m, logit);
    float r  = __expf(m - mn);
    float pp = __expf(logit - mn);
    l = l*r + pp; m = mn;
    #pragma unroll
    for (int d = 0; d < 16; d++)
      acc[d] = acc[d]*r + pp*kb[(size_t)(128 + h*16+d)*NK + pos];
  }
  size_t idx = (size_t)((((bb*8 + h)*16 + q)*S) + s)*18;
  part[idx] = m; part[idx+1] = l;
  #pragma unroll
  for (int d = 0; d < 16; d++) part[idx+2+d] = acc[d];
}

// combine S partials -> latr:(B,128,16)
__global__ void latcomb_k(const float* __restrict__ part, float* __restrict__ latr, int S){
  int t = threadIdx.x;               // 256 = 2b * 8h * 16q
  int q = t & 15, h = (t >> 4) & 7, bb = t >> 7;
  size_t base = (size_t)(((bb*8 + h)*16 + q)*S)*18;
  float M = MINIT;
  for (int s = 0; s < S; s++) M = fmaxf(M, part[base + (size_t)s*18]);
  float L = 0.f, acc[16];
  #pragma unroll
  for (int d = 0; d < 16; d++) acc[d] = 0.f;
  for (int s = 0; s < S; s++){
    const float* ps = part + base + (size_t)s*18;
    float w = __expf(ps[0] - M);
    L += ps[1]*w;
    #pragma unroll
    for (int d = 0; d < 16; d++) acc[d] += ps[2+d]*w;
  }
  float li = 1.f / fmaxf(L, 1e-30f);
  #pragma unroll
  for (int d = 0; d < 16; d++)
    latr[(size_t)bb*2048 + (size_t)(h*16+d)*16 + q] = acc[d]*li;
}

// ---------------- 4x4 mean pool (proven) ----------------
__global__ void pool4_k(const float* __restrict__ xn, float* __restrict__ xc){
  int i = blockIdx.x*blockDim.x + threadIdx.x;
  if (i >= 2*128*144) return;
  int pc = i % 144; int bc = i / 144;
  int hc = pc / 12, wc = pc % 12;
  const float* s = xn + (size_t)bc*2304 + hc*4*48 + wc*4;
  float acc = 0.f;
  #pragma unroll
  for (int r = 0; r < 4; r++)
    #pragma unroll
    for (int c2 = 0; c2 < 4; c2++) acc += s[r*48 + c2];
  xc[i] = acc * 0.0625f;
}

// ---------------- bilinear upsample 12->48 (proven) ----------------
__global__ void ups_k(const float* __restrict__ g, float* __restrict__ out){
  int i = blockIdx.x*blockDim.x + threadIdx.x;
  if (i >= 2*128*2304) return;
  int p = i % 2304; int bc = i / 2304;
  int h = p / 48, w = p % 48;
  float sh = h*0.25f - 0.375f;
  float sw = w*0.25f - 0.375f;
  float fh0 = floorf(sh), fw0 = floorf(sw);
  float fh = sh - fh0, fw = sw - fw0;
  int h0 = (int)fh0, w0 = (int)fw0;
  int h0c = min(11, max(0, h0)),   h1c = min(11, max(0, h0+1));
  int w0c = min(11, max(0, w0)),   w1c = min(11, max(0, w0+1));
  const float* s = g + (size_t)bc*144;
  float v00 = s[h0c*12 + w0c], v01 = s[h0c*12 + w1c];
  float v10 = s[h1c*12 + w0c], v11 = s[h1c*12 + w1c];
  out[i] = (1.f-fh)*((1.f-fw)*v00 + fw*v01) + fh*((1.f-fw)*v10 + fw*v11);
}

extern "C" void kernel_launch(void* const* d_in, const int* in_sizes, int n_in,
                              void* d_out, int out_size, void* d_ws, size_t ws_size,
                              hipStream_t stream){
  const int B = 2, C = 128, HW = 2304;
  const void* x_in        = d_in[0];
  const void* g1          = d_in[1];
  const void* b1          = d_in[2];
  const void* loc_qkv_w   = d_in[3];
  const void* loc_proj_w  = d_in[4];
  const void* loc_proj_b  = d_in[5];
  const void* glob_qkv_w  = d_in[6];
  const void* glob_proj_w = d_in[7];
  const void* glob_proj_b = d_in[8];
  const void* fuse_w1     = d_in[9];
  const void* fuse_b1     = d_in[10];
  const void* fuse_w2     = d_in[11];
  const void* fuse_b2     = d_in[12];
  const void* glat        = d_in[13];
  const void* blat        = d_in[14];
  const void* latents     = d_in[15];
  const void* qlat_w      = d_in[16];
  const void* kvx_w       = d_in[17];
  const void* qx_w        = d_in[18];
  const void* kvlat_w     = d_in[19];
  const void* lat_proj_w  = d_in[20];
  const void* lat_proj_b  = d_in[21];
  const void* g2          = d_in[22];
  const void* b2          = d_in[23];
  const void* ffn_w1      = d_in[24];
  const void* ffn_b1      = d_in[25];
  const void* ffn_w2      = d_in[26];
  const void* ffn_b2      = d_in[27];

  // ---- round-2/7 workspace layout + part buffer inside Q region ----
  float* ws = (float*)d_ws;
  float* P  = ws + 0;        // persistent residual accumulator
  float* N  = ws + 589824;   // LN output / f1 / xw
  float* A  = ws + 1179648;  // att / gup / qx
  float* Q  = ws + 1769472;  // big region, 2,359,296 floats
  float* FLAG = ws + 4128768;

  // branch-1 aliases inside Q
  float* qkv   = Q;                 // 1,769,472
  float* L     = Q + 1769472;       // local, 589,824
  float* xc    = Q;                 // after qkv dead: 36,864
  float* qkvc  = Q + 36864;         // 110,592
  float* gatt  = Q + 147456;        // 36,864
  float* gproj = Q + 184320;        // 36,864
  // branch-2 aliases inside Q
  float* kvx   = Q;                 // 1,179,648
  float* latf  = Q + 1179648;       // 2,048
  float* qlat  = Q + 1181696;       // 4,096
  float* latr  = Q + 1185792;       // 4,096
  float* kvlat = Q + 1189888;       // 8,192 -> ends 1,198,080
  float* part  = Q + 1198080;       // 73,728 (S=16 split partials) -> ends 1,271,808
  // branch-3 alias
  float* ffh   = Q;                 // 2,359,296

  dim3 blk(256);

  detect_k<<<1, 64, 0, stream>>>(x_in, FLAG);
  cvt_k<<<2304, blk, 0, stream>>>(x_in, P, 589824, FLAG);

  // ---- BioAttentionFusion branch ----
  ln2d_k<<<dim3(9,B), blk, 0, stream>>>(P, g1, b1, N, C, HW, FLAG);
  conv1x1_k<<<dim3(9,384,B), blk, 0, stream>>>(N,(long)C*HW,C, nullptr,0,0, loc_qkv_w,nullptr,nullptr, qkv,0,384,HW,0, FLAG);
  attn4_k<<<dim3(36,8,B), blk, 0, stream>>>(qkv,(long)384*HW,0, qkv,(long)384*HW,128,256, A,(long)C*HW, HW,HW,0.25f);
  conv1x1_k<<<dim3(9,128,B), blk, 0, stream>>>(A,(long)C*HW,C, nullptr,0,0, loc_proj_w,loc_proj_b,nullptr, L,0,C,HW,0, FLAG);
  pool4_k<<<144, blk, 0, stream>>>(N, xc);
  conv1x1_k<<<dim3(1,384,B), blk, 0, stream>>>(xc,(long)C*144,C, nullptr,0,0, glob_qkv_w,nullptr,nullptr, qkvc,0,384,144,0, FLAG);
  cosattn_k<<<dim3(1,8,B), blk, 0, stream>>>(qkvc,(long)384*144,0, qkvc,(long)384*144,128,256, gatt,(long)C*144, 144,144,0.25f);
  conv1x1_k<<<dim3(1,128,B), blk, 0, stream>>>(gatt,(long)C*144,C, nullptr,0,0, glob_proj_w,glob_proj_b,nullptr, gproj,0,C,144,0, FLAG);
  ups_k<<<2304, blk, 0, stream>>>(gproj, A);                                          // A = upsampled global
  conv1x1_k<<<dim3(9,128,B), blk, 0, stream>>>(L,(long)C*HW,C, A,(long)C*HW,C, fuse_w1,fuse_b1,nullptr, N,0,C,HW,1, FLAG);  // N = gelu(fuse1)
  conv1x1_k<<<dim3(9,128,B), blk, 0, stream>>>(N,(long)C*HW,C, nullptr,0,0, fuse_w2,fuse_b2,P, P,0,C,HW,0, FLAG);           // P = x + f

  // ---- LatentMixer branch ----
  ln2d_k<<<dim3(9,B), blk, 0, stream>>>(P, glat, blat, N, C, HW, FLAG);
  conv1x1_k<<<dim3(9,256,B), blk, 0, stream>>>(N,(long)C*HW,C, nullptr,0,0, kvx_w,nullptr,nullptr, kvx,0,256,HW,0, FLAG);
  conv1x1_k<<<dim3(9,128,B), blk, 0, stream>>>(N,(long)C*HW,C, nullptr,0,0, qx_w,nullptr,nullptr, A,0,C,HW,0, FLAG);        // A = qx
  cvt_k<<<8, blk, 0, stream>>>(latents, latf, 2048, FLAG);
  conv1x1_k<<<dim3(1,128,B), blk, 0, stream>>>(latf,0L,C, nullptr,0,0, qlat_w,nullptr,nullptr, qlat,0,C,16,0, FLAG);
  latpart_k<<<dim3(16,8,B), 64, 0, stream>>>(qlat, kvx, (long)256*HW, part, HW, 16);
  latcomb_k<<<1, blk, 0, stream>>>(part, latr, 16);
  conv1x1_k<<<dim3(1,256,B), blk, 0, stream>>>(latr,(long)C*16,C, nullptr,0,0, kvlat_w,nullptr,nullptr, kvlat,0,256,16,0, FLAG);
  attn4_k<<<dim3(36,8,B), blk, 0, stream>>>(A,(long)C*HW,0, kvlat,(long)256*16,0,128, N,(long)C*HW, HW,16,0.25f);           // N = xw
  conv1x1_k<<<dim3(9,128,B), blk, 0, stream>>>(N,(long)C*HW,C, nullptr,0,0, lat_proj_w,lat_proj_b,P, P,0,C,HW,0, FLAG);     // P = x2

  // ---- FFN branch ----
  ln2d_k<<<dim3(9,B), blk, 0, stream>>>(P, g2, b2, N, C, HW, FLAG);
  conv1x1_k<<<dim3(9,512,B), blk, 0, stream>>>(N,(long)C*HW,C, nullptr,0,0, ffn_w1,ffn_b1,nullptr, ffh,0,512,HW,1, FLAG);
  conv1x1_k<<<dim3(9,128,B), blk, 0, stream>>>(ffh,(long)512*HW,512, nullptr,0,0, ffn_w2,ffn_b2,P, d_out,1,C,HW,0, FLAG);
}

// Round 12
// 1701.754 us; speedup vs baseline: 1.9872x; 1.2026x over previous
//
#include <hip/hip_runtime.h>
#include <hip/hip_bf16.h>

typedef __hip_bfloat16 bf16;

#define HD 16
#define TK 128
#define KP 20            // attn LDS pitch: 16 dims + 4 pad, keeps float4 16B-aligned
#define MINIT (-1e30f)

__device__ __forceinline__ float b2f(bf16 v){ return __bfloat162float(v); }
__device__ __forceinline__ float gelu_f(float x){ return 0.5f*x*(1.0f+erff(x*0.70710678118654752f)); }
__device__ __forceinline__ float rdv(const void* p, size_t i, bool bf){
  return bf ? b2f(((const bf16*)p)[i]) : ((const float*)p)[i];
}

// ---------------- dtype detector (proven): 1.0 if bf16 ----------------
__global__ void detect_k(const void* __restrict__ x, float* __restrict__ flag){
  if (threadIdx.x == 0 && blockIdx.x == 0){
    const float* xf = (const float*)x;
    const bf16*  xb = (const bf16*)x;
    double sF = 0.0, sB = 0.0;
    for (int i = 0; i < 512; i++){ float v = fabsf(xf[i]);     if (!(v < 1e30f)) v = 1e30f; sF += v; }
    for (int i = 0; i < 1024; i++){ float v = fabsf(b2f(xb[i])); if (!(v < 1e30f)) v = 1e30f; sB += v; }
    float mF = (float)(sF/512.0), mB = (float)(sB/1024.0);
    float dF = fabsf(logf(fmaxf(mF, 1e-30f)));
    float dB = fabsf(logf(fmaxf(mB, 1e-30f)));
    *flag = (dB <= dF) ? 1.0f : 0.0f;
  }
}

// ---------------- input -> fp32 convert (proven) ----------------
__global__ void cvt_k(const void* __restrict__ in, float* __restrict__ out, int n,
                      const float* __restrict__ flagp){
  bool bf = *flagp > 0.5f;
  int i = blockIdx.x*blockDim.x + threadIdx.x;
  if (i < n) out[i] = rdv(in, i, bf);
}

// ---------------- LayerNorm over channels, per pixel (proven) ----------------
__global__ void ln2d_k(const float* __restrict__ x, const void* __restrict__ g,
                       const void* __restrict__ b, float* __restrict__ y,
                       int C, int HW, const float* __restrict__ flagp){
  bool bf = *flagp > 0.5f;
  int p  = blockIdx.x*blockDim.x + threadIdx.x;
  int bb = blockIdx.y;
  if (p >= HW) return;
  const float* xb = x + (size_t)bb*C*HW + p;
  float s = 0.f, s2 = 0.f;
  for (int c = 0; c < C; c++){ float v = xb[(size_t)c*HW]; s += v; s2 += v*v; }
  float mu  = s  / (float)C;
  float var = fmaxf(s2 / (float)C - mu*mu, 0.f);
  float inv = rsqrtf(var + 1e-5f);
  float* yb = y + (size_t)bb*C*HW + p;
  for (int c = 0; c < C; c++){
    yb[(size_t)c*HW] = (xb[(size_t)c*HW] - mu)*inv*rdv(g,c,bf) + rdv(b,c,bf);
  }
}

// ---------------- generic scalar 1x1 conv (proven; small NP cases) ----------------
__global__ void conv1x1_k(const float* __restrict__ in1, long in1_bs, int C1,
                          const float* __restrict__ in2, long in2_bs, int C2,
                          const void* __restrict__ w, const void* __restrict__ bias,
                          const float* __restrict__ res,
                          void* __restrict__ out, int to_out, int O, int NP, int act,
                          const float* __restrict__ flagp){
  bool bf = *flagp > 0.5f;
  int p = blockIdx.x*blockDim.x + threadIdx.x;
  if (p >= NP) return;
  int o = blockIdx.y, bb = blockIdx.z;
  size_t wrow = (size_t)o*(C1 + C2);
  float acc = bias ? rdv(bias, o, bf) : 0.f;
  const float* i1 = in1 + (size_t)bb*in1_bs + p;
  for (int c = 0; c < C1; c++) acc += rdv(w, wrow + c, bf) * i1[(size_t)c*NP];
  if (in2){
    const float* i2 = in2 + (size_t)bb*in2_bs + p;
    for (int c = 0; c < C2; c++) acc += rdv(w, wrow + C1 + c, bf) * i2[(size_t)c*NP];
  }
  if (act == 1) acc = gelu_f(acc);
  if (res) acc += res[((size_t)bb*O + o)*NP + p];
  size_t oi = ((size_t)bb*O + o)*NP + p;
  if (to_out){
    if (bf) ((bf16*)out)[oi] = __float2bfloat16(acc);
    else    ((float*)out)[oi] = acc;
  } else {
    ((float*)out)[oi] = acc;
  }
}

// ---------------- BISECT SUBJECT: conv1x1 clone, 4 pixels per thread ----------------
// Identical structure/args to conv1x1_k (FLAG, void* weights, grid.y=O, no launch_bounds).
// Each thread handles pixels p, p+np4, p+2*np4, p+3*np4 (np4 = NP/4; NP must be %4).
__global__ void conv1x1p4_k(const float* __restrict__ in1, long in1_bs, int C1,
                            const float* __restrict__ in2, long in2_bs, int C2,
                            const void* __restrict__ w, const void* __restrict__ bias,
                            const float* __restrict__ res,
                            void* __restrict__ out, int to_out, int O, int NP, int act,
                            const float* __restrict__ flagp){
  bool bf = *flagp > 0.5f;
  int np4 = NP >> 2;
  int p = blockIdx.x*blockDim.x + threadIdx.x;
  if (p >= np4) return;
  int o = blockIdx.y, bb = blockIdx.z;
  size_t wrow = (size_t)o*(C1 + C2);
  float b0 = bias ? rdv(bias, o, bf) : 0.f;
  float a0 = b0, a1 = b0, a2 = b0, a3 = b0;
  const float* i1 = in1 + (size_t)bb*in1_bs + p;
  for (int c = 0; c < C1; c++){
    float wv = rdv(w, wrow + c, bf);
    size_t base = (size_t)c*NP;
    a0 += wv * i1[base];
    a1 += wv * i1[base + np4];
    a2 += wv * i1[base + 2*np4];
    a3 += wv * i1[base + 3*np4];
  }
  if (in2){
    const float* i2 = in2 + (size_t)bb*in2_bs + p;
    for (int c = 0; c < C2; c++){
      float wv = rdv(w, wrow + C1 + c, bf);
      size_t base = (size_t)c*NP;
      a0 += wv * i2[base];
      a1 += wv * i2[base + np4];
      a2 += wv * i2[base + 2*np4];
      a3 += wv * i2[base + 3*np4];
    }
  }
  if (act == 1){ a0 = gelu_f(a0); a1 = gelu_f(a1); a2 = gelu_f(a2); a3 = gelu_f(a3); }
  size_t oi = ((size_t)bb*O + o)*NP + p;
  if (res){
    a0 += res[oi];
    a1 += res[oi + np4];
    a2 += res[oi + 2*np4];
    a3 += res[oi + 3*np4];
  }
  if (to_out){
    if (bf){
      ((bf16*)out)[oi]         = __float2bfloat16(a0);
      ((bf16*)out)[oi + np4]   = __float2bfloat16(a1);
      ((bf16*)out)[oi + 2*np4] = __float2bfloat16(a2);
      ((bf16*)out)[oi + 3*np4] = __float2bfloat16(a3);
    } else {
      ((float*)out)[oi]         = a0;
      ((float*)out)[oi + np4]   = a1;
      ((float*)out)[oi + 2*np4] = a2;
      ((float*)out)[oi + 3*np4] = a3;
    }
  } else {
    ((float*)out)[oi]         = a0;
    ((float*)out)[oi + np4]   = a1;
    ((float*)out)[oi + 2*np4] = a2;
    ((float*)out)[oi + 3*np4] = a3;
  }
}

// ---------------- cosine attention, proven round-2 kernel (global attn NK=144) ----------------
__global__ void cosattn_k(const float* __restrict__ Q, long qbs, int qoff,
                          const float* __restrict__ KV, long kbs, int koff, int voff,
                          float* __restrict__ Out, long obs,
                          int NQ, int NK, float scale){
  __shared__ float Ks[HD*TK];
  __shared__ float Vs[HD*TK];
  __shared__ float KnI[TK];
  int tid = threadIdx.x;
  int h  = blockIdx.y, bb = blockIdx.z;
  int qi = blockIdx.x*blockDim.x + tid;
  bool qv = qi < NQ;
  float qn[HD], acc[HD];
  float m = -INFINITY, l = 0.f;
  if (qv){
    float s = 0.f;
    #pragma unroll
    for (int d = 0; d < HD; d++){
      qn[d] = Q[(size_t)bb*qbs + (size_t)(qoff + h*HD + d)*NQ + qi];
      s += qn[d]*qn[d];
    }
    float inv = scale / fmaxf(sqrtf(s), 1e-12f);
    #pragma unroll
    for (int d = 0; d < HD; d++){ qn[d] *= inv; acc[d] = 0.f; }
  }
  for (int k0 = 0; k0 < NK; k0 += TK){
    int lim = min(TK, NK - k0);
    for (int i = tid; i < HD*TK; i += blockDim.x){
      int pos = i % TK, d = i / TK;
      if (pos < lim){
        Ks[d*TK + pos] = KV[(size_t)bb*kbs + (size_t)(koff + h*HD + d)*NK + k0 + pos];
        Vs[d*TK + pos] = KV[(size_t)bb*kbs + (size_t)(voff + h*HD + d)*NK + k0 + pos];
      }
    }
    __syncthreads();
    if (tid < lim){
      float s = 0.f;
      #pragma unroll
      for (int d = 0; d < HD; d++){ float v = Ks[d*TK + tid]; s += v*v; }
      KnI[tid] = 1.f / fmaxf(sqrtf(s), 1e-12f);
    }
    __syncthreads();
    if (qv){
      for (int pos = 0; pos < lim; pos++){
        float dot = 0.f;
        #pragma unroll
        for (int d = 0; d < HD; d++) dot += qn[d]*Ks[d*TK + pos];
        float logit = dot * KnI[pos];
        float mn = fmaxf(m, logit);
        float r  = __expf(m - mn);
        float pp = __expf(logit - mn);
        l = l*r + pp;
        #pragma unroll
        for (int d = 0; d < HD; d++) acc[d] = acc[d]*r + pp*Vs[d*TK + pos];
        m = mn;
      }
    }
    __syncthreads();
  }
  if (qv){
    float li = 1.f / fmaxf(l, 1e-30f);
    #pragma unroll
    for (int d = 0; d < HD; d++)
      Out[(size_t)bb*obs + (size_t)(h*HD + d)*NQ + qi] = acc[d]*li;
  }
}

// ---------------- attn4 (proven round-8; local + xw attention) ----------------
__global__ __launch_bounds__(256) void attn4_k(
    const float* __restrict__ Q, long qbs, int qoff,
    const float* __restrict__ KV, long kbs, int koff, int voff,
    float* __restrict__ Out, long obs, int NQ, int NK, float scale)
{
  __shared__ __align__(16) float Ks[TK*KP];
  __shared__ __align__(16) float Vs[TK*KP];
  __shared__ float KnI[TK];
  int tid = threadIdx.x;
  int sub = tid & 3;
  int h = blockIdx.y, bb = blockIdx.z;
  int qi = blockIdx.x*64 + (tid >> 2);
  bool qv = qi < NQ;
  float qn[4] = {0,0,0,0}, acc[4] = {0,0,0,0};
  float m = MINIT, l = 0.f;
  if (qv){
    float s = 0.f;
    #pragma unroll
    for (int j = 0; j < 4; j++){
      qn[j] = Q[(size_t)bb*qbs + (size_t)(qoff + h*16 + sub*4 + j)*NQ + qi];
      s += qn[j]*qn[j];
    }
    s += __shfl_xor(s, 1); s += __shfl_xor(s, 2);
    float inv = scale / fmaxf(sqrtf(s), 1e-12f);
    #pragma unroll
    for (int j = 0; j < 4; j++) qn[j] *= inv;
  }
  for (int k0 = 0; k0 < NK; k0 += TK){
    int lim = min(TK, NK - k0);
    for (int i = tid; i < 16*TK; i += 256){
      int pos = i & (TK-1), d = i >> 7;
      if (pos < lim){
        Ks[pos*KP + d] = KV[(size_t)bb*kbs + (size_t)(koff + h*16 + d)*NK + k0 + pos];
        Vs[pos*KP + d] = KV[(size_t)bb*kbs + (size_t)(voff + h*16 + d)*NK + k0 + pos];
      }
    }
    __syncthreads();
    if (tid < lim){
      float s = 0.f;
      #pragma unroll
      for (int d = 0; d < 16; d++){ float v = Ks[tid*KP + d]; s += v*v; }
      KnI[tid] = 1.f / fmaxf(sqrtf(s), 1e-12f);
    }
    __syncthreads();
    for (int pos = 0; pos < lim; pos++){
      float4 k4 = *(const float4*)&Ks[pos*KP + sub*4];
      float dd = qn[0]*k4.x + qn[1]*k4.y + qn[2]*k4.z + qn[3]*k4.w;
      dd += __shfl_xor(dd, 1); dd += __shfl_xor(dd, 2);
      float logit = dd * KnI[pos];
      float mn = fmaxf(m, logit);
      float r  = __expf(m - mn);
      float pp = __expf(logit - mn);
      l = l*r + pp; m = mn;
      float4 v4 = *(const float4*)&Vs[pos*KP + sub*4];
      acc[0] = acc[0]*r + pp*v4.x;
      acc[1] = acc[1]*r + pp*v4.y;
      acc[2] = acc[2]*r + pp*v4.z;
      acc[3] = acc[3]*r + pp*v4.w;
    }
    __syncthreads();
  }
  if (qv){
    float li = 1.f / fmaxf(l, 1e-30f);
    #pragma unroll
    for (int j = 0; j < 4; j++)
      Out[(size_t)bb*obs + (size_t)(h*16 + sub*4 + j)*NQ + qi] = acc[j]*li;
  }
}

// ---------------- latent-read attention, split-K partials (proven) ----------------
__global__ void latpart_k(const float* __restrict__ ql, const float* __restrict__ kvx,
                          long kbs, float* __restrict__ part, int NK, int S){
  int s = blockIdx.x, h = blockIdx.y, bb = blockIdx.z;
  int q = threadIdx.x;
  if (q >= 16) return;
  float qn[16]; float ss = 0.f;
  #pragma unroll
  for (int d = 0; d < 16; d++){
    qn[d] = ql[(size_t)bb*2048 + (size_t)(h*16+d)*16 + q];
    ss += qn[d]*qn[d];
  }
  float inv = 0.25f / fmaxf(sqrtf(ss), 1e-12f);
  #pragma unroll
  for (int d = 0; d < 16; d++) qn[d] *= inv;
  float m = MINIT, l = 0.f, acc[16];
  #pragma unroll
  for (int d = 0; d < 16; d++) acc[d] = 0.f;
  int chunk = NK / S;
  int k0 = s*chunk, k1 = k0 + chunk;
  const float* kb = kvx + (size_t)bb*kbs;
  for (int pos = k0; pos < k1; pos++){
    float kd[16]; float ks = 0.f;
    #pragma unroll
    for (int d = 0; d < 16; d++){
      kd[d] = kb[(size_t)(h*16+d)*NK + pos];
      ks += kd[d]*kd[d];
    }
    float kin = 1.f / fmaxf(sqrtf(ks), 1e-12f);
    float dot = 0.f;
    #pragma unroll
    for (int d = 0; d < 16; d++) dot += qn[d]*kd[d];
    float logit = dot * kin;
    float mn = fmaxf(m, logit);
    float r  = __expf(m - mn);
    float pp = __expf(logit - mn);
    l = l*r + pp; m = mn;
    #pragma unroll
    for (int d = 0; d < 16; d++)
      acc[d] = acc[d]*r + pp*kb[(size_t)(128 + h*16+d)*NK + pos];
  }
  size_t idx = (size_t)((((bb*8 + h)*16 + q)*S) + s)*18;
  part[idx] = m; part[idx+1] = l;
  #pragma unroll
  for (int d = 0; d < 16; d++) part[idx+2+d] = acc[d];
}

__global__ void latcomb_k(const float* __restrict__ part, float* __restrict__ latr, int S){
  int t = threadIdx.x;
  int q = t & 15, h = (t >> 4) & 7, bb = t >> 7;
  size_t base = (size_t)(((bb*8 + h)*16 + q)*S)*18;
  float M = MINIT;
  for (int s = 0; s < S; s++) M = fmaxf(M, part[base + (size_t)s*18]);
  float L = 0.f, acc[16];
  #pragma unroll
  for (int d = 0; d < 16; d++) acc[d] = 0.f;
  for (int s = 0; s < S; s++){
    const float* ps = part + base + (size_t)s*18;
    float w = __expf(ps[0] - M);
    L += ps[1]*w;
    #pragma unroll
    for (int d = 0; d < 16; d++) acc[d] += ps[2+d]*w;
  }
  float li = 1.f / fmaxf(L, 1e-30f);
  #pragma unroll
  for (int d = 0; d < 16; d++)
    latr[(size_t)bb*2048 + (size_t)(h*16+d)*16 + q] = acc[d]*li;
}

// ---------------- 4x4 mean pool (proven) ----------------
__global__ void pool4_k(const float* __restrict__ xn, float* __restrict__ xc){
  int i = blockIdx.x*blockDim.x + threadIdx.x;
  if (i >= 2*128*144) return;
  int pc = i % 144; int bc = i / 144;
  int hc = pc / 12, wc = pc % 12;
  const float* s = xn + (size_t)bc*2304 + hc*4*48 + wc*4;
  float acc = 0.f;
  #pragma unroll
  for (int r = 0; r < 4; r++)
    #pragma unroll
    for (int c2 = 0; c2 < 4; c2++) acc += s[r*48 + c2];
  xc[i] = acc * 0.0625f;
}

// ---------------- bilinear upsample 12->48 (proven) ----------------
__global__ void ups_k(const float* __restrict__ g, float* __restrict__ out){
  int i = blockIdx.x*blockDim.x + threadIdx.x;
  if (i >= 2*128*2304) return;
  int p = i % 2304; int bc = i / 2304;
  int h = p / 48, w = p % 48;
  float sh = h*0.25f - 0.375f;
  float sw = w*0.25f - 0.375f;
  float fh0 = floorf(sh), fw0 = floorf(sw);
  float fh = sh - fh0, fw = sw - fw0;
  int h0 = (int)fh0, w0 = (int)fw0;
  int h0c = min(11, max(0, h0)),   h1c = min(11, max(0, h0+1));
  int w0c = min(11, max(0, w0)),   w1c = min(11, max(0, w0+1));
  const float* s = g + (size_t)bc*144;
  float v00 = s[h0c*12 + w0c], v01 = s[h0c*12 + w1c];
  float v10 = s[h1c*12 + w0c], v11 = s[h1c*12 + w1c];
  out[i] = (1.f-fh)*((1.f-fw)*v00 + fw*v01) + fh*((1.f-fw)*v10 + fw*v11);
}

extern "C" void kernel_launch(void* const* d_in, const int* in_sizes, int n_in,
                              void* d_out, int out_size, void* d_ws, size_t ws_size,
                              hipStream_t stream){
  const int B = 2, C = 128, HW = 2304;
  const void* x_in        = d_in[0];
  const void* g1          = d_in[1];
  const void* b1          = d_in[2];
  const void* loc_qkv_w   = d_in[3];
  const void* loc_proj_w  = d_in[4];
  const void* loc_proj_b  = d_in[5];
  const void* glob_qkv_w  = d_in[6];
  const void* glob_proj_w = d_in[7];
  const void* glob_proj_b = d_in[8];
  const void* fuse_w1     = d_in[9];
  const void* fuse_b1     = d_in[10];
  const void* fuse_w2     = d_in[11];
  const void* fuse_b2     = d_in[12];
  const void* glat        = d_in[13];
  const void* blat        = d_in[14];
  const void* latents     = d_in[15];
  const void* qlat_w      = d_in[16];
  const void* kvx_w       = d_in[17];
  const void* qx_w        = d_in[18];
  const void* kvlat_w     = d_in[19];
  const void* lat_proj_w  = d_in[20];
  const void* lat_proj_b  = d_in[21];
  const void* g2          = d_in[22];
  const void* b2          = d_in[23];
  const void* ffn_w1      = d_in[24];
  const void* ffn_b1      = d_in[25];
  const void* ffn_w2      = d_in[26];
  const void* ffn_b2      = d_in[27];

  // ---- R8 workspace layout VERBATIM ----
  float* ws = (float*)d_ws;
  float* P  = ws + 0;
  float* N  = ws + 589824;
  float* A  = ws + 1179648;
  float* Q  = ws + 1769472;
  float* FLAG = ws + 4128768;

  float* qkv   = Q;                 // 1,769,472
  float* L     = Q + 1769472;       // 589,824
  float* xc    = Q;
  float* qkvc  = Q + 36864;
  float* gatt  = Q + 147456;
  float* gproj = Q + 184320;
  float* kvx   = Q;                 // 1,179,648
  float* latf  = Q + 1179648;
  float* qlat  = Q + 1181696;
  float* latr  = Q + 1185792;
  float* kvlat = Q + 1189888;
  float* part  = Q + 1198080;       // 73,728 (S=16)
  float* ffh   = Q;                 // 2,359,296

  dim3 blk(256);

  detect_k<<<1, 64, 0, stream>>>(x_in, FLAG);
  cvt_k<<<2304, blk, 0, stream>>>(x_in, P, 589824, FLAG);

  // ---- BioAttentionFusion branch ----
  ln2d_k<<<dim3(9,B), blk, 0, stream>>>(P, g1, b1, N, C, HW, FLAG);
  conv1x1p4_k<<<dim3(3,384,B), blk, 0, stream>>>(N,(long)C*HW,C, nullptr,0,0, loc_qkv_w,nullptr,nullptr, qkv,0,384,HW,0, FLAG);
  attn4_k<<<dim3(36,8,B), blk, 0, stream>>>(qkv,(long)384*HW,0, qkv,(long)384*HW,128,256, A,(long)C*HW, HW,HW,0.25f);
  conv1x1p4_k<<<dim3(3,128,B), blk, 0, stream>>>(A,(long)C*HW,C, nullptr,0,0, loc_proj_w,loc_proj_b,nullptr, L,0,C,HW,0, FLAG);
  pool4_k<<<144, blk, 0, stream>>>(N, xc);
  conv1x1_k<<<dim3(1,384,B), blk, 0, stream>>>(xc,(long)C*144,C, nullptr,0,0, glob_qkv_w,nullptr,nullptr, qkvc,0,384,144,0, FLAG);
  cosattn_k<<<dim3(1,8,B), blk, 0, stream>>>(qkvc,(long)384*144,0, qkvc,(long)384*144,128,256, gatt,(long)C*144, 144,144,0.25f);
  conv1x1_k<<<dim3(1,128,B), blk, 0, stream>>>(gatt,(long)C*144,C, nullptr,0,0, glob_proj_w,glob_proj_b,nullptr, gproj,0,C,144,0, FLAG);
  ups_k<<<2304, blk, 0, stream>>>(gproj, A);                                          // A = upsampled global
  conv1x1p4_k<<<dim3(3,128,B), blk, 0, stream>>>(L,(long)C*HW,C, A,(long)C*HW,C, fuse_w1,fuse_b1,nullptr, N,0,C,HW,1, FLAG);  // N = gelu(fuse1)
  conv1x1p4_k<<<dim3(3,128,B), blk, 0, stream>>>(N,(long)C*HW,C, nullptr,0,0, fuse_w2,fuse_b2,P, P,0,C,HW,0, FLAG);           // P = x + f

  // ---- LatentMixer branch ----
  ln2d_k<<<dim3(9,B), blk, 0, stream>>>(P, glat, blat, N, C, HW, FLAG);
  conv1x1p4_k<<<dim3(3,256,B), blk, 0, stream>>>(N,(long)C*HW,C, nullptr,0,0, kvx_w,nullptr,nullptr, kvx,0,256,HW,0, FLAG);
  conv1x1p4_k<<<dim3(3,128,B), blk, 0, stream>>>(N,(long)C*HW,C, nullptr,0,0, qx_w,nullptr,nullptr, A,0,C,HW,0, FLAG);        // A = qx
  cvt_k<<<8, blk, 0, stream>>>(latents, latf, 2048, FLAG);
  conv1x1_k<<<dim3(1,128,B), blk, 0, stream>>>(latf,0L,C, nullptr,0,0, qlat_w,nullptr,nullptr, qlat,0,C,16,0, FLAG);
  latpart_k<<<dim3(16,8,B), 64, 0, stream>>>(qlat, kvx, (long)256*HW, part, HW, 16);
  latcomb_k<<<1, blk, 0, stream>>>(part, latr, 16);
  conv1x1_k<<<dim3(1,256,B), blk, 0, stream>>>(latr,(long)C*16,C, nullptr,0,0, kvlat_w,nullptr,nullptr, kvlat,0,256,16,0, FLAG);
  attn4_k<<<dim3(36,8,B), blk, 0, stream>>>(A,(long)C*HW,0, kvlat,(long)256*16,0,128, N,(long)C*HW, HW,16,0.25f);             // N = xw
  conv1x1p4_k<<<dim3(3,128,B), blk, 0, stream>>>(N,(long)C*HW,C, nullptr,0,0, lat_proj_w,lat_proj_b,P, P,0,C,HW,0, FLAG);     // P = x2

  // ---- FFN branch ----
  ln2d_k<<<dim3(9,B), blk, 0, stream>>>(P, g2, b2, N, C, HW, FLAG);
  conv1x1p4_k<<<dim3(3,512,B), blk, 0, stream>>>(N,(long)C*HW,C, nullptr,0,0, ffn_w1,ffn_b1,nullptr, ffh,0,512,HW,1, FLAG);
  conv1x1p4_k<<<dim3(3,128,B), blk, 0, stream>>>(ffh,(long)512*HW,512, nullptr,0,0, ffn_w2,ffn_b2,P, d_out,1,C,HW,0, FLAG);
}

// Round 13
// 1565.015 us; speedup vs baseline: 2.1608x; 1.0874x over previous
//
#include <hip/hip_runtime.h>
#include <hip/hip_bf16.h>

typedef __hip_bfloat16 bf16;

#define HD 16
#define TK 128
#define KP 20            // attn LDS pitch: 16 dims + 4 pad, keeps float4 16B-aligned
#define MINIT (-1e30f)

__device__ __forceinline__ float b2f(bf16 v){ return __bfloat162float(v); }
__device__ __forceinline__ float gelu_f(float x){ return 0.5f*x*(1.0f+erff(x*0.70710678118654752f)); }
__device__ __forceinline__ float rdv(const void* p, size_t i, bool bf){
  return bf ? b2f(((const bf16*)p)[i]) : ((const float*)p)[i];
}

// ---------------- dtype detector (proven): 1.0 if bf16 ----------------
__global__ void detect_k(const void* __restrict__ x, float* __restrict__ flag){
  if (threadIdx.x == 0 && blockIdx.x == 0){
    const float* xf = (const float*)x;
    const bf16*  xb = (const bf16*)x;
    double sF = 0.0, sB = 0.0;
    for (int i = 0; i < 512; i++){ float v = fabsf(xf[i]);     if (!(v < 1e30f)) v = 1e30f; sF += v; }
    for (int i = 0; i < 1024; i++){ float v = fabsf(b2f(xb[i])); if (!(v < 1e30f)) v = 1e30f; sB += v; }
    float mF = (float)(sF/512.0), mB = (float)(sB/1024.0);
    float dF = fabsf(logf(fmaxf(mF, 1e-30f)));
    float dB = fabsf(logf(fmaxf(mB, 1e-30f)));
    *flag = (dB <= dF) ? 1.0f : 0.0f;
  }
}

// ---------------- input -> fp32 convert (proven) ----------------
__global__ void cvt_k(const void* __restrict__ in, float* __restrict__ out, int n,
                      const float* __restrict__ flagp){
  bool bf = *flagp > 0.5f;
  int i = blockIdx.x*blockDim.x + threadIdx.x;
  if (i < n) out[i] = rdv(in, i, bf);
}

// ---------------- LayerNorm over channels, per pixel (proven) ----------------
__global__ void ln2d_k(const float* __restrict__ x, const void* __restrict__ g,
                       const void* __restrict__ b, float* __restrict__ y,
                       int C, int HW, const float* __restrict__ flagp){
  bool bf = *flagp > 0.5f;
  int p  = blockIdx.x*blockDim.x + threadIdx.x;
  int bb = blockIdx.y;
  if (p >= HW) return;
  const float* xb = x + (size_t)bb*C*HW + p;
  float s = 0.f, s2 = 0.f;
  for (int c = 0; c < C; c++){ float v = xb[(size_t)c*HW]; s += v; s2 += v*v; }
  float mu  = s  / (float)C;
  float var = fmaxf(s2 / (float)C - mu*mu, 0.f);
  float inv = rsqrtf(var + 1e-5f);
  float* yb = y + (size_t)bb*C*HW + p;
  for (int c = 0; c < C; c++){
    yb[(size_t)c*HW] = (xb[(size_t)c*HW] - mu)*inv*rdv(g,c,bf) + rdv(b,c,bf);
  }
}

// ---------------- generic scalar 1x1 conv (proven; small NP cases) ----------------
__global__ void conv1x1_k(const float* __restrict__ in1, long in1_bs, int C1,
                          const float* __restrict__ in2, long in2_bs, int C2,
                          const void* __restrict__ w, const void* __restrict__ bias,
                          const float* __restrict__ res,
                          void* __restrict__ out, int to_out, int O, int NP, int act,
                          const float* __restrict__ flagp){
  bool bf = *flagp > 0.5f;
  int p = blockIdx.x*blockDim.x + threadIdx.x;
  if (p >= NP) return;
  int o = blockIdx.y, bb = blockIdx.z;
  size_t wrow = (size_t)o*(C1 + C2);
  float acc = bias ? rdv(bias, o, bf) : 0.f;
  const float* i1 = in1 + (size_t)bb*in1_bs + p;
  for (int c = 0; c < C1; c++) acc += rdv(w, wrow + c, bf) * i1[(size_t)c*NP];
  if (in2){
    const float* i2 = in2 + (size_t)bb*in2_bs + p;
    for (int c = 0; c < C2; c++) acc += rdv(w, wrow + C1 + c, bf) * i2[(size_t)c*NP];
  }
  if (act == 1) acc = gelu_f(acc);
  if (res) acc += res[((size_t)bb*O + o)*NP + p];
  size_t oi = ((size_t)bb*O + o)*NP + p;
  if (to_out){
    if (bf) ((bf16*)out)[oi] = __float2bfloat16(acc);
    else    ((float*)out)[oi] = acc;
  } else {
    ((float*)out)[oi] = acc;
  }
}

// ---------------- conv1x1 clone, 4 pixels per thread (proven R12) ----------------
__global__ void conv1x1p4_k(const float* __restrict__ in1, long in1_bs, int C1,
                            const float* __restrict__ in2, long in2_bs, int C2,
                            const void* __restrict__ w, const void* __restrict__ bias,
                            const float* __restrict__ res,
                            void* __restrict__ out, int to_out, int O, int NP, int act,
                            const float* __restrict__ flagp){
  bool bf = *flagp > 0.5f;
  int np4 = NP >> 2;
  int p = blockIdx.x*blockDim.x + threadIdx.x;
  if (p >= np4) return;
  int o = blockIdx.y, bb = blockIdx.z;
  size_t wrow = (size_t)o*(C1 + C2);
  float b0 = bias ? rdv(bias, o, bf) : 0.f;
  float a0 = b0, a1 = b0, a2 = b0, a3 = b0;
  const float* i1 = in1 + (size_t)bb*in1_bs + p;
  for (int c = 0; c < C1; c++){
    float wv = rdv(w, wrow + c, bf);
    size_t base = (size_t)c*NP;
    a0 += wv * i1[base];
    a1 += wv * i1[base + np4];
    a2 += wv * i1[base + 2*np4];
    a3 += wv * i1[base + 3*np4];
  }
  if (in2){
    const float* i2 = in2 + (size_t)bb*in2_bs + p;
    for (int c = 0; c < C2; c++){
      float wv = rdv(w, wrow + C1 + c, bf);
      size_t base = (size_t)c*NP;
      a0 += wv * i2[base];
      a1 += wv * i2[base + np4];
      a2 += wv * i2[base + 2*np4];
      a3 += wv * i2[base + 3*np4];
    }
  }
  if (act == 1){ a0 = gelu_f(a0); a1 = gelu_f(a1); a2 = gelu_f(a2); a3 = gelu_f(a3); }
  size_t oi = ((size_t)bb*O + o)*NP + p;
  if (res){
    a0 += res[oi];
    a1 += res[oi + np4];
    a2 += res[oi + 2*np4];
    a3 += res[oi + 3*np4];
  }
  if (to_out){
    if (bf){
      ((bf16*)out)[oi]         = __float2bfloat16(a0);
      ((bf16*)out)[oi + np4]   = __float2bfloat16(a1);
      ((bf16*)out)[oi + 2*np4] = __float2bfloat16(a2);
      ((bf16*)out)[oi + 3*np4] = __float2bfloat16(a3);
    } else {
      ((float*)out)[oi]         = a0;
      ((float*)out)[oi + np4]   = a1;
      ((float*)out)[oi + 2*np4] = a2;
      ((float*)out)[oi + 3*np4] = a3;
    }
  } else {
    ((float*)out)[oi]         = a0;
    ((float*)out)[oi + np4]   = a1;
    ((float*)out)[oi + 2*np4] = a2;
    ((float*)out)[oi + 3*np4] = a3;
  }
}

// ---------------- cosine attention, proven round-2 kernel (global attn NK=144) ----------------
__global__ void cosattn_k(const float* __restrict__ Q, long qbs, int qoff,
                          const float* __restrict__ KV, long kbs, int koff, int voff,
                          float* __restrict__ Out, long obs,
                          int NQ, int NK, float scale){
  __shared__ float Ks[HD*TK];
  __shared__ float Vs[HD*TK];
  __shared__ float KnI[TK];
  int tid = threadIdx.x;
  int h  = blockIdx.y, bb = blockIdx.z;
  int qi = blockIdx.x*blockDim.x + tid;
  bool qv = qi < NQ;
  float qn[HD], acc[HD];
  float m = -INFINITY, l = 0.f;
  if (qv){
    float s = 0.f;
    #pragma unroll
    for (int d = 0; d < HD; d++){
      qn[d] = Q[(size_t)bb*qbs + (size_t)(qoff + h*HD + d)*NQ + qi];
      s += qn[d]*qn[d];
    }
    float inv = scale / fmaxf(sqrtf(s), 1e-12f);
    #pragma unroll
    for (int d = 0; d < HD; d++){ qn[d] *= inv; acc[d] = 0.f; }
  }
  for (int k0 = 0; k0 < NK; k0 += TK){
    int lim = min(TK, NK - k0);
    for (int i = tid; i < HD*TK; i += blockDim.x){
      int pos = i % TK, d = i / TK;
      if (pos < lim){
        Ks[d*TK + pos] = KV[(size_t)bb*kbs + (size_t)(koff + h*HD + d)*NK + k0 + pos];
        Vs[d*TK + pos] = KV[(size_t)bb*kbs + (size_t)(voff + h*HD + d)*NK + k0 + pos];
      }
    }
    __syncthreads();
    if (tid < lim){
      float s = 0.f;
      #pragma unroll
      for (int d = 0; d < HD; d++){ float v = Ks[d*TK + tid]; s += v*v; }
      KnI[tid] = 1.f / fmaxf(sqrtf(s), 1e-12f);
    }
    __syncthreads();
    if (qv){
      for (int pos = 0; pos < lim; pos++){
        float dot = 0.f;
        #pragma unroll
        for (int d = 0; d < HD; d++) dot += qn[d]*Ks[d*TK + pos];
        float logit = dot * KnI[pos];
        float mn = fmaxf(m, logit);
        float r  = __expf(m - mn);
        float pp = __expf(logit - mn);
        l = l*r + pp;
        #pragma unroll
        for (int d = 0; d < HD; d++) acc[d] = acc[d]*r + pp*Vs[d*TK + pos];
        m = mn;
      }
    }
    __syncthreads();
  }
  if (qv){
    float li = 1.f / fmaxf(l, 1e-30f);
    #pragma unroll
    for (int d = 0; d < HD; d++)
      Out[(size_t)bb*obs + (size_t)(h*HD + d)*NQ + qi] = acc[d]*li;
  }
}

// ---------------- attn4 — DELTA THIS ROUND: online-max removed ----------------
// Cosine logits are bounded (|logit| <= scale = 0.25) so exp never overflows:
// softmax(x) = exp(x)/sum(exp(x)) computed directly. Removes the serial
// m/rescale chain: acc becomes pure FMA accumulation.
__global__ __launch_bounds__(256) void attn4_k(
    const float* __restrict__ Q, long qbs, int qoff,
    const float* __restrict__ KV, long kbs, int koff, int voff,
    float* __restrict__ Out, long obs, int NQ, int NK, float scale)
{
  __shared__ __align__(16) float Ks[TK*KP];
  __shared__ __align__(16) float Vs[TK*KP];
  __shared__ float KnI[TK];
  int tid = threadIdx.x;
  int sub = tid & 3;
  int h = blockIdx.y, bb = blockIdx.z;
  int qi = blockIdx.x*64 + (tid >> 2);
  bool qv = qi < NQ;
  float qn[4] = {0,0,0,0}, acc[4] = {0,0,0,0};
  float l = 0.f;
  if (qv){
    float s = 0.f;
    #pragma unroll
    for (int j = 0; j < 4; j++){
      qn[j] = Q[(size_t)bb*qbs + (size_t)(qoff + h*16 + sub*4 + j)*NQ + qi];
      s += qn[j]*qn[j];
    }
    s += __shfl_xor(s, 1); s += __shfl_xor(s, 2);
    float inv = scale / fmaxf(sqrtf(s), 1e-12f);
    #pragma unroll
    for (int j = 0; j < 4; j++) qn[j] *= inv;
  }
  for (int k0 = 0; k0 < NK; k0 += TK){
    int lim = min(TK, NK - k0);
    for (int i = tid; i < 16*TK; i += 256){
      int pos = i & (TK-1), d = i >> 7;
      if (pos < lim){
        Ks[pos*KP + d] = KV[(size_t)bb*kbs + (size_t)(koff + h*16 + d)*NK + k0 + pos];
        Vs[pos*KP + d] = KV[(size_t)bb*kbs + (size_t)(voff + h*16 + d)*NK + k0 + pos];
      }
    }
    __syncthreads();
    if (tid < lim){
      float s = 0.f;
      #pragma unroll
      for (int d = 0; d < 16; d++){ float v = Ks[tid*KP + d]; s += v*v; }
      KnI[tid] = 1.f / fmaxf(sqrtf(s), 1e-12f);
    }
    __syncthreads();
    for (int pos = 0; pos < lim; pos++){
      float4 k4 = *(const float4*)&Ks[pos*KP + sub*4];
      float dd = qn[0]*k4.x + qn[1]*k4.y + qn[2]*k4.z + qn[3]*k4.w;
      dd += __shfl_xor(dd, 1); dd += __shfl_xor(dd, 2);
      float pp = __expf(dd * KnI[pos]);   // |dd*KnI| <= 0.25: safe, no max needed
      l += pp;
      float4 v4 = *(const float4*)&Vs[pos*KP + sub*4];
      acc[0] += pp*v4.x;
      acc[1] += pp*v4.y;
      acc[2] += pp*v4.z;
      acc[3] += pp*v4.w;
    }
    __syncthreads();
  }
  if (qv){
    float li = 1.f / fmaxf(l, 1e-30f);
    #pragma unroll
    for (int j = 0; j < 4; j++)
      Out[(size_t)bb*obs + (size_t)(h*16 + sub*4 + j)*NQ + qi] = acc[j]*li;
  }
}

// ---------------- latent-read attention, split-K partials (proven) ----------------
__global__ void latpart_k(const float* __restrict__ ql, const float* __restrict__ kvx,
                          long kbs, float* __restrict__ part, int NK, int S){
  int s = blockIdx.x, h = blockIdx.y, bb = blockIdx.z;
  int q = threadIdx.x;
  if (q >= 16) return;
  float qn[16]; float ss = 0.f;
  #pragma unroll
  for (int d = 0; d < 16; d++){
    qn[d] = ql[(size_t)bb*2048 + (size_t)(h*16+d)*16 + q];
    ss += qn[d]*qn[d];
  }
  float inv = 0.25f / fmaxf(sqrtf(ss), 1e-12f);
  #pragma unroll
  for (int d = 0; d < 16; d++) qn[d] *= inv;
  float m = MINIT, l = 0.f, acc[16];
  #pragma unroll
  for (int d = 0; d < 16; d++) acc[d] = 0.f;
  int chunk = NK / S;
  int k0 = s*chunk, k1 = k0 + chunk;
  const float* kb = kvx + (size_t)bb*kbs;
  for (int pos = k0; pos < k1; pos++){
    float kd[16]; float ks = 0.f;
    #pragma unroll
    for (int d = 0; d < 16; d++){
      kd[d] = kb[(size_t)(h*16+d)*NK + pos];
      ks += kd[d]*kd[d];
    }
    float kin = 1.f / fmaxf(sqrtf(ks), 1e-12f);
    float dot = 0.f;
    #pragma unroll
    for (int d = 0; d < 16; d++) dot += qn[d]*kd[d];
    float logit = dot * kin;
    float mn = fmaxf(m, logit);
    float r  = __expf(m - mn);
    float pp = __expf(logit - mn);
    l = l*r + pp; m = mn;
    #pragma unroll
    for (int d = 0; d < 16; d++)
      acc[d] = acc[d]*r + pp*kb[(size_t)(128 + h*16+d)*NK + pos];
  }
  size_t idx = (size_t)((((bb*8 + h)*16 + q)*S) + s)*18;
  part[idx] = m; part[idx+1] = l;
  #pragma unroll
  for (int d = 0; d < 16; d++) part[idx+2+d] = acc[d];
}

__global__ void latcomb_k(const float* __restrict__ part, float* __restrict__ latr, int S){
  int t = threadIdx.x;
  int q = t & 15, h = (t >> 4) & 7, bb = t >> 7;
  size_t base = (size_t)(((bb*8 + h)*16 + q)*S)*18;
  float M = MINIT;
  for (int s = 0; s < S; s++) M = fmaxf(M, part[base + (size_t)s*18]);
  float L = 0.f, acc[16];
  #pragma unroll
  for (int d = 0; d < 16; d++) acc[d] = 0.f;
  for (int s = 0; s < S; s++){
    const float* ps = part + base + (size_t)s*18;
    float w = __expf(ps[0] - M);
    L += ps[1]*w;
    #pragma unroll
    for (int d = 0; d < 16; d++) acc[d] += ps[2+d]*w;
  }
  float li = 1.f / fmaxf(L, 1e-30f);
  #pragma unroll
  for (int d = 0; d < 16; d++)
    latr[(size_t)bb*2048 + (size_t)(h*16+d)*16 + q] = acc[d]*li;
}

// ---------------- 4x4 mean pool (proven) ----------------
__global__ void pool4_k(const float* __restrict__ xn, float* __restrict__ xc){
  int i = blockIdx.x*blockDim.x + threadIdx.x;
  if (i >= 2*128*144) return;
  int pc = i % 144; int bc = i / 144;
  int hc = pc / 12, wc = pc % 12;
  const float* s = xn + (size_t)bc*2304 + hc*4*48 + wc*4;
  float acc = 0.f;
  #pragma unroll
  for (int r = 0; r < 4; r++)
    #pragma unroll
    for (int c2 = 0; c2 < 4; c2++) acc += s[r*48 + c2];
  xc[i] = acc * 0.0625f;
}

// ---------------- bilinear upsample 12->48 (proven) ----------------
__global__ void ups_k(const float* __restrict__ g, float* __restrict__ out){
  int i = blockIdx.x*blockDim.x + threadIdx.x;
  if (i >= 2*128*2304) return;
  int p = i % 2304; int bc = i / 2304;
  int h = p / 48, w = p % 48;
  float sh = h*0.25f - 0.375f;
  float sw = w*0.25f - 0.375f;
  float fh0 = floorf(sh), fw0 = floorf(sw);
  float fh = sh - fh0, fw = sw - fw0;
  int h0 = (int)fh0, w0 = (int)fw0;
  int h0c = min(11, max(0, h0)),   h1c = min(11, max(0, h0+1));
  int w0c = min(11, max(0, w0)),   w1c = min(11, max(0, w0+1));
  const float* s = g + (size_t)bc*144;
  float v00 = s[h0c*12 + w0c], v01 = s[h0c*12 + w1c];
  float v10 = s[h1c*12 + w0c], v11 = s[h1c*12 + w1c];
  out[i] = (1.f-fh)*((1.f-fw)*v00 + fw*v01) + fh*((1.f-fw)*v10 + fw*v11);
}

extern "C" void kernel_launch(void* const* d_in, const int* in_sizes, int n_in,
                              void* d_out, int out_size, void* d_ws, size_t ws_size,
                              hipStream_t stream){
  const int B = 2, C = 128, HW = 2304;
  const void* x_in        = d_in[0];
  const void* g1          = d_in[1];
  const void* b1          = d_in[2];
  const void* loc_qkv_w   = d_in[3];
  const void* loc_proj_w  = d_in[4];
  const void* loc_proj_b  = d_in[5];
  const void* glob_qkv_w  = d_in[6];
  const void* glob_proj_w = d_in[7];
  const void* glob_proj_b = d_in[8];
  const void* fuse_w1     = d_in[9];
  const void* fuse_b1     = d_in[10];
  const void* fuse_w2     = d_in[11];
  const void* fuse_b2     = d_in[12];
  const void* glat        = d_in[13];
  const void* blat        = d_in[14];
  const void* latents     = d_in[15];
  const void* qlat_w      = d_in[16];
  const void* kvx_w       = d_in[17];
  const void* qx_w        = d_in[18];
  const void* kvlat_w     = d_in[19];
  const void* lat_proj_w  = d_in[20];
  const void* lat_proj_b  = d_in[21];
  const void* g2          = d_in[22];
  const void* b2          = d_in[23];
  const void* ffn_w1      = d_in[24];
  const void* ffn_b1      = d_in[25];
  const void* ffn_w2      = d_in[26];
  const void* ffn_b2      = d_in[27];

  // ---- R8/R12 workspace layout VERBATIM ----
  float* ws = (float*)d_ws;
  float* P  = ws + 0;
  float* N  = ws + 589824;
  float* A  = ws + 1179648;
  float* Q  = ws + 1769472;
  float* FLAG = ws + 4128768;

  float* qkv   = Q;                 // 1,769,472
  float* L     = Q + 1769472;       // 589,824
  float* xc    = Q;
  float* qkvc  = Q + 36864;
  float* gatt  = Q + 147456;
  float* gproj = Q + 184320;
  float* kvx   = Q;                 // 1,179,648
  float* latf  = Q + 1179648;
  float* qlat  = Q + 1181696;
  float* latr  = Q + 1185792;
  float* kvlat = Q + 1189888;
  float* part  = Q + 1198080;       // 73,728 (S=16)
  float* ffh   = Q;                 // 2,359,296

  dim3 blk(256);

  detect_k<<<1, 64, 0, stream>>>(x_in, FLAG);
  cvt_k<<<2304, blk, 0, stream>>>(x_in, P, 589824, FLAG);

  // ---- BioAttentionFusion branch ----
  ln2d_k<<<dim3(9,B), blk, 0, stream>>>(P, g1, b1, N, C, HW, FLAG);
  conv1x1p4_k<<<dim3(3,384,B), blk, 0, stream>>>(N,(long)C*HW,C, nullptr,0,0, loc_qkv_w,nullptr,nullptr, qkv,0,384,HW,0, FLAG);
  attn4_k<<<dim3(36,8,B), blk, 0, stream>>>(qkv,(long)384*HW,0, qkv,(long)384*HW,128,256, A,(long)C*HW, HW,HW,0.25f);
  conv1x1p4_k<<<dim3(3,128,B), blk, 0, stream>>>(A,(long)C*HW,C, nullptr,0,0, loc_proj_w,loc_proj_b,nullptr, L,0,C,HW,0, FLAG);
  pool4_k<<<144, blk, 0, stream>>>(N, xc);
  conv1x1_k<<<dim3(1,384,B), blk, 0, stream>>>(xc,(long)C*144,C, nullptr,0,0, glob_qkv_w,nullptr,nullptr, qkvc,0,384,144,0, FLAG);
  cosattn_k<<<dim3(1,8,B), blk, 0, stream>>>(qkvc,(long)384*144,0, qkvc,(long)384*144,128,256, gatt,(long)C*144, 144,144,0.25f);
  conv1x1_k<<<dim3(1,128,B), blk, 0, stream>>>(gatt,(long)C*144,C, nullptr,0,0, glob_proj_w,glob_proj_b,nullptr, gproj,0,C,144,0, FLAG);
  ups_k<<<2304, blk, 0, stream>>>(gproj, A);                                          // A = upsampled global
  conv1x1p4_k<<<dim3(3,128,B), blk, 0, stream>>>(L,(long)C*HW,C, A,(long)C*HW,C, fuse_w1,fuse_b1,nullptr, N,0,C,HW,1, FLAG);  // N = gelu(fuse1)
  conv1x1p4_k<<<dim3(3,128,B), blk, 0, stream>>>(N,(long)C*HW,C, nullptr,0,0, fuse_w2,fuse_b2,P, P,0,C,HW,0, FLAG);           // P = x + f

  // ---- LatentMixer branch ----
  ln2d_k<<<dim3(9,B), blk, 0, stream>>>(P, glat, blat, N, C, HW, FLAG);
  conv1x1p4_k<<<dim3(3,256,B), blk, 0, stream>>>(N,(long)C*HW,C, nullptr,0,0, kvx_w,nullptr,nullptr, kvx,0,256,HW,0, FLAG);
  conv1x1p4_k<<<dim3(3,128,B), blk, 0, stream>>>(N,(long)C*HW,C, nullptr,0,0, qx_w,nullptr,nullptr, A,0,C,HW,0, FLAG);        // A = qx
  cvt_k<<<8, blk, 0, stream>>>(latents, latf, 2048, FLAG);
  conv1x1_k<<<dim3(1,128,B), blk, 0, stream>>>(latf,0L,C, nullptr,0,0, qlat_w,nullptr,nullptr, qlat,0,C,16,0, FLAG);
  latpart_k<<<dim3(16,8,B), 64, 0, stream>>>(qlat, kvx, (long)256*HW, part, HW, 16);
  latcomb_k<<<1, blk, 0, stream>>>(part, latr, 16);
  conv1x1_k<<<dim3(1,256,B), blk, 0, stream>>>(latr,(long)C*16,C, nullptr,0,0, kvlat_w,nullptr,nullptr, kvlat,0,256,16,0, FLAG);
  attn4_k<<<dim3(36,8,B), blk, 0, stream>>>(A,(long)C*HW,0, kvlat,(long)256*16,0,128, N,(long)C*HW, HW,16,0.25f);             // N = xw
  conv1x1p4_k<<<dim3(3,128,B), blk, 0, stream>>>(N,(long)C*HW,C, nullptr,0,0, lat_proj_w,lat_proj_b,P, P,0,C,HW,0, FLAG);     // P = x2

  // ---- FFN branch ----
  ln2d_k<<<dim3(9,B), blk, 0, stream>>>(P, g2, b2, N, C, HW, FLAG);
  conv1x1p4_k<<<dim3(3,512,B), blk, 0, stream>>>(N,(long)C*HW,C, nullptr,0,0, ffn_w1,ffn_b1,nullptr, ffh,0,512,HW,1, FLAG);
  conv1x1p4_k<<<dim3(3,128,B), blk, 0, stream>>>(ffh,(long)512*HW,512, nullptr,0,0, ffn_w2,ffn_b2,P, d_out,1,C,HW,0, FLAG);
}

// Round 14
// 1418.366 us; speedup vs baseline: 2.3842x; 1.1034x over previous
//
#include <hip/hip_runtime.h>
#include <hip/hip_bf16.h>

typedef __hip_bfloat16 bf16;

#define HD 16
#define TK 128
#define KP 20            // attn LDS pitch: 16 dims + 4 pad, keeps float4 16B-aligned
#define CT 64            // flat_attn tile positions per wave-chunk
#define MINIT (-1e30f)

__device__ __forceinline__ float b2f(bf16 v){ return __bfloat162float(v); }
__device__ __forceinline__ float gelu_f(float x){ return 0.5f*x*(1.0f+erff(x*0.70710678118654752f)); }
__device__ __forceinline__ float rdv(const void* p, size_t i, bool bf){
  return bf ? b2f(((const bf16*)p)[i]) : ((const float*)p)[i];
}

// ---------------- dtype detector (proven; runtime FLAG=0 -> inputs are fp32) ----------------
__global__ void detect_k(const void* __restrict__ x, float* __restrict__ flag){
  if (threadIdx.x == 0 && blockIdx.x == 0){
    const float* xf = (const float*)x;
    const bf16*  xb = (const bf16*)x;
    double sF = 0.0, sB = 0.0;
    for (int i = 0; i < 512; i++){ float v = fabsf(xf[i]);     if (!(v < 1e30f)) v = 1e30f; sF += v; }
    for (int i = 0; i < 1024; i++){ float v = fabsf(b2f(xb[i])); if (!(v < 1e30f)) v = 1e30f; sB += v; }
    float mF = (float)(sF/512.0), mB = (float)(sB/1024.0);
    float dF = fabsf(logf(fmaxf(mF, 1e-30f)));
    float dB = fabsf(logf(fmaxf(mB, 1e-30f)));
    *flag = (dB <= dF) ? 1.0f : 0.0f;
  }
}

// ---------------- input -> fp32 convert (proven) ----------------
__global__ void cvt_k(const void* __restrict__ in, float* __restrict__ out, int n,
                      const float* __restrict__ flagp){
  bool bf = *flagp > 0.5f;
  int i = blockIdx.x*blockDim.x + threadIdx.x;
  if (i < n) out[i] = rdv(in, i, bf);
}

// ---------------- LayerNorm over channels, per pixel (proven) ----------------
__global__ void ln2d_k(const float* __restrict__ x, const void* __restrict__ g,
                       const void* __restrict__ b, float* __restrict__ y,
                       int C, int HW, const float* __restrict__ flagp){
  bool bf = *flagp > 0.5f;
  int p  = blockIdx.x*blockDim.x + threadIdx.x;
  int bb = blockIdx.y;
  if (p >= HW) return;
  const float* xb = x + (size_t)bb*C*HW + p;
  float s = 0.f, s2 = 0.f;
  for (int c = 0; c < C; c++){ float v = xb[(size_t)c*HW]; s += v; s2 += v*v; }
  float mu  = s  / (float)C;
  float var = fmaxf(s2 / (float)C - mu*mu, 0.f);
  float inv = rsqrtf(var + 1e-5f);
  float* yb = y + (size_t)bb*C*HW + p;
  for (int c = 0; c < C; c++){
    yb[(size_t)c*HW] = (xb[(size_t)c*HW] - mu)*inv*rdv(g,c,bf) + rdv(b,c,bf);
  }
}

// ---------------- generic scalar 1x1 conv (proven; small NP cases) ----------------
__global__ void conv1x1_k(const float* __restrict__ in1, long in1_bs, int C1,
                          const float* __restrict__ in2, long in2_bs, int C2,
                          const void* __restrict__ w, const void* __restrict__ bias,
                          const float* __restrict__ res,
                          void* __restrict__ out, int to_out, int O, int NP, int act,
                          const float* __restrict__ flagp){
  bool bf = *flagp > 0.5f;
  int p = blockIdx.x*blockDim.x + threadIdx.x;
  if (p >= NP) return;
  int o = blockIdx.y, bb = blockIdx.z;
  size_t wrow = (size_t)o*(C1 + C2);
  float acc = bias ? rdv(bias, o, bf) : 0.f;
  const float* i1 = in1 + (size_t)bb*in1_bs + p;
  for (int c = 0; c < C1; c++) acc += rdv(w, wrow + c, bf) * i1[(size_t)c*NP];
  if (in2){
    const float* i2 = in2 + (size_t)bb*in2_bs + p;
    for (int c = 0; c < C2; c++) acc += rdv(w, wrow + C1 + c, bf) * i2[(size_t)c*NP];
  }
  if (act == 1) acc = gelu_f(acc);
  if (res) acc += res[((size_t)bb*O + o)*NP + p];
  size_t oi = ((size_t)bb*O + o)*NP + p;
  if (to_out){
    if (bf) ((bf16*)out)[oi] = __float2bfloat16(acc);
    else    ((float*)out)[oi] = acc;
  } else {
    ((float*)out)[oi] = acc;
  }
}

// ---------------- conv, 4 pixels x 4 out-channels per thread (conv1x1p4 lineage, FLAG weights) ----------------
// grid.y = O/4. Each thread: pixels p, p+np4, p+2np4, p+3np4 for out-ch o0..o0+3.
__global__ void convp4o4_k(const float* __restrict__ in1, long in1_bs, int C1,
                           const float* __restrict__ in2, long in2_bs, int C2,
                           const void* __restrict__ w, const void* __restrict__ bias,
                           const float* __restrict__ res,
                           void* __restrict__ out, int to_out, int O, int NP, int act,
                           const float* __restrict__ flagp){
  bool bf = *flagp > 0.5f;
  int np4 = NP >> 2;
  int p = blockIdx.x*blockDim.x + threadIdx.x;
  if (p >= np4) return;
  int o0 = blockIdx.y*4, bb = blockIdx.z;
  int CW = C1 + C2;
  float acc[4][4];
  #pragma unroll
  for (int k = 0; k < 4; k++){
    float b0 = bias ? rdv(bias, o0+k, bf) : 0.f;
    acc[k][0] = b0; acc[k][1] = b0; acc[k][2] = b0; acc[k][3] = b0;
  }
  const float* i1 = in1 + (size_t)bb*in1_bs + p;
  for (int c = 0; c < C1; c++){
    size_t base = (size_t)c*NP;
    float x0 = i1[base], x1 = i1[base + np4], x2 = i1[base + 2*np4], x3 = i1[base + 3*np4];
    #pragma unroll
    for (int k = 0; k < 4; k++){
      float wv = rdv(w, (size_t)(o0+k)*CW + c, bf);
      acc[k][0] += wv*x0; acc[k][1] += wv*x1; acc[k][2] += wv*x2; acc[k][3] += wv*x3;
    }
  }
  if (in2){
    const float* i2 = in2 + (size_t)bb*in2_bs + p;
    for (int c = 0; c < C2; c++){
      size_t base = (size_t)c*NP;
      float x0 = i2[base], x1 = i2[base + np4], x2 = i2[base + 2*np4], x3 = i2[base + 3*np4];
      #pragma unroll
      for (int k = 0; k < 4; k++){
        float wv = rdv(w, (size_t)(o0+k)*CW + C1 + c, bf);
        acc[k][0] += wv*x0; acc[k][1] += wv*x1; acc[k][2] += wv*x2; acc[k][3] += wv*x3;
      }
    }
  }
  #pragma unroll
  for (int k = 0; k < 4; k++){
    size_t oi = ((size_t)bb*O + o0+k)*NP + p;
    #pragma unroll
    for (int j = 0; j < 4; j++){
      float v = acc[k][j];
      if (act == 1) v = gelu_f(v);
      if (res) v += res[oi + (size_t)j*np4];
      if (to_out){
        if (bf) ((bf16*)out)[oi + (size_t)j*np4] = __float2bfloat16(v);
        else    ((float*)out)[oi + (size_t)j*np4] = v;
      } else {
        ((float*)out)[oi + (size_t)j*np4] = v;
      }
    }
  }
}

// ---------------- flat cosine attention: one query/lane, no-max softmax, wave split-K ----------------
// fp32-only (no weight reads). NQ % 64 == 0, NK % 256 == 0, (NK/4) % CT == 0. Local attn: NQ=NK=2304.
__global__ __launch_bounds__(256) void flat_attn_k(
    const float* __restrict__ Q, long qbs, int qoff,
    const float* __restrict__ KV, long kbs, int koff, int voff,
    float* __restrict__ Out, long obs, int NQ, int NK, float scale)
{
  __shared__ __align__(16) float Ks[4*CT*KP];
  __shared__ __align__(16) float Vs[4*CT*KP];
  __shared__ float Kn[4*CT];
  int t = threadIdx.x, lane = t & 63, wv = t >> 6;
  int h = blockIdx.y, bb = blockIdx.z;
  int qi = blockIdx.x*64 + lane;
  float qn[16]; float s = 0.f;
  #pragma unroll
  for (int d = 0; d < 16; d++){
    qn[d] = Q[(size_t)bb*qbs + (size_t)(qoff + h*16 + d)*NQ + qi];
    s += qn[d]*qn[d];
  }
  float inv = scale / fmaxf(sqrtf(s), 1e-12f);
  #pragma unroll
  for (int d = 0; d < 16; d++) qn[d] *= inv;
  float acc[16]; float l = 0.f;
  #pragma unroll
  for (int d = 0; d < 16; d++) acc[d] = 0.f;
  int chunk = NK >> 2;
  const float* kvb = KV + (size_t)bb*kbs;
  for (int t0 = 0; t0 < chunk; t0 += CT){
    for (int i = t; i < 4*CT*16; i += 256){
      int w2 = i >> 10;            // CT*16 = 1024
      int r  = i & 1023;
      int pos = r & 63, d = r >> 6;
      size_t g = (size_t)(h*16 + d)*NK + (size_t)w2*chunk + t0 + pos;
      Ks[w2*CT*KP + pos*KP + d] = kvb[(size_t)koff*NK + g];
      Vs[w2*CT*KP + pos*KP + d] = kvb[(size_t)voff*NK + g];
    }
    __syncthreads();
    {
      float ss = 0.f;
      #pragma unroll
      for (int d = 0; d < 16; d++){ float v = Ks[wv*CT*KP + lane*KP + d]; ss += v*v; }
      Kn[wv*CT + lane] = 1.f / fmaxf(sqrtf(ss), 1e-12f);
    }
    __syncthreads();
    const float* ks = &Ks[wv*CT*KP];
    const float* vs = &Vs[wv*CT*KP];
    const float* kn = &Kn[wv*CT];
    for (int pos = 0; pos < CT; pos++){
      float4 a  = *(const float4*)&ks[pos*KP];
      float4 b4 = *(const float4*)&ks[pos*KP + 4];
      float4 c4 = *(const float4*)&ks[pos*KP + 8];
      float4 d4 = *(const float4*)&ks[pos*KP + 12];
      float dot = qn[0]*a.x  + qn[1]*a.y  + qn[2]*a.z  + qn[3]*a.w
                + qn[4]*b4.x + qn[5]*b4.y + qn[6]*b4.z + qn[7]*b4.w
                + qn[8]*c4.x + qn[9]*c4.y + qn[10]*c4.z+ qn[11]*c4.w
                + qn[12]*d4.x+ qn[13]*d4.y+ qn[14]*d4.z+ qn[15]*d4.w;
      float pp = __expf(dot * kn[pos]);   // |logit| <= scale: no max needed
      l += pp;
      float4 va = *(const float4*)&vs[pos*KP];
      float4 vb = *(const float4*)&vs[pos*KP + 4];
      float4 vc = *(const float4*)&vs[pos*KP + 8];
      float4 vd = *(const float4*)&vs[pos*KP + 12];
      acc[0] += pp*va.x; acc[1] += pp*va.y; acc[2] += pp*va.z; acc[3] += pp*va.w;
      acc[4] += pp*vb.x; acc[5] += pp*vb.y; acc[6] += pp*vb.z; acc[7] += pp*vb.w;
      acc[8] += pp*vc.x; acc[9] += pp*vc.y; acc[10]+= pp*vc.z; acc[11]+= pp*vc.w;
      acc[12]+= pp*vd.x; acc[13]+= pp*vd.y; acc[14]+= pp*vd.z; acc[15]+= pp*vd.w;
    }
    __syncthreads();
  }
  // combine 4 wave-partials through LDS (reuse Ks; max index 4351 < 5120)
  #pragma unroll
  for (int d = 0; d < 16; d++) Ks[(wv*64 + lane)*17 + d] = acc[d];
  Ks[(wv*64 + lane)*17 + 16] = l;
  __syncthreads();
  if (wv == 0){
    float lt = 0.f; float at[16];
    #pragma unroll
    for (int d = 0; d < 16; d++) at[d] = 0.f;
    #pragma unroll
    for (int w2 = 0; w2 < 4; w2++){
      const float* ps = &Ks[(w2*64 + lane)*17];
      lt += ps[16];
      #pragma unroll
      for (int d = 0; d < 16; d++) at[d] += ps[d];
    }
    float li = 1.f / fmaxf(lt, 1e-30f);
    #pragma unroll
    for (int d = 0; d < 16; d++)
      Out[(size_t)bb*obs + (size_t)(h*16 + d)*NQ + qi] = at[d]*li;
  }
}

// ---------------- cosine attention (proven; global attn NK=144) ----------------
__global__ void cosattn_k(const float* __restrict__ Q, long qbs, int qoff,
                          const float* __restrict__ KV, long kbs, int koff, int voff,
                          float* __restrict__ Out, long obs,
                          int NQ, int NK, float scale){
  __shared__ float Ks[HD*TK];
  __shared__ float Vs[HD*TK];
  __shared__ float KnI[TK];
  int tid = threadIdx.x;
  int h  = blockIdx.y, bb = blockIdx.z;
  int qi = blockIdx.x*blockDim.x + tid;
  bool qv = qi < NQ;
  float qn[HD], acc[HD];
  float m = -INFINITY, l = 0.f;
  if (qv){
    float s = 0.f;
    #pragma unroll
    for (int d = 0; d < HD; d++){
      qn[d] = Q[(size_t)bb*qbs + (size_t)(qoff + h*HD + d)*NQ + qi];
      s += qn[d]*qn[d];
    }
    float inv = scale / fmaxf(sqrtf(s), 1e-12f);
    #pragma unroll
    for (int d = 0; d < HD; d++){ qn[d] *= inv; acc[d] = 0.f; }
  }
  for (int k0 = 0; k0 < NK; k0 += TK){
    int lim = min(TK, NK - k0);
    for (int i = tid; i < HD*TK; i += blockDim.x){
      int pos = i % TK, d = i / TK;
      if (pos < lim){
        Ks[d*TK + pos] = KV[(size_t)bb*kbs + (size_t)(koff + h*HD + d)*NK + k0 + pos];
        Vs[d*TK + pos] = KV[(size_t)bb*kbs + (size_t)(voff + h*HD + d)*NK + k0 + pos];
      }
    }
    __syncthreads();
    if (tid < lim){
      float s = 0.f;
      #pragma unroll
      for (int d = 0; d < HD; d++){ float v = Ks[d*TK + tid]; s += v*v; }
      KnI[tid] = 1.f / fmaxf(sqrtf(s), 1e-12f);
    }
    __syncthreads();
    if (qv){
      for (int pos = 0; pos < lim; pos++){
        float dot = 0.f;
        #pragma unroll
        for (int d = 0; d < HD; d++) dot += qn[d]*Ks[d*TK + pos];
        float logit = dot * KnI[pos];
        float mn = fmaxf(m, logit);
        float r  = __expf(m - mn);
        float pp = __expf(logit - mn);
        l = l*r + pp;
        #pragma unroll
        for (int d = 0; d < HD; d++) acc[d] = acc[d]*r + pp*Vs[d*TK + pos];
        m = mn;
      }
    }
    __syncthreads();
  }
  if (qv){
    float li = 1.f / fmaxf(l, 1e-30f);
    #pragma unroll
    for (int d = 0; d < HD; d++)
      Out[(size_t)bb*obs + (size_t)(h*HD + d)*NQ + qi] = acc[d]*li;
  }
}

// ---------------- attn4, no-max (proven R13; xw attention NK=16) ----------------
__global__ __launch_bounds__(256) void attn4_k(
    const float* __restrict__ Q, long qbs, int qoff,
    const float* __restrict__ KV, long kbs, int koff, int voff,
    float* __restrict__ Out, long obs, int NQ, int NK, float scale)
{
  __shared__ __align__(16) float Ks[TK*KP];
  __shared__ __align__(16) float Vs[TK*KP];
  __shared__ float KnI[TK];
  int tid = threadIdx.x;
  int sub = tid & 3;
  int h = blockIdx.y, bb = blockIdx.z;
  int qi = blockIdx.x*64 + (tid >> 2);
  bool qv = qi < NQ;
  float qn[4] = {0,0,0,0}, acc[4] = {0,0,0,0};
  float l = 0.f;
  if (qv){
    float s = 0.f;
    #pragma unroll
    for (int j = 0; j < 4; j++){
      qn[j] = Q[(size_t)bb*qbs + (size_t)(qoff + h*16 + sub*4 + j)*NQ + qi];
      s += qn[j]*qn[j];
    }
    s += __shfl_xor(s, 1); s += __shfl_xor(s, 2);
    float inv = scale / fmaxf(sqrtf(s), 1e-12f);
    #pragma unroll
    for (int j = 0; j < 4; j++) qn[j] *= inv;
  }
  for (int k0 = 0; k0 < NK; k0 += TK){
    int lim = min(TK, NK - k0);
    for (int i = tid; i < 16*TK; i += 256){
      int pos = i & (TK-1), d = i >> 7;
      if (pos < lim){
        Ks[pos*KP + d] = KV[(size_t)bb*kbs + (size_t)(koff + h*16 + d)*NK + k0 + pos];
        Vs[pos*KP + d] = KV[(size_t)bb*kbs + (size_t)(voff + h*16 + d)*NK + k0 + pos];
      }
    }
    __syncthreads();
    if (tid < lim){
      float s = 0.f;
      #pragma unroll
      for (int d = 0; d < 16; d++){ float v = Ks[tid*KP + d]; s += v*v; }
      KnI[tid] = 1.f / fmaxf(sqrtf(s), 1e-12f);
    }
    __syncthreads();
    for (int pos = 0; pos < lim; pos++){
      float4 k4 = *(const float4*)&Ks[pos*KP + sub*4];
      float dd = qn[0]*k4.x + qn[1]*k4.y + qn[2]*k4.z + qn[3]*k4.w;
      dd += __shfl_xor(dd, 1); dd += __shfl_xor(dd, 2);
      float pp = __expf(dd * KnI[pos]);
      l += pp;
      float4 v4 = *(const float4*)&Vs[pos*KP + sub*4];
      acc[0] += pp*v4.x;
      acc[1] += pp*v4.y;
      acc[2] += pp*v4.z;
      acc[3] += pp*v4.w;
    }
    __syncthreads();
  }
  if (qv){
    float li = 1.f / fmaxf(l, 1e-30f);
    #pragma unroll
    for (int j = 0; j < 4; j++)
      Out[(size_t)bb*obs + (size_t)(h*16 + sub*4 + j)*NQ + qi] = acc[j]*li;
  }
}

// ---------------- latent-read attention, split-K partials (proven) ----------------
__global__ void latpart_k(const float* __restrict__ ql, const float* __restrict__ kvx,
                          long kbs, float* __restrict__ part, int NK, int S){
  int s = blockIdx.x, h = blockIdx.y, bb = blockIdx.z;
  int q = threadIdx.x;
  if (q >= 16) return;
  float qn[16]; float ss = 0.f;
  #pragma unroll
  for (int d = 0; d < 16; d++){
    qn[d] = ql[(size_t)bb*2048 + (size_t)(h*16+d)*16 + q];
    ss += qn[d]*qn[d];
  }
  float inv = 0.25f / fmaxf(sqrtf(ss), 1e-12f);
  #pragma unroll
  for (int d = 0; d < 16; d++) qn[d] *= inv;
  float m = MINIT, l = 0.f, acc[16];
  #pragma unroll
  for (int d = 0; d < 16; d++) acc[d] = 0.f;
  int chunk = NK / S;
  int k0 = s*chunk, k1 = k0 + chunk;
  const float* kb = kvx + (size_t)bb*kbs;
  for (int pos = k0; pos < k1; pos++){
    float kd[16]; float ks = 0.f;
    #pragma unroll
    for (int d = 0; d < 16; d++){
      kd[d] = kb[(size_t)(h*16+d)*NK + pos];
      ks += kd[d]*kd[d];
    }
    float kin = 1.f / fmaxf(sqrtf(ks), 1e-12f);
    float dot = 0.f;
    #pragma unroll
    for (int d = 0; d < 16; d++) dot += qn[d]*kd[d];
    float logit = dot * kin;
    float mn = fmaxf(m, logit);
    float r  = __expf(m - mn);
    float pp = __expf(logit - mn);
    l = l*r + pp; m = mn;
    #pragma unroll
    for (int d = 0; d < 16; d++)
      acc[d] = acc[d]*r + pp*kb[(size_t)(128 + h*16+d)*NK + pos];
  }
  size_t idx = (size_t)((((bb*8 + h)*16 + q)*S) + s)*18;
  part[idx] = m; part[idx+1] = l;
  #pragma unroll
  for (int d = 0; d < 16; d++) part[idx+2+d] = acc[d];
}

__global__ void latcomb_k(const float* __restrict__ part, float* __restrict__ latr, int S){
  int t = threadIdx.x;
  int q = t & 15, h = (t >> 4) & 7, bb = t >> 7;
  size_t base = (size_t)(((bb*8 + h)*16 + q)*S)*18;
  float M = MINIT;
  for (int s = 0; s < S; s++) M = fmaxf(M, part[base + (size_t)s*18]);
  float L = 0.f, acc[16];
  #pragma unroll
  for (int d = 0; d < 16; d++) acc[d] = 0.f;
  for (int s = 0; s < S; s++){
    const float* ps = part + base + (size_t)s*18;
    float w = __expf(ps[0] - M);
    L += ps[1]*w;
    #pragma unroll
    for (int d = 0; d < 16; d++) acc[d] += ps[2+d]*w;
  }
  float li = 1.f / fmaxf(L, 1e-30f);
  #pragma unroll
  for (int d = 0; d < 16; d++)
    latr[(size_t)bb*2048 + (size_t)(h*16+d)*16 + q] = acc[d]*li;
}

// ---------------- 4x4 mean pool (proven) ----------------
__global__ void pool4_k(const float* __restrict__ xn, float* __restrict__ xc){
  int i = blockIdx.x*blockDim.x + threadIdx.x;
  if (i >= 2*128*144) return;
  int pc = i % 144; int bc = i / 144;
  int hc = pc / 12, wc = pc % 12;
  const float* s = xn + (size_t)bc*2304 + hc*4*48 + wc*4;
  float acc = 0.f;
  #pragma unroll
  for (int r = 0; r < 4; r++)
    #pragma unroll
    for (int c2 = 0; c2 < 4; c2++) acc += s[r*48 + c2];
  xc[i] = acc * 0.0625f;
}

// ---------------- bilinear upsample 12->48 (proven) ----------------
__global__ void ups_k(const float* __restrict__ g, float* __restrict__ out){
  int i = blockIdx.x*blockDim.x + threadIdx.x;
  if (i >= 2*128*2304) return;
  int p = i % 2304; int bc = i / 2304;
  int h = p / 48, w = p % 48;
  float sh = h*0.25f - 0.375f;
  float sw = w*0.25f - 0.375f;
  float fh0 = floorf(sh), fw0 = floorf(sw);
  float fh = sh - fh0, fw = sw - fw0;
  int h0 = (int)fh0, w0 = (int)fw0;
  int h0c = min(11, max(0, h0)),   h1c = min(11, max(0, h0+1));
  int w0c = min(11, max(0, w0)),   w1c = min(11, max(0, w0+1));
  const float* s = g + (size_t)bc*144;
  float v00 = s[h0c*12 + w0c], v01 = s[h0c*12 + w1c];
  float v10 = s[h1c*12 + w0c], v11 = s[h1c*12 + w1c];
  out[i] = (1.f-fh)*((1.f-fw)*v00 + fw*v01) + fh*((1.f-fw)*v10 + fw*v11);
}

extern "C" void kernel_launch(void* const* d_in, const int* in_sizes, int n_in,
                              void* d_out, int out_size, void* d_ws, size_t ws_size,
                              hipStream_t stream){
  const int B = 2, C = 128, HW = 2304;
  const void* x_in        = d_in[0];
  const void* g1          = d_in[1];
  const void* b1          = d_in[2];
  const void* loc_qkv_w   = d_in[3];
  const void* loc_proj_w  = d_in[4];
  const void* loc_proj_b  = d_in[5];
  const void* glob_qkv_w  = d_in[6];
  const void* glob_proj_w = d_in[7];
  const void* glob_proj_b = d_in[8];
  const void* fuse_w1     = d_in[9];
  const void* fuse_b1     = d_in[10];
  const void* fuse_w2     = d_in[11];
  const void* fuse_b2     = d_in[12];
  const void* glat        = d_in[13];
  const void* blat        = d_in[14];
  const void* latents     = d_in[15];
  const void* qlat_w      = d_in[16];
  const void* kvx_w       = d_in[17];
  const void* qx_w        = d_in[18];
  const void* kvlat_w     = d_in[19];
  const void* lat_proj_w  = d_in[20];
  const void* lat_proj_b  = d_in[21];
  const void* g2          = d_in[22];
  const void* b2          = d_in[23];
  const void* ffn_w1      = d_in[24];
  const void* ffn_b1      = d_in[25];
  const void* ffn_w2      = d_in[26];
  const void* ffn_b2      = d_in[27];

  // ---- R8/R12/R13 workspace layout VERBATIM ----
  float* ws = (float*)d_ws;
  float* P  = ws + 0;
  float* N  = ws + 589824;
  float* A  = ws + 1179648;
  float* Q  = ws + 1769472;
  float* FLAG = ws + 4128768;

  float* qkv   = Q;                 // 1,769,472
  float* L     = Q + 1769472;       // 589,824
  float* xc    = Q;
  float* qkvc  = Q + 36864;
  float* gatt  = Q + 147456;
  float* gproj = Q + 184320;
  float* kvx   = Q;                 // 1,179,648
  float* latf  = Q + 1179648;
  float* qlat  = Q + 1181696;
  float* latr  = Q + 1185792;
  float* kvlat = Q + 1189888;
  float* part  = Q + 1198080;       // 73,728 (S=16)
  float* ffh   = Q;                 // 2,359,296

  dim3 blk(256);

  detect_k<<<1, 64, 0, stream>>>(x_in, FLAG);
  cvt_k<<<2304, blk, 0, stream>>>(x_in, P, 589824, FLAG);

  // ---- BioAttentionFusion branch ----
  ln2d_k<<<dim3(9,B), blk, 0, stream>>>(P, g1, b1, N, C, HW, FLAG);
  convp4o4_k<<<dim3(3,96,B), blk, 0, stream>>>(N,(long)C*HW,C, nullptr,0,0, loc_qkv_w,nullptr,nullptr, qkv,0,384,HW,0, FLAG);
  flat_attn_k<<<dim3(36,8,B), blk, 0, stream>>>(qkv,(long)384*HW,0, qkv,(long)384*HW,128,256, A,(long)C*HW, HW,HW,0.25f);
  convp4o4_k<<<dim3(3,32,B), blk, 0, stream>>>(A,(long)C*HW,C, nullptr,0,0, loc_proj_w,loc_proj_b,nullptr, L,0,C,HW,0, FLAG);
  pool4_k<<<144, blk, 0, stream>>>(N, xc);
  conv1x1_k<<<dim3(1,384,B), blk, 0, stream>>>(xc,(long)C*144,C, nullptr,0,0, glob_qkv_w,nullptr,nullptr, qkvc,0,384,144,0, FLAG);
  cosattn_k<<<dim3(1,8,B), blk, 0, stream>>>(qkvc,(long)384*144,0, qkvc,(long)384*144,128,256, gatt,(long)C*144, 144,144,0.25f);
  conv1x1_k<<<dim3(1,128,B), blk, 0, stream>>>(gatt,(long)C*144,C, nullptr,0,0, glob_proj_w,glob_proj_b,nullptr, gproj,0,C,144,0, FLAG);
  ups_k<<<2304, blk, 0, stream>>>(gproj, A);                                          // A = upsampled global
  convp4o4_k<<<dim3(3,32,B), blk, 0, stream>>>(L,(long)C*HW,C, A,(long)C*HW,C, fuse_w1,fuse_b1,nullptr, N,0,C,HW,1, FLAG);  // N = gelu(fuse1)
  convp4o4_k<<<dim3(3,32,B), blk, 0, stream>>>(N,(long)C*HW,C, nullptr,0,0, fuse_w2,fuse_b2,P, P,0,C,HW,0, FLAG);           // P = x + f

  // ---- LatentMixer branch ----
  ln2d_k<<<dim3(9,B), blk, 0, stream>>>(P, glat, blat, N, C, HW, FLAG);
  convp4o4_k<<<dim3(3,64,B), blk, 0, stream>>>(N,(long)C*HW,C, nullptr,0,0, kvx_w,nullptr,nullptr, kvx,0,256,HW,0, FLAG);
  convp4o4_k<<<dim3(3,32,B), blk, 0, stream>>>(N,(long)C*HW,C, nullptr,0,0, qx_w,nullptr,nullptr, A,0,C,HW,0, FLAG);        // A = qx
  cvt_k<<<8, blk, 0, stream>>>(latents, latf, 2048, FLAG);
  conv1x1_k<<<dim3(1,128,B), blk, 0, stream>>>(latf,0L,C, nullptr,0,0, qlat_w,nullptr,nullptr, qlat,0,C,16,0, FLAG);
  latpart_k<<<dim3(16,8,B), 64, 0, stream>>>(qlat, kvx, (long)256*HW, part, HW, 16);
  latcomb_k<<<1, blk, 0, stream>>>(part, latr, 16);
  conv1x1_k<<<dim3(1,256,B), blk, 0, stream>>>(latr,(long)C*16,C, nullptr,0,0, kvlat_w,nullptr,nullptr, kvlat,0,256,16,0, FLAG);
  attn4_k<<<dim3(36,8,B), blk, 0, stream>>>(A,(long)C*HW,0, kvlat,(long)256*16,0,128, N,(long)C*HW, HW,16,0.25f);           // N = xw
  convp4o4_k<<<dim3(3,32,B), blk, 0, stream>>>(N,(long)C*HW,C, nullptr,0,0, lat_proj_w,lat_proj_b,P, P,0,C,HW,0, FLAG);     // P = x2

  // ---- FFN branch ----
  ln2d_k<<<dim3(9,B), blk, 0, stream>>>(P, g2, b2, N, C, HW, FLAG);
  convp4o4_k<<<dim3(3,128,B), blk, 0, stream>>>(N,(long)C*HW,C, nullptr,0,0, ffn_w1,ffn_b1,nullptr, ffh,0,512,HW,1, FLAG);
  convp4o4_k<<<dim3(3,32,B), blk, 0, stream>>>(ffh,(long)512*HW,512, nullptr,0,0, ffn_w2,ffn_b2,P, d_out,1,C,HW,0, FLAG);
}

// Round 15
// 1352.886 us; speedup vs baseline: 2.4996x; 1.0484x over previous
//
#include <hip/hip_runtime.h>
#include <hip/hip_bf16.h>

typedef __hip_bfloat16 bf16;

#define HD 16
#define TK 128
#define KP 20            // attn LDS pitch: 16 dims + 4 pad, keeps float4 16B-aligned
#define CT 64            // flat_attn tile positions per wave-chunk
#define MINIT (-1e30f)

__device__ __forceinline__ float b2f(bf16 v){ return __bfloat162float(v); }
__device__ __forceinline__ float gelu_f(float x){ return 0.5f*x*(1.0f+erff(x*0.70710678118654752f)); }
__device__ __forceinline__ float rdv(const void* p, size_t i, bool bf){
  return bf ? b2f(((const bf16*)p)[i]) : ((const float*)p)[i];
}

// ---------------- dtype detector (proven) ----------------
__global__ void detect_k(const void* __restrict__ x, float* __restrict__ flag){
  if (threadIdx.x == 0 && blockIdx.x == 0){
    const float* xf = (const float*)x;
    const bf16*  xb = (const bf16*)x;
    double sF = 0.0, sB = 0.0;
    for (int i = 0; i < 512; i++){ float v = fabsf(xf[i]);     if (!(v < 1e30f)) v = 1e30f; sF += v; }
    for (int i = 0; i < 1024; i++){ float v = fabsf(b2f(xb[i])); if (!(v < 1e30f)) v = 1e30f; sB += v; }
    float mF = (float)(sF/512.0), mB = (float)(sB/1024.0);
    float dF = fabsf(logf(fmaxf(mF, 1e-30f)));
    float dB = fabsf(logf(fmaxf(mB, 1e-30f)));
    *flag = (dB <= dF) ? 1.0f : 0.0f;
  }
}

// ---------------- input -> fp32 convert (proven) ----------------
__global__ void cvt_k(const void* __restrict__ in, float* __restrict__ out, int n,
                      const float* __restrict__ flagp){
  bool bf = *flagp > 0.5f;
  int i = blockIdx.x*blockDim.x + threadIdx.x;
  if (i < n) out[i] = rdv(in, i, bf);
}

// ---------------- LayerNorm over channels, per pixel (proven) ----------------
__global__ void ln2d_k(const float* __restrict__ x, const void* __restrict__ g,
                       const void* __restrict__ b, float* __restrict__ y,
                       int C, int HW, const float* __restrict__ flagp){
  bool bf = *flagp > 0.5f;
  int p  = blockIdx.x*blockDim.x + threadIdx.x;
  int bb = blockIdx.y;
  if (p >= HW) return;
  const float* xb = x + (size_t)bb*C*HW + p;
  float s = 0.f, s2 = 0.f;
  for (int c = 0; c < C; c++){ float v = xb[(size_t)c*HW]; s += v; s2 += v*v; }
  float mu  = s  / (float)C;
  float var = fmaxf(s2 / (float)C - mu*mu, 0.f);
  float inv = rsqrtf(var + 1e-5f);
  float* yb = y + (size_t)bb*C*HW + p;
  for (int c = 0; c < C; c++){
    yb[(size_t)c*HW] = (xb[(size_t)c*HW] - mu)*inv*rdv(g,c,bf) + rdv(b,c,bf);
  }
}

// ---------------- generic scalar 1x1 conv (proven; small NP cases) ----------------
__global__ void conv1x1_k(const float* __restrict__ in1, long in1_bs, int C1,
                          const float* __restrict__ in2, long in2_bs, int C2,
                          const void* __restrict__ w, const void* __restrict__ bias,
                          const float* __restrict__ res,
                          void* __restrict__ out, int to_out, int O, int NP, int act,
                          const float* __restrict__ flagp){
  bool bf = *flagp > 0.5f;
  int p = blockIdx.x*blockDim.x + threadIdx.x;
  if (p >= NP) return;
  int o = blockIdx.y, bb = blockIdx.z;
  size_t wrow = (size_t)o*(C1 + C2);
  float acc = bias ? rdv(bias, o, bf) : 0.f;
  const float* i1 = in1 + (size_t)bb*in1_bs + p;
  for (int c = 0; c < C1; c++) acc += rdv(w, wrow + c, bf) * i1[(size_t)c*NP];
  if (in2){
    const float* i2 = in2 + (size_t)bb*in2_bs + p;
    for (int c = 0; c < C2; c++) acc += rdv(w, wrow + C1 + c, bf) * i2[(size_t)c*NP];
  }
  if (act == 1) acc = gelu_f(acc);
  if (res) acc += res[((size_t)bb*O + o)*NP + p];
  size_t oi = ((size_t)bb*O + o)*NP + p;
  if (to_out){
    if (bf) ((bf16*)out)[oi] = __float2bfloat16(acc);
    else    ((float*)out)[oi] = acc;
  } else {
    ((float*)out)[oi] = acc;
  }
}

// ---------------- conv1x1 clone, 4 pixels per thread (proven R12/R13) ----------------
__global__ void conv1x1p4_k(const float* __restrict__ in1, long in1_bs, int C1,
                            const float* __restrict__ in2, long in2_bs, int C2,
                            const void* __restrict__ w, const void* __restrict__ bias,
                            const float* __restrict__ res,
                            void* __restrict__ out, int to_out, int O, int NP, int act,
                            const float* __restrict__ flagp){
  bool bf = *flagp > 0.5f;
  int np4 = NP >> 2;
  int p = blockIdx.x*blockDim.x + threadIdx.x;
  if (p >= np4) return;
  int o = blockIdx.y, bb = blockIdx.z;
  size_t wrow = (size_t)o*(C1 + C2);
  float b0 = bias ? rdv(bias, o, bf) : 0.f;
  float a0 = b0, a1 = b0, a2 = b0, a3 = b0;
  const float* i1 = in1 + (size_t)bb*in1_bs + p;
  for (int c = 0; c < C1; c++){
    float wv = rdv(w, wrow + c, bf);
    size_t base = (size_t)c*NP;
    a0 += wv * i1[base];
    a1 += wv * i1[base + np4];
    a2 += wv * i1[base + 2*np4];
    a3 += wv * i1[base + 3*np4];
  }
  if (in2){
    const float* i2 = in2 + (size_t)bb*in2_bs + p;
    for (int c = 0; c < C2; c++){
      float wv = rdv(w, wrow + C1 + c, bf);
      size_t base = (size_t)c*NP;
      a0 += wv * i2[base];
      a1 += wv * i2[base + np4];
      a2 += wv * i2[base + 2*np4];
      a3 += wv * i2[base + 3*np4];
    }
  }
  if (act == 1){ a0 = gelu_f(a0); a1 = gelu_f(a1); a2 = gelu_f(a2); a3 = gelu_f(a3); }
  size_t oi = ((size_t)bb*O + o)*NP + p;
  if (res){
    a0 += res[oi];
    a1 += res[oi + np4];
    a2 += res[oi + 2*np4];
    a3 += res[oi + 3*np4];
  }
  if (to_out){
    if (bf){
      ((bf16*)out)[oi]         = __float2bfloat16(a0);
      ((bf16*)out)[oi + np4]   = __float2bfloat16(a1);
      ((bf16*)out)[oi + 2*np4] = __float2bfloat16(a2);
      ((bf16*)out)[oi + 3*np4] = __float2bfloat16(a3);
    } else {
      ((float*)out)[oi]         = a0;
      ((float*)out)[oi + np4]   = a1;
      ((float*)out)[oi + 2*np4] = a2;
      ((float*)out)[oi + 3*np4] = a3;
    }
  } else {
    ((float*)out)[oi]         = a0;
    ((float*)out)[oi + np4]   = a1;
    ((float*)out)[oi + 2*np4] = a2;
    ((float*)out)[oi + 3*np4] = a3;
  }
}

// ---------------- flat cosine attention (proven R14; local attn) ----------------
__global__ __launch_bounds__(256) void flat_attn_k(
    const float* __restrict__ Q, long qbs, int qoff,
    const float* __restrict__ KV, long kbs, int koff, int voff,
    float* __restrict__ Out, long obs, int NQ, int NK, float scale)
{
  __shared__ __align__(16) float Ks[4*CT*KP];
  __shared__ __align__(16) float Vs[4*CT*KP];
  __shared__ float Kn[4*CT];
  int t = threadIdx.x, lane = t & 63, wv = t >> 6;
  int h = blockIdx.y, bb = blockIdx.z;
  int qi = blockIdx.x*64 + lane;
  float qn[16]; float s = 0.f;
  #pragma unroll
  for (int d = 0; d < 16; d++){
    qn[d] = Q[(size_t)bb*qbs + (size_t)(qoff + h*16 + d)*NQ + qi];
    s += qn[d]*qn[d];
  }
  float inv = scale / fmaxf(sqrtf(s), 1e-12f);
  #pragma unroll
  for (int d = 0; d < 16; d++) qn[d] *= inv;
  float acc[16]; float l = 0.f;
  #pragma unroll
  for (int d = 0; d < 16; d++) acc[d] = 0.f;
  int chunk = NK >> 2;
  const float* kvb = KV + (size_t)bb*kbs;
  for (int t0 = 0; t0 < chunk; t0 += CT){
    for (int i = t; i < 4*CT*16; i += 256){
      int w2 = i >> 10;
      int r  = i & 1023;
      int pos = r & 63, d = r >> 6;
      size_t g = (size_t)(h*16 + d)*NK + (size_t)w2*chunk + t0 + pos;
      Ks[w2*CT*KP + pos*KP + d] = kvb[(size_t)koff*NK + g];
      Vs[w2*CT*KP + pos*KP + d] = kvb[(size_t)voff*NK + g];
    }
    __syncthreads();
    {
      float ss = 0.f;
      #pragma unroll
      for (int d = 0; d < 16; d++){ float v = Ks[wv*CT*KP + lane*KP + d]; ss += v*v; }
      Kn[wv*CT + lane] = 1.f / fmaxf(sqrtf(ss), 1e-12f);
    }
    __syncthreads();
    const float* ks = &Ks[wv*CT*KP];
    const float* vs = &Vs[wv*CT*KP];
    const float* kn = &Kn[wv*CT];
    for (int pos = 0; pos < CT; pos++){
      float4 a  = *(const float4*)&ks[pos*KP];
      float4 b4 = *(const float4*)&ks[pos*KP + 4];
      float4 c4 = *(const float4*)&ks[pos*KP + 8];
      float4 d4 = *(const float4*)&ks[pos*KP + 12];
      float dot = qn[0]*a.x  + qn[1]*a.y  + qn[2]*a.z  + qn[3]*a.w
                + qn[4]*b4.x + qn[5]*b4.y + qn[6]*b4.z + qn[7]*b4.w
                + qn[8]*c4.x + qn[9]*c4.y + qn[10]*c4.z+ qn[11]*c4.w
                + qn[12]*d4.x+ qn[13]*d4.y+ qn[14]*d4.z+ qn[15]*d4.w;
      float pp = __expf(dot * kn[pos]);
      l += pp;
      float4 va = *(const float4*)&vs[pos*KP];
      float4 vb = *(const float4*)&vs[pos*KP + 4];
      float4 vc = *(const float4*)&vs[pos*KP + 8];
      float4 vd = *(const float4*)&vs[pos*KP + 12];
      acc[0] += pp*va.x; acc[1] += pp*va.y; acc[2] += pp*va.z; acc[3] += pp*va.w;
      acc[4] += pp*vb.x; acc[5] += pp*vb.y; acc[6] += pp*vb.z; acc[7] += pp*vb.w;
      acc[8] += pp*vc.x; acc[9] += pp*vc.y; acc[10]+= pp*vc.z; acc[11]+= pp*vc.w;
      acc[12]+= pp*vd.x; acc[13]+= pp*vd.y; acc[14]+= pp*vd.z; acc[15]+= pp*vd.w;
    }
    __syncthreads();
  }
  #pragma unroll
  for (int d = 0; d < 16; d++) Ks[(wv*64 + lane)*17 + d] = acc[d];
  Ks[(wv*64 + lane)*17 + 16] = l;
  __syncthreads();
  if (wv == 0){
    float lt = 0.f; float at[16];
    #pragma unroll
    for (int d = 0; d < 16; d++) at[d] = 0.f;
    #pragma unroll
    for (int w2 = 0; w2 < 4; w2++){
      const float* ps = &Ks[(w2*64 + lane)*17];
      lt += ps[16];
      #pragma unroll
      for (int d = 0; d < 16; d++) at[d] += ps[d];
    }
    float li = 1.f / fmaxf(lt, 1e-30f);
    #pragma unroll
    for (int d = 0; d < 16; d++)
      Out[(size_t)bb*obs + (size_t)(h*16 + d)*NQ + qi] = at[d]*li;
  }
}

// ---------------- cosine attention (proven; global attn NK=144) ----------------
__global__ void cosattn_k(const float* __restrict__ Q, long qbs, int qoff,
                          const float* __restrict__ KV, long kbs, int koff, int voff,
                          float* __restrict__ Out, long obs,
                          int NQ, int NK, float scale){
  __shared__ float Ks[HD*TK];
  __shared__ float Vs[HD*TK];
  __shared__ float KnI[TK];
  int tid = threadIdx.x;
  int h  = blockIdx.y, bb = blockIdx.z;
  int qi = blockIdx.x*blockDim.x + tid;
  bool qv = qi < NQ;
  float qn[HD], acc[HD];
  float m = -INFINITY, l = 0.f;
  if (qv){
    float s = 0.f;
    #pragma unroll
    for (int d = 0; d < HD; d++){
      qn[d] = Q[(size_t)bb*qbs + (size_t)(qoff + h*HD + d)*NQ + qi];
      s += qn[d]*qn[d];
    }
    float inv = scale / fmaxf(sqrtf(s), 1e-12f);
    #pragma unroll
    for (int d = 0; d < HD; d++){ qn[d] *= inv; acc[d] = 0.f; }
  }
  for (int k0 = 0; k0 < NK; k0 += TK){
    int lim = min(TK, NK - k0);
    for (int i = tid; i < HD*TK; i += blockDim.x){
      int pos = i % TK, d = i / TK;
      if (pos < lim){
        Ks[d*TK + pos] = KV[(size_t)bb*kbs + (size_t)(koff + h*HD + d)*NK + k0 + pos];
        Vs[d*TK + pos] = KV[(size_t)bb*kbs + (size_t)(voff + h*HD + d)*NK + k0 + pos];
      }
    }
    __syncthreads();
    if (tid < lim){
      float s = 0.f;
      #pragma unroll
      for (int d = 0; d < HD; d++){ float v = Ks[d*TK + tid]; s += v*v; }
      KnI[tid] = 1.f / fmaxf(sqrtf(s), 1e-12f);
    }
    __syncthreads();
    if (qv){
      for (int pos = 0; pos < lim; pos++){
        float dot = 0.f;
        #pragma unroll
        for (int d = 0; d < HD; d++) dot += qn[d]*Ks[d*TK + pos];
        float logit = dot * KnI[pos];
        float mn = fmaxf(m, logit);
        float r  = __expf(m - mn);
        float pp = __expf(logit - mn);
        l = l*r + pp;
        #pragma unroll
        for (int d = 0; d < HD; d++) acc[d] = acc[d]*r + pp*Vs[d*TK + pos];
        m = mn;
      }
    }
    __syncthreads();
  }
  if (qv){
    float li = 1.f / fmaxf(l, 1e-30f);
    #pragma unroll
    for (int d = 0; d < HD; d++)
      Out[(size_t)bb*obs + (size_t)(h*HD + d)*NQ + qi] = acc[d]*li;
  }
}

// ---------------- attn4, no-max (proven R13/R14; xw attention NK=16) ----------------
__global__ __launch_bounds__(256) void attn4_k(
    const float* __restrict__ Q, long qbs, int qoff,
    const float* __restrict__ KV, long kbs, int koff, int voff,
    float* __restrict__ Out, long obs, int NQ, int NK, float scale)
{
  __shared__ __align__(16) float Ks[TK*KP];
  __shared__ __align__(16) float Vs[TK*KP];
  __shared__ float KnI[TK];
  int tid = threadIdx.x;
  int sub = tid & 3;
  int h = blockIdx.y, bb = blockIdx.z;
  int qi = blockIdx.x*64 + (tid >> 2);
  bool qv = qi < NQ;
  float qn[4] = {0,0,0,0}, acc[4] = {0,0,0,0};
  float l = 0.f;
  if (qv){
    float s = 0.f;
    #pragma unroll
    for (int j = 0; j < 4; j++){
      qn[j] = Q[(size_t)bb*qbs + (size_t)(qoff + h*16 + sub*4 + j)*NQ + qi];
      s += qn[j]*qn[j];
    }
    s += __shfl_xor(s, 1); s += __shfl_xor(s, 2);
    float inv = scale / fmaxf(sqrtf(s), 1e-12f);
    #pragma unroll
    for (int j = 0; j < 4; j++) qn[j] *= inv;
  }
  for (int k0 = 0; k0 < NK; k0 += TK){
    int lim = min(TK, NK - k0);
    for (int i = tid; i < 16*TK; i += 256){
      int pos = i & (TK-1), d = i >> 7;
      if (pos < lim){
        Ks[pos*KP + d] = KV[(size_t)bb*kbs + (size_t)(koff + h*16 + d)*NK + k0 + pos];
        Vs[pos*KP + d] = KV[(size_t)bb*kbs + (size_t)(voff + h*16 + d)*NK + k0 + pos];
      }
    }
    __syncthreads();
    if (tid < lim){
      float s = 0.f;
      #pragma unroll
      for (int d = 0; d < 16; d++){ float v = Ks[tid*KP + d]; s += v*v; }
      KnI[tid] = 1.f / fmaxf(sqrtf(s), 1e-12f);
    }
    __syncthreads();
    for (int pos = 0; pos < lim; pos++){
      float4 k4 = *(const float4*)&Ks[pos*KP + sub*4];
      float dd = qn[0]*k4.x + qn[1]*k4.y + qn[2]*k4.z + qn[3]*k4.w;
      dd += __shfl_xor(dd, 1); dd += __shfl_xor(dd, 2);
      float pp = __expf(dd * KnI[pos]);
      l += pp;
      float4 v4 = *(const float4*)&Vs[pos*KP + sub*4];
      acc[0] += pp*v4.x;
      acc[1] += pp*v4.y;
      acc[2] += pp*v4.z;
      acc[3] += pp*v4.w;
    }
    __syncthreads();
  }
  if (qv){
    float li = 1.f / fmaxf(l, 1e-30f);
    #pragma unroll
    for (int j = 0; j < 4; j++)
      Out[(size_t)bb*obs + (size_t)(h*16 + sub*4 + j)*NQ + qi] = acc[j]*li;
  }
}

// ---------------- latent-read attention, split-K partials (proven) ----------------
__global__ void latpart_k(const float* __restrict__ ql, const float* __restrict__ kvx,
                          long kbs, float* __restrict__ part, int NK, int S){
  int s = blockIdx.x, h = blockIdx.y, bb = blockIdx.z;
  int q = threadIdx.x;
  if (q >= 16) return;
  float qn[16]; float ss = 0.f;
  #pragma unroll
  for (int d = 0; d < 16; d++){
    qn[d] = ql[(size_t)bb*2048 + (size_t)(h*16+d)*16 + q];
    ss += qn[d]*qn[d];
  }
  float inv = 0.25f / fmaxf(sqrtf(ss), 1e-12f);
  #pragma unroll
  for (int d = 0; d < 16; d++) qn[d] *= inv;
  float m = MINIT, l = 0.f, acc[16];
  #pragma unroll
  for (int d = 0; d < 16; d++) acc[d] = 0.f;
  int chunk = NK / S;
  int k0 = s*chunk, k1 = k0 + chunk;
  const float* kb = kvx + (size_t)bb*kbs;
  for (int pos = k0; pos < k1; pos++){
    float kd[16]; float ks = 0.f;
    #pragma unroll
    for (int d = 0; d < 16; d++){
      kd[d] = kb[(size_t)(h*16+d)*NK + pos];
      ks += kd[d]*kd[d];
    }
    float kin = 1.f / fmaxf(sqrtf(ks), 1e-12f);
    float dot = 0.f;
    #pragma unroll
    for (int d = 0; d < 16; d++) dot += qn[d]*kd[d];
    float logit = dot * kin;
    float mn = fmaxf(m, logit);
    float r  = __expf(m - mn);
    float pp = __expf(logit - mn);
    l = l*r + pp; m = mn;
    #pragma unroll
    for (int d = 0; d < 16; d++)
      acc[d] = acc[d]*r + pp*kb[(size_t)(128 + h*16+d)*NK + pos];
  }
  size_t idx = (size_t)((((bb*8 + h)*16 + q)*S) + s)*18;
  part[idx] = m; part[idx+1] = l;
  #pragma unroll
  for (int d = 0; d < 16; d++) part[idx+2+d] = acc[d];
}

__global__ void latcomb_k(const float* __restrict__ part, float* __restrict__ latr, int S){
  int t = threadIdx.x;
  int q = t & 15, h = (t >> 4) & 7, bb = t >> 7;
  size_t base = (size_t)(((bb*8 + h)*16 + q)*S)*18;
  float M = MINIT;
  for (int s = 0; s < S; s++) M = fmaxf(M, part[base + (size_t)s*18]);
  float L = 0.f, acc[16];
  #pragma unroll
  for (int d = 0; d < 16; d++) acc[d] = 0.f;
  for (int s = 0; s < S; s++){
    const float* ps = part + base + (size_t)s*18;
    float w = __expf(ps[0] - M);
    L += ps[1]*w;
    #pragma unroll
    for (int d = 0; d < 16; d++) acc[d] += ps[2+d]*w;
  }
  float li = 1.f / fmaxf(L, 1e-30f);
  #pragma unroll
  for (int d = 0; d < 16; d++)
    latr[(size_t)bb*2048 + (size_t)(h*16+d)*16 + q] = acc[d]*li;
}

// ---------------- 4x4 mean pool (proven) ----------------
__global__ void pool4_k(const float* __restrict__ xn, float* __restrict__ xc){
  int i = blockIdx.x*blockDim.x + threadIdx.x;
  if (i >= 2*128*144) return;
  int pc = i % 144; int bc = i / 144;
  int hc = pc / 12, wc = pc % 12;
  const float* s = xn + (size_t)bc*2304 + hc*4*48 + wc*4;
  float acc = 0.f;
  #pragma unroll
  for (int r = 0; r < 4; r++)
    #pragma unroll
    for (int c2 = 0; c2 < 4; c2++) acc += s[r*48 + c2];
  xc[i] = acc * 0.0625f;
}

// ---------------- bilinear upsample 12->48 (proven) ----------------
__global__ void ups_k(const float* __restrict__ g, float* __restrict__ out){
  int i = blockIdx.x*blockDim.x + threadIdx.x;
  if (i >= 2*128*2304) return;
  int p = i % 2304; int bc = i / 2304;
  int h = p / 48, w = p % 48;
  float sh = h*0.25f - 0.375f;
  float sw = w*0.25f - 0.375f;
  float fh0 = floorf(sh), fw0 = floorf(sw);
  float fh = sh - fh0, fw = sw - fw0;
  int h0 = (int)fh0, w0 = (int)fw0;
  int h0c = min(11, max(0, h0)),   h1c = min(11, max(0, h0+1));
  int w0c = min(11, max(0, w0)),   w1c = min(11, max(0, w0+1));
  const float* s = g + (size_t)bc*144;
  float v00 = s[h0c*12 + w0c], v01 = s[h0c*12 + w1c];
  float v10 = s[h1c*12 + w0c], v11 = s[h1c*12 + w1c];
  out[i] = (1.f-fh)*((1.f-fw)*v00 + fw*v01) + fh*((1.f-fw)*v10 + fw*v11);
}

extern "C" void kernel_launch(void* const* d_in, const int* in_sizes, int n_in,
                              void* d_out, int out_size, void* d_ws, size_t ws_size,
                              hipStream_t stream){
  const int B = 2, C = 128, HW = 2304;
  const void* x_in        = d_in[0];
  const void* g1          = d_in[1];
  const void* b1          = d_in[2];
  const void* loc_qkv_w   = d_in[3];
  const void* loc_proj_w  = d_in[4];
  const void* loc_proj_b  = d_in[5];
  const void* glob_qkv_w  = d_in[6];
  const void* glob_proj_w = d_in[7];
  const void* glob_proj_b = d_in[8];
  const void* fuse_w1     = d_in[9];
  const void* fuse_b1     = d_in[10];
  const void* fuse_w2     = d_in[11];
  const void* fuse_b2     = d_in[12];
  const void* glat        = d_in[13];
  const void* blat        = d_in[14];
  const void* latents     = d_in[15];
  const void* qlat_w      = d_in[16];
  const void* kvx_w       = d_in[17];
  const void* qx_w        = d_in[18];
  const void* kvlat_w     = d_in[19];
  const void* lat_proj_w  = d_in[20];
  const void* lat_proj_b  = d_in[21];
  const void* g2          = d_in[22];
  const void* b2          = d_in[23];
  const void* ffn_w1      = d_in[24];
  const void* ffn_b1      = d_in[25];
  const void* ffn_w2      = d_in[26];
  const void* ffn_b2      = d_in[27];

  // ---- R8/R12/R13/R14 workspace layout VERBATIM ----
  float* ws = (float*)d_ws;
  float* P  = ws + 0;
  float* N  = ws + 589824;
  float* A  = ws + 1179648;
  float* Q  = ws + 1769472;
  float* FLAG = ws + 4128768;

  float* qkv   = Q;                 // 1,769,472
  float* L     = Q + 1769472;       // 589,824
  float* xc    = Q;
  float* qkvc  = Q + 36864;
  float* gatt  = Q + 147456;
  float* gproj = Q + 184320;
  float* kvx   = Q;                 // 1,179,648
  float* latf  = Q + 1179648;
  float* qlat  = Q + 1181696;
  float* latr  = Q + 1185792;
  float* kvlat = Q + 1189888;
  float* part  = Q + 1198080;       // 73,728 (S=16)
  float* ffh   = Q;                 // 2,359,296

  dim3 blk(256);

  detect_k<<<1, 64, 0, stream>>>(x_in, FLAG);
  cvt_k<<<2304, blk, 0, stream>>>(x_in, P, 589824, FLAG);

  // ---- BioAttentionFusion branch ----
  ln2d_k<<<dim3(9,B), blk, 0, stream>>>(P, g1, b1, N, C, HW, FLAG);
  conv1x1p4_k<<<dim3(3,384,B), blk, 0, stream>>>(N,(long)C*HW,C, nullptr,0,0, loc_qkv_w,nullptr,nullptr, qkv,0,384,HW,0, FLAG);
  flat_attn_k<<<dim3(36,8,B), blk, 0, stream>>>(qkv,(long)384*HW,0, qkv,(long)384*HW,128,256, A,(long)C*HW, HW,HW,0.25f);
  conv1x1p4_k<<<dim3(3,128,B), blk, 0, stream>>>(A,(long)C*HW,C, nullptr,0,0, loc_proj_w,loc_proj_b,nullptr, L,0,C,HW,0, FLAG);
  pool4_k<<<144, blk, 0, stream>>>(N, xc);
  conv1x1_k<<<dim3(1,384,B), blk, 0, stream>>>(xc,(long)C*144,C, nullptr,0,0, glob_qkv_w,nullptr,nullptr, qkvc,0,384,144,0, FLAG);
  cosattn_k<<<dim3(1,8,B), blk, 0, stream>>>(qkvc,(long)384*144,0, qkvc,(long)384*144,128,256, gatt,(long)C*144, 144,144,0.25f);
  conv1x1_k<<<dim3(1,128,B), blk, 0, stream>>>(gatt,(long)C*144,C, nullptr,0,0, glob_proj_w,glob_proj_b,nullptr, gproj,0,C,144,0, FLAG);
  ups_k<<<2304, blk, 0, stream>>>(gproj, A);                                          // A = upsampled global
  conv1x1p4_k<<<dim3(3,128,B), blk, 0, stream>>>(L,(long)C*HW,C, A,(long)C*HW,C, fuse_w1,fuse_b1,nullptr, N,0,C,HW,1, FLAG);  // N = gelu(fuse1)
  conv1x1p4_k<<<dim3(3,128,B), blk, 0, stream>>>(N,(long)C*HW,C, nullptr,0,0, fuse_w2,fuse_b2,P, P,0,C,HW,0, FLAG);           // P = x + f

  // ---- LatentMixer branch ----
  ln2d_k<<<dim3(9,B), blk, 0, stream>>>(P, glat, blat, N, C, HW, FLAG);
  conv1x1p4_k<<<dim3(3,256,B), blk, 0, stream>>>(N,(long)C*HW,C, nullptr,0,0, kvx_w,nullptr,nullptr, kvx,0,256,HW,0, FLAG);
  conv1x1p4_k<<<dim3(3,128,B), blk, 0, stream>>>(N,(long)C*HW,C, nullptr,0,0, qx_w,nullptr,nullptr, A,0,C,HW,0, FLAG);        // A = qx
  cvt_k<<<8, blk, 0, stream>>>(latents, latf, 2048, FLAG);
  conv1x1_k<<<dim3(1,128,B), blk, 0, stream>>>(latf,0L,C, nullptr,0,0, qlat_w,nullptr,nullptr, qlat,0,C,16,0, FLAG);
  latpart_k<<<dim3(16,8,B), 64, 0, stream>>>(qlat, kvx, (long)256*HW, part, HW, 16);
  latcomb_k<<<1, blk, 0, stream>>>(part, latr, 16);
  conv1x1_k<<<dim3(1,256,B), blk, 0, stream>>>(latr,(long)C*16,C, nullptr,0,0, kvlat_w,nullptr,nullptr, kvlat,0,256,16,0, FLAG);
  attn4_k<<<dim3(36,8,B), blk, 0, stream>>>(A,(long)C*HW,0, kvlat,(long)256*16,0,128, N,(long)C*HW, HW,16,0.25f);             // N = xw
  conv1x1p4_k<<<dim3(3,128,B), blk, 0, stream>>>(N,(long)C*HW,C, nullptr,0,0, lat_proj_w,lat_proj_b,P, P,0,C,HW,0, FLAG);     // P = x2

  // ---- FFN branch ----
  ln2d_k<<<dim3(9,B), blk, 0, stream>>>(P, g2, b2, N, C, HW, FLAG);
  conv1x1p4_k<<<dim3(3,512,B), blk, 0, stream>>>(N,(long)C*HW,C, nullptr,0,0, ffn_w1,ffn_b1,nullptr, ffh,0,512,HW,1, FLAG);
  conv1x1p4_k<<<dim3(3,128,B), blk, 0, stream>>>(ffh,(long)512*HW,512, nullptr,0,0, ffn_w2,ffn_b2,P, d_out,1,C,HW,0, FLAG);
}

// Round 16
// 1268.173 us; speedup vs baseline: 2.6666x; 1.0668x over previous
//
#include <hip/hip_runtime.h>
#include <hip/hip_bf16.h>

typedef __hip_bfloat16 bf16;

#define HD 16
#define TK 128
#define KP 20            // attn LDS pitch: 16 dims + 4 pad, keeps float4 16B-aligned
#define CT 64            // flat_attn tile positions per wave-chunk
#define MINIT (-1e30f)

__device__ __forceinline__ float b2f(bf16 v){ return __bfloat162float(v); }
__device__ __forceinline__ float gelu_f(float x){ return 0.5f*x*(1.0f+erff(x*0.70710678118654752f)); }
__device__ __forceinline__ float rdv(const void* p, size_t i, bool bf){
  return bf ? b2f(((const bf16*)p)[i]) : ((const float*)p)[i];
}

// ---------------- dtype detector (proven) ----------------
__global__ void detect_k(const void* __restrict__ x, float* __restrict__ flag){
  if (threadIdx.x == 0 && blockIdx.x == 0){
    const float* xf = (const float*)x;
    const bf16*  xb = (const bf16*)x;
    double sF = 0.0, sB = 0.0;
    for (int i = 0; i < 512; i++){ float v = fabsf(xf[i]);     if (!(v < 1e30f)) v = 1e30f; sF += v; }
    for (int i = 0; i < 1024; i++){ float v = fabsf(b2f(xb[i])); if (!(v < 1e30f)) v = 1e30f; sB += v; }
    float mF = (float)(sF/512.0), mB = (float)(sB/1024.0);
    float dF = fabsf(logf(fmaxf(mF, 1e-30f)));
    float dB = fabsf(logf(fmaxf(mB, 1e-30f)));
    *flag = (dB <= dF) ? 1.0f : 0.0f;
  }
}

// ---------------- input -> fp32 convert (proven) ----------------
__global__ void cvt_k(const void* __restrict__ in, float* __restrict__ out, int n,
                      const float* __restrict__ flagp){
  bool bf = *flagp > 0.5f;
  int i = blockIdx.x*blockDim.x + threadIdx.x;
  if (i < n) out[i] = rdv(in, i, bf);
}

// ---------------- LayerNorm over channels, per pixel (proven) ----------------
__global__ void ln2d_k(const float* __restrict__ x, const void* __restrict__ g,
                       const void* __restrict__ b, float* __restrict__ y,
                       int C, int HW, const float* __restrict__ flagp){
  bool bf = *flagp > 0.5f;
  int p  = blockIdx.x*blockDim.x + threadIdx.x;
  int bb = blockIdx.y;
  if (p >= HW) return;
  const float* xb = x + (size_t)bb*C*HW + p;
  float s = 0.f, s2 = 0.f;
  for (int c = 0; c < C; c++){ float v = xb[(size_t)c*HW]; s += v; s2 += v*v; }
  float mu  = s  / (float)C;
  float var = fmaxf(s2 / (float)C - mu*mu, 0.f);
  float inv = rsqrtf(var + 1e-5f);
  float* yb = y + (size_t)bb*C*HW + p;
  for (int c = 0; c < C; c++){
    yb[(size_t)c*HW] = (xb[(size_t)c*HW] - mu)*inv*rdv(g,c,bf) + rdv(b,c,bf);
  }
}

// ---------------- generic scalar 1x1 conv (proven; small NP cases) ----------------
__global__ void conv1x1_k(const float* __restrict__ in1, long in1_bs, int C1,
                          const float* __restrict__ in2, long in2_bs, int C2,
                          const void* __restrict__ w, const void* __restrict__ bias,
                          const float* __restrict__ res,
                          void* __restrict__ out, int to_out, int O, int NP, int act,
                          const float* __restrict__ flagp){
  bool bf = *flagp > 0.5f;
  int p = blockIdx.x*blockDim.x + threadIdx.x;
  if (p >= NP) return;
  int o = blockIdx.y, bb = blockIdx.z;
  size_t wrow = (size_t)o*(C1 + C2);
  float acc = bias ? rdv(bias, o, bf) : 0.f;
  const float* i1 = in1 + (size_t)bb*in1_bs + p;
  for (int c = 0; c < C1; c++) acc += rdv(w, wrow + c, bf) * i1[(size_t)c*NP];
  if (in2){
    const float* i2 = in2 + (size_t)bb*in2_bs + p;
    for (int c = 0; c < C2; c++) acc += rdv(w, wrow + C1 + c, bf) * i2[(size_t)c*NP];
  }
  if (act == 1) acc = gelu_f(acc);
  if (res) acc += res[((size_t)bb*O + o)*NP + p];
  size_t oi = ((size_t)bb*O + o)*NP + p;
  if (to_out){
    if (bf) ((bf16*)out)[oi] = __float2bfloat16(acc);
    else    ((float*)out)[oi] = acc;
  } else {
    ((float*)out)[oi] = acc;
  }
}

// ---------------- DELTA: conv1x1, 4 consecutive pixels via float4 loads ----------------
// Same structure/args as proven conv1x1p4_k (FLAG weights, grid.y=O); only the
// pixel->thread mapping changed to consecutive so input/res/out move as float4.
__global__ void conv1x1v4_k(const float* __restrict__ in1, long in1_bs, int C1,
                            const float* __restrict__ in2, long in2_bs, int C2,
                            const void* __restrict__ w, const void* __restrict__ bias,
                            const float* __restrict__ res,
                            void* __restrict__ out, int to_out, int O, int NP, int act,
                            const float* __restrict__ flagp){
  bool bf = *flagp > 0.5f;
  int np4 = NP >> 2;
  int p = blockIdx.x*blockDim.x + threadIdx.x;
  if (p >= np4) return;
  int o = blockIdx.y, bb = blockIdx.z;
  size_t wrow = (size_t)o*(C1 + C2);
  float b0 = bias ? rdv(bias, o, bf) : 0.f;
  float a0 = b0, a1 = b0, a2 = b0, a3 = b0;
  const float4* i1 = (const float4*)(in1 + (size_t)bb*in1_bs);
  for (int c = 0; c < C1; c++){
    float wv = rdv(w, wrow + c, bf);
    float4 v = i1[(size_t)c*np4 + p];
    a0 += wv*v.x; a1 += wv*v.y; a2 += wv*v.z; a3 += wv*v.w;
  }
  if (in2){
    const float4* i2 = (const float4*)(in2 + (size_t)bb*in2_bs);
    for (int c = 0; c < C2; c++){
      float wv = rdv(w, wrow + C1 + c, bf);
      float4 v = i2[(size_t)c*np4 + p];
      a0 += wv*v.x; a1 += wv*v.y; a2 += wv*v.z; a3 += wv*v.w;
    }
  }
  if (act == 1){ a0 = gelu_f(a0); a1 = gelu_f(a1); a2 = gelu_f(a2); a3 = gelu_f(a3); }
  size_t orow = ((size_t)bb*O + o)*np4 + p;     // float4 index
  if (res){
    float4 r = ((const float4*)res)[orow];
    a0 += r.x; a1 += r.y; a2 += r.z; a3 += r.w;
  }
  if (to_out && bf){
    bf16* ob = (bf16*)out + orow*4;
    ob[0] = __float2bfloat16(a0); ob[1] = __float2bfloat16(a1);
    ob[2] = __float2bfloat16(a2); ob[3] = __float2bfloat16(a3);
  } else {
    float4 v; v.x = a0; v.y = a1; v.z = a2; v.w = a3;
    ((float4*)out)[orow] = v;
  }
}

// ---------------- flat cosine attention (proven R14/R15; local attn) ----------------
__global__ __launch_bounds__(256) void flat_attn_k(
    const float* __restrict__ Q, long qbs, int qoff,
    const float* __restrict__ KV, long kbs, int koff, int voff,
    float* __restrict__ Out, long obs, int NQ, int NK, float scale)
{
  __shared__ __align__(16) float Ks[4*CT*KP];
  __shared__ __align__(16) float Vs[4*CT*KP];
  __shared__ float Kn[4*CT];
  int t = threadIdx.x, lane = t & 63, wv = t >> 6;
  int h = blockIdx.y, bb = blockIdx.z;
  int qi = blockIdx.x*64 + lane;
  float qn[16]; float s = 0.f;
  #pragma unroll
  for (int d = 0; d < 16; d++){
    qn[d] = Q[(size_t)bb*qbs + (size_t)(qoff + h*16 + d)*NQ + qi];
    s += qn[d]*qn[d];
  }
  float inv = scale / fmaxf(sqrtf(s), 1e-12f);
  #pragma unroll
  for (int d = 0; d < 16; d++) qn[d] *= inv;
  float acc[16]; float l = 0.f;
  #pragma unroll
  for (int d = 0; d < 16; d++) acc[d] = 0.f;
  int chunk = NK >> 2;
  const float* kvb = KV + (size_t)bb*kbs;
  for (int t0 = 0; t0 < chunk; t0 += CT){
    for (int i = t; i < 4*CT*16; i += 256){
      int w2 = i >> 10;
      int r  = i & 1023;
      int pos = r & 63, d = r >> 6;
      size_t g = (size_t)(h*16 + d)*NK + (size_t)w2*chunk + t0 + pos;
      Ks[w2*CT*KP + pos*KP + d] = kvb[(size_t)koff*NK + g];
      Vs[w2*CT*KP + pos*KP + d] = kvb[(size_t)voff*NK + g];
    }
    __syncthreads();
    {
      float ss = 0.f;
      #pragma unroll
      for (int d = 0; d < 16; d++){ float v = Ks[wv*CT*KP + lane*KP + d]; ss += v*v; }
      Kn[wv*CT + lane] = 1.f / fmaxf(sqrtf(ss), 1e-12f);
    }
    __syncthreads();
    const float* ks = &Ks[wv*CT*KP];
    const float* vs = &Vs[wv*CT*KP];
    const float* kn = &Kn[wv*CT];
    for (int pos = 0; pos < CT; pos++){
      float4 a  = *(const float4*)&ks[pos*KP];
      float4 b4 = *(const float4*)&ks[pos*KP + 4];
      float4 c4 = *(const float4*)&ks[pos*KP + 8];
      float4 d4 = *(const float4*)&ks[pos*KP + 12];
      float dot = qn[0]*a.x  + qn[1]*a.y  + qn[2]*a.z  + qn[3]*a.w
                + qn[4]*b4.x + qn[5]*b4.y + qn[6]*b4.z + qn[7]*b4.w
                + qn[8]*c4.x + qn[9]*c4.y + qn[10]*c4.z+ qn[11]*c4.w
                + qn[12]*d4.x+ qn[13]*d4.y+ qn[14]*d4.z+ qn[15]*d4.w;
      float pp = __expf(dot * kn[pos]);
      l += pp;
      float4 va = *(const float4*)&vs[pos*KP];
      float4 vb = *(const float4*)&vs[pos*KP + 4];
      float4 vc = *(const float4*)&vs[pos*KP + 8];
      float4 vd = *(const float4*)&vs[pos*KP + 12];
      acc[0] += pp*va.x; acc[1] += pp*va.y; acc[2] += pp*va.z; acc[3] += pp*va.w;
      acc[4] += pp*vb.x; acc[5] += pp*vb.y; acc[6] += pp*vb.z; acc[7] += pp*vb.w;
      acc[8] += pp*vc.x; acc[9] += pp*vc.y; acc[10]+= pp*vc.z; acc[11]+= pp*vc.w;
      acc[12]+= pp*vd.x; acc[13]+= pp*vd.y; acc[14]+= pp*vd.z; acc[15]+= pp*vd.w;
    }
    __syncthreads();
  }
  #pragma unroll
  for (int d = 0; d < 16; d++) Ks[(wv*64 + lane)*17 + d] = acc[d];
  Ks[(wv*64 + lane)*17 + 16] = l;
  __syncthreads();
  if (wv == 0){
    float lt = 0.f; float at[16];
    #pragma unroll
    for (int d = 0; d < 16; d++) at[d] = 0.f;
    #pragma unroll
    for (int w2 = 0; w2 < 4; w2++){
      const float* ps = &Ks[(w2*64 + lane)*17];
      lt += ps[16];
      #pragma unroll
      for (int d = 0; d < 16; d++) at[d] += ps[d];
    }
    float li = 1.f / fmaxf(lt, 1e-30f);
    #pragma unroll
    for (int d = 0; d < 16; d++)
      Out[(size_t)bb*obs + (size_t)(h*16 + d)*NQ + qi] = at[d]*li;
  }
}

// ---------------- cosine attention (proven; global attn NK=144) ----------------
__global__ void cosattn_k(const float* __restrict__ Q, long qbs, int qoff,
                          const float* __restrict__ KV, long kbs, int koff, int voff,
                          float* __restrict__ Out, long obs,
                          int NQ, int NK, float scale){
  __shared__ float Ks[HD*TK];
  __shared__ float Vs[HD*TK];
  __shared__ float KnI[TK];
  int tid = threadIdx.x;
  int h  = blockIdx.y, bb = blockIdx.z;
  int qi = blockIdx.x*blockDim.x + tid;
  bool qv = qi < NQ;
  float qn[HD], acc[HD];
  float m = -INFINITY, l = 0.f;
  if (qv){
    float s = 0.f;
    #pragma unroll
    for (int d = 0; d < HD; d++){
      qn[d] = Q[(size_t)bb*qbs + (size_t)(qoff + h*HD + d)*NQ + qi];
      s += qn[d]*qn[d];
    }
    float inv = scale / fmaxf(sqrtf(s), 1e-12f);
    #pragma unroll
    for (int d = 0; d < HD; d++){ qn[d] *= inv; acc[d] = 0.f; }
  }
  for (int k0 = 0; k0 < NK; k0 += TK){
    int lim = min(TK, NK - k0);
    for (int i = tid; i < HD*TK; i += blockDim.x){
      int pos = i % TK, d = i / TK;
      if (pos < lim){
        Ks[d*TK + pos] = KV[(size_t)bb*kbs + (size_t)(koff + h*HD + d)*NK + k0 + pos];
        Vs[d*TK + pos] = KV[(size_t)bb*kbs + (size_t)(voff + h*HD + d)*NK + k0 + pos];
      }
    }
    __syncthreads();
    if (tid < lim){
      float s = 0.f;
      #pragma unroll
      for (int d = 0; d < HD; d++){ float v = Ks[d*TK + tid]; s += v*v; }
      KnI[tid] = 1.f / fmaxf(sqrtf(s), 1e-12f);
    }
    __syncthreads();
    if (qv){
      for (int pos = 0; pos < lim; pos++){
        float dot = 0.f;
        #pragma unroll
        for (int d = 0; d < HD; d++) dot += qn[d]*Ks[d*TK + pos];
        float logit = dot * KnI[pos];
        float mn = fmaxf(m, logit);
        float r  = __expf(m - mn);
        float pp = __expf(logit - mn);
        l = l*r + pp;
        #pragma unroll
        for (int d = 0; d < HD; d++) acc[d] = acc[d]*r + pp*Vs[d*TK + pos];
        m = mn;
      }
    }
    __syncthreads();
  }
  if (qv){
    float li = 1.f / fmaxf(l, 1e-30f);
    #pragma unroll
    for (int d = 0; d < HD; d++)
      Out[(size_t)bb*obs + (size_t)(h*HD + d)*NQ + qi] = acc[d]*li;
  }
}

// ---------------- attn4, no-max (proven; xw attention NK=16) ----------------
__global__ __launch_bounds__(256) void attn4_k(
    const float* __restrict__ Q, long qbs, int qoff,
    const float* __restrict__ KV, long kbs, int koff, int voff,
    float* __restrict__ Out, long obs, int NQ, int NK, float scale)
{
  __shared__ __align__(16) float Ks[TK*KP];
  __shared__ __align__(16) float Vs[TK*KP];
  __shared__ float KnI[TK];
  int tid = threadIdx.x;
  int sub = tid & 3;
  int h = blockIdx.y, bb = blockIdx.z;
  int qi = blockIdx.x*64 + (tid >> 2);
  bool qv = qi < NQ;
  float qn[4] = {0,0,0,0}, acc[4] = {0,0,0,0};
  float l = 0.f;
  if (qv){
    float s = 0.f;
    #pragma unroll
    for (int j = 0; j < 4; j++){
      qn[j] = Q[(size_t)bb*qbs + (size_t)(qoff + h*16 + sub*4 + j)*NQ + qi];
      s += qn[j]*qn[j];
    }
    s += __shfl_xor(s, 1); s += __shfl_xor(s, 2);
    float inv = scale / fmaxf(sqrtf(s), 1e-12f);
    #pragma unroll
    for (int j = 0; j < 4; j++) qn[j] *= inv;
  }
  for (int k0 = 0; k0 < NK; k0 += TK){
    int lim = min(TK, NK - k0);
    for (int i = tid; i < 16*TK; i += 256){
      int pos = i & (TK-1), d = i >> 7;
      if (pos < lim){
        Ks[pos*KP + d] = KV[(size_t)bb*kbs + (size_t)(koff + h*16 + d)*NK + k0 + pos];
        Vs[pos*KP + d] = KV[(size_t)bb*kbs + (size_t)(voff + h*16 + d)*NK + k0 + pos];
      }
    }
    __syncthreads();
    if (tid < lim){
      float s = 0.f;
      #pragma unroll
      for (int d = 0; d < 16; d++){ float v = Ks[tid*KP + d]; s += v*v; }
      KnI[tid] = 1.f / fmaxf(sqrtf(s), 1e-12f);
    }
    __syncthreads();
    for (int pos = 0; pos < lim; pos++){
      float4 k4 = *(const float4*)&Ks[pos*KP + sub*4];
      float dd = qn[0]*k4.x + qn[1]*k4.y + qn[2]*k4.z + qn[3]*k4.w;
      dd += __shfl_xor(dd, 1); dd += __shfl_xor(dd, 2);
      float pp = __expf(dd * KnI[pos]);
      l += pp;
      float4 v4 = *(const float4*)&Vs[pos*KP + sub*4];
      acc[0] += pp*v4.x;
      acc[1] += pp*v4.y;
      acc[2] += pp*v4.z;
      acc[3] += pp*v4.w;
    }
    __syncthreads();
  }
  if (qv){
    float li = 1.f / fmaxf(l, 1e-30f);
    #pragma unroll
    for (int j = 0; j < 4; j++)
      Out[(size_t)bb*obs + (size_t)(h*16 + sub*4 + j)*NQ + qi] = acc[j]*li;
  }
}

// ---------------- latent-read attention, split-K partials (proven) ----------------
__global__ void latpart_k(const float* __restrict__ ql, const float* __restrict__ kvx,
                          long kbs, float* __restrict__ part, int NK, int S){
  int s = blockIdx.x, h = blockIdx.y, bb = blockIdx.z;
  int q = threadIdx.x;
  if (q >= 16) return;
  float qn[16]; float ss = 0.f;
  #pragma unroll
  for (int d = 0; d < 16; d++){
    qn[d] = ql[(size_t)bb*2048 + (size_t)(h*16+d)*16 + q];
    ss += qn[d]*qn[d];
  }
  float inv = 0.25f / fmaxf(sqrtf(ss), 1e-12f);
  #pragma unroll
  for (int d = 0; d < 16; d++) qn[d] *= inv;
  float m = MINIT, l = 0.f, acc[16];
  #pragma unroll
  for (int d = 0; d < 16; d++) acc[d] = 0.f;
  int chunk = NK / S;
  int k0 = s*chunk, k1 = k0 + chunk;
  const float* kb = kvx + (size_t)bb*kbs;
  for (int pos = k0; pos < k1; pos++){
    float kd[16]; float ks = 0.f;
    #pragma unroll
    for (int d = 0; d < 16; d++){
      kd[d] = kb[(size_t)(h*16+d)*NK + pos];
      ks += kd[d]*kd[d];
    }
    float kin = 1.f / fmaxf(sqrtf(ks), 1e-12f);
    float dot = 0.f;
    #pragma unroll
    for (int d = 0; d < 16; d++) dot += qn[d]*kd[d];
    float logit = dot * kin;
    float mn = fmaxf(m, logit);
    float r  = __expf(m - mn);
    float pp = __expf(logit - mn);
    l = l*r + pp; m = mn;
    #pragma unroll
    for (int d = 0; d < 16; d++)
      acc[d] = acc[d]*r + pp*kb[(size_t)(128 + h*16+d)*NK + pos];
  }
  size_t idx = (size_t)((((bb*8 + h)*16 + q)*S) + s)*18;
  part[idx] = m; part[idx+1] = l;
  #pragma unroll
  for (int d = 0; d < 16; d++) part[idx+2+d] = acc[d];
}

__global__ void latcomb_k(const float* __restrict__ part, float* __restrict__ latr, int S){
  int t = threadIdx.x;
  int q = t & 15, h = (t >> 4) & 7, bb = t >> 7;
  size_t base = (size_t)(((bb*8 + h)*16 + q)*S)*18;
  float M = MINIT;
  for (int s = 0; s < S; s++) M = fmaxf(M, part[base + (size_t)s*18]);
  float L = 0.f, acc[16];
  #pragma unroll
  for (int d = 0; d < 16; d++) acc[d] = 0.f;
  for (int s = 0; s < S; s++){
    const float* ps = part + base + (size_t)s*18;
    float w = __expf(ps[0] - M);
    L += ps[1]*w;
    #pragma unroll
    for (int d = 0; d < 16; d++) acc[d] += ps[2+d]*w;
  }
  float li = 1.f / fmaxf(L, 1e-30f);
  #pragma unroll
  for (int d = 0; d < 16; d++)
    latr[(size_t)bb*2048 + (size_t)(h*16+d)*16 + q] = acc[d]*li;
}

// ---------------- 4x4 mean pool (proven) ----------------
__global__ void pool4_k(const float* __restrict__ xn, float* __restrict__ xc){
  int i = blockIdx.x*blockDim.x + threadIdx.x;
  if (i >= 2*128*144) return;
  int pc = i % 144; int bc = i / 144;
  int hc = pc / 12, wc = pc % 12;
  const float* s = xn + (size_t)bc*2304 + hc*4*48 + wc*4;
  float acc = 0.f;
  #pragma unroll
  for (int r = 0; r < 4; r++)
    #pragma unroll
    for (int c2 = 0; c2 < 4; c2++) acc += s[r*48 + c2];
  xc[i] = acc * 0.0625f;
}

// ---------------- bilinear upsample 12->48 (proven) ----------------
__global__ void ups_k(const float* __restrict__ g, float* __restrict__ out){
  int i = blockIdx.x*blockDim.x + threadIdx.x;
  if (i >= 2*128*2304) return;
  int p = i % 2304; int bc = i / 2304;
  int h = p / 48, w = p % 48;
  float sh = h*0.25f - 0.375f;
  float sw = w*0.25f - 0.375f;
  float fh0 = floorf(sh), fw0 = floorf(sw);
  float fh = sh - fh0, fw = sw - fw0;
  int h0 = (int)fh0, w0 = (int)fw0;
  int h0c = min(11, max(0, h0)),   h1c = min(11, max(0, h0+1));
  int w0c = min(11, max(0, w0)),   w1c = min(11, max(0, w0+1));
  const float* s = g + (size_t)bc*144;
  float v00 = s[h0c*12 + w0c], v01 = s[h0c*12 + w1c];
  float v10 = s[h1c*12 + w0c], v11 = s[h1c*12 + w1c];
  out[i] = (1.f-fh)*((1.f-fw)*v00 + fw*v01) + fh*((1.f-fw)*v10 + fw*v11);
}

extern "C" void kernel_launch(void* const* d_in, const int* in_sizes, int n_in,
                              void* d_out, int out_size, void* d_ws, size_t ws_size,
                              hipStream_t stream){
  const int B = 2, C = 128, HW = 2304;
  const void* x_in        = d_in[0];
  const void* g1          = d_in[1];
  const void* b1          = d_in[2];
  const void* loc_qkv_w   = d_in[3];
  const void* loc_proj_w  = d_in[4];
  const void* loc_proj_b  = d_in[5];
  const void* glob_qkv_w  = d_in[6];
  const void* glob_proj_w = d_in[7];
  const void* glob_proj_b = d_in[8];
  const void* fuse_w1     = d_in[9];
  const void* fuse_b1     = d_in[10];
  const void* fuse_w2     = d_in[11];
  const void* fuse_b2     = d_in[12];
  const void* glat        = d_in[13];
  const void* blat        = d_in[14];
  const void* latents     = d_in[15];
  const void* qlat_w      = d_in[16];
  const void* kvx_w       = d_in[17];
  const void* qx_w        = d_in[18];
  const void* kvlat_w     = d_in[19];
  const void* lat_proj_w  = d_in[20];
  const void* lat_proj_b  = d_in[21];
  const void* g2          = d_in[22];
  const void* b2          = d_in[23];
  const void* ffn_w1      = d_in[24];
  const void* ffn_b1      = d_in[25];
  const void* ffn_w2      = d_in[26];
  const void* ffn_b2      = d_in[27];

  // ---- workspace layout VERBATIM (R8..R15) ----
  float* ws = (float*)d_ws;
  float* P  = ws + 0;
  float* N  = ws + 589824;
  float* A  = ws + 1179648;
  float* Q  = ws + 1769472;
  float* FLAG = ws + 4128768;

  float* qkv   = Q;                 // 1,769,472
  float* L     = Q + 1769472;       // 589,824
  float* xc    = Q;
  float* qkvc  = Q + 36864;
  float* gatt  = Q + 147456;
  float* gproj = Q + 184320;
  float* kvx   = Q;                 // 1,179,648
  float* latf  = Q + 1179648;
  float* qlat  = Q + 1181696;
  float* latr  = Q + 1185792;
  float* kvlat = Q + 1189888;
  float* part  = Q + 1198080;       // 73,728 (S=16)
  float* ffh   = Q;                 // 2,359,296

  dim3 blk(256);

  detect_k<<<1, 64, 0, stream>>>(x_in, FLAG);
  cvt_k<<<2304, blk, 0, stream>>>(x_in, P, 589824, FLAG);

  // ---- BioAttentionFusion branch ----
  ln2d_k<<<dim3(9,B), blk, 0, stream>>>(P, g1, b1, N, C, HW, FLAG);
  conv1x1v4_k<<<dim3(3,384,B), blk, 0, stream>>>(N,(long)C*HW,C, nullptr,0,0, loc_qkv_w,nullptr,nullptr, qkv,0,384,HW,0, FLAG);
  flat_attn_k<<<dim3(36,8,B), blk, 0, stream>>>(qkv,(long)384*HW,0, qkv,(long)384*HW,128,256, A,(long)C*HW, HW,HW,0.25f);
  conv1x1v4_k<<<dim3(3,128,B), blk, 0, stream>>>(A,(long)C*HW,C, nullptr,0,0, loc_proj_w,loc_proj_b,nullptr, L,0,C,HW,0, FLAG);
  pool4_k<<<144, blk, 0, stream>>>(N, xc);
  conv1x1_k<<<dim3(1,384,B), blk, 0, stream>>>(xc,(long)C*144,C, nullptr,0,0, glob_qkv_w,nullptr,nullptr, qkvc,0,384,144,0, FLAG);
  cosattn_k<<<dim3(1,8,B), blk, 0, stream>>>(qkvc,(long)384*144,0, qkvc,(long)384*144,128,256, gatt,(long)C*144, 144,144,0.25f);
  conv1x1_k<<<dim3(1,128,B), blk, 0, stream>>>(gatt,(long)C*144,C, nullptr,0,0, glob_proj_w,glob_proj_b,nullptr, gproj,0,C,144,0, FLAG);
  ups_k<<<2304, blk, 0, stream>>>(gproj, A);                                          // A = upsampled global
  conv1x1v4_k<<<dim3(3,128,B), blk, 0, stream>>>(L,(long)C*HW,C, A,(long)C*HW,C, fuse_w1,fuse_b1,nullptr, N,0,C,HW,1, FLAG);  // N = gelu(fuse1)
  conv1x1v4_k<<<dim3(3,128,B), blk, 0, stream>>>(N,(long)C*HW,C, nullptr,0,0, fuse_w2,fuse_b2,P, P,0,C,HW,0, FLAG);           // P = x + f

  // ---- LatentMixer branch ----
  ln2d_k<<<dim3(9,B), blk, 0, stream>>>(P, glat, blat, N, C, HW, FLAG);
  conv1x1v4_k<<<dim3(3,256,B), blk, 0, stream>>>(N,(long)C*HW,C, nullptr,0,0, kvx_w,nullptr,nullptr, kvx,0,256,HW,0, FLAG);
  conv1x1v4_k<<<dim3(3,128,B), blk, 0, stream>>>(N,(long)C*HW,C, nullptr,0,0, qx_w,nullptr,nullptr, A,0,C,HW,0, FLAG);        // A = qx
  cvt_k<<<8, blk, 0, stream>>>(latents, latf, 2048, FLAG);
  conv1x1_k<<<dim3(1,128,B), blk, 0, stream>>>(latf,0L,C, nullptr,0,0, qlat_w,nullptr,nullptr, qlat,0,C,16,0, FLAG);
  latpart_k<<<dim3(16,8,B), 64, 0, stream>>>(qlat, kvx, (long)256*HW, part, HW, 16);
  latcomb_k<<<1, blk, 0, stream>>>(part, latr, 16);
  conv1x1_k<<<dim3(1,256,B), blk, 0, stream>>>(latr,(long)C*16,C, nullptr,0,0, kvlat_w,nullptr,nullptr, kvlat,0,256,16,0, FLAG);
  attn4_k<<<dim3(36,8,B), blk, 0, stream>>>(A,(long)C*HW,0, kvlat,(long)256*16,0,128, N,(long)C*HW, HW,16,0.25f);             // N = xw
  conv1x1v4_k<<<dim3(3,128,B), blk, 0, stream>>>(N,(long)C*HW,C, nullptr,0,0, lat_proj_w,lat_proj_b,P, P,0,C,HW,0, FLAG);     // P = x2

  // ---- FFN branch ----
  ln2d_k<<<dim3(9,B), blk, 0, stream>>>(P, g2, b2, N, C, HW, FLAG);
  conv1x1v4_k<<<dim3(3,512,B), blk, 0, stream>>>(N,(long)C*HW,C, nullptr,0,0, ffn_w1,ffn_b1,nullptr, ffh,0,512,HW,1, FLAG);
  conv1x1v4_k<<<dim3(3,128,B), blk, 0, stream>>>(ffh,(long)512*HW,512, nullptr,0,0, ffn_w2,ffn_b2,P, d_out,1,C,HW,0, FLAG);
}

// Round 17
// 961.711 us; speedup vs baseline: 3.5163x; 1.3187x over previous
//
#include <hip/hip_runtime.h>
#include <hip/hip_bf16.h>

typedef __hip_bfloat16 bf16;

#define HD 16
#define TK 128
#define KP 20            // attn LDS pitch: 16 dims + 4 pad, keeps float4 16B-aligned
#define CT 64            // flat_attn tile positions per wave-chunk
#define MINIT (-1e30f)

__device__ __forceinline__ float b2f(bf16 v){ return __bfloat162float(v); }
__device__ __forceinline__ float gelu_f(float x){ return 0.5f*x*(1.0f+erff(x*0.70710678118654752f)); }
__device__ __forceinline__ float rdv(const void* p, size_t i, bool bf){
  return bf ? b2f(((const bf16*)p)[i]) : ((const float*)p)[i];
}

// ---------------- dtype detector (proven) ----------------
__global__ void detect_k(const void* __restrict__ x, float* __restrict__ flag){
  if (threadIdx.x == 0 && blockIdx.x == 0){
    const float* xf = (const float*)x;
    const bf16*  xb = (const bf16*)x;
    double sF = 0.0, sB = 0.0;
    for (int i = 0; i < 512; i++){ float v = fabsf(xf[i]);     if (!(v < 1e30f)) v = 1e30f; sF += v; }
    for (int i = 0; i < 1024; i++){ float v = fabsf(b2f(xb[i])); if (!(v < 1e30f)) v = 1e30f; sB += v; }
    float mF = (float)(sF/512.0), mB = (float)(sB/1024.0);
    float dF = fabsf(logf(fmaxf(mF, 1e-30f)));
    float dB = fabsf(logf(fmaxf(mB, 1e-30f)));
    *flag = (dB <= dF) ? 1.0f : 0.0f;
  }
}

// ---------------- input -> fp32 convert (proven) ----------------
__global__ void cvt_k(const void* __restrict__ in, float* __restrict__ out, int n,
                      const float* __restrict__ flagp){
  bool bf = *flagp > 0.5f;
  int i = blockIdx.x*blockDim.x + threadIdx.x;
  if (i < n) out[i] = rdv(in, i, bf);
}

// ---------------- LayerNorm over channels, per pixel (proven) ----------------
__global__ void ln2d_k(const float* __restrict__ x, const void* __restrict__ g,
                       const void* __restrict__ b, float* __restrict__ y,
                       int C, int HW, const float* __restrict__ flagp){
  bool bf = *flagp > 0.5f;
  int p  = blockIdx.x*blockDim.x + threadIdx.x;
  int bb = blockIdx.y;
  if (p >= HW) return;
  const float* xb = x + (size_t)bb*C*HW + p;
  float s = 0.f, s2 = 0.f;
  for (int c = 0; c < C; c++){ float v = xb[(size_t)c*HW]; s += v; s2 += v*v; }
  float mu  = s  / (float)C;
  float var = fmaxf(s2 / (float)C - mu*mu, 0.f);
  float inv = rsqrtf(var + 1e-5f);
  float* yb = y + (size_t)bb*C*HW + p;
  for (int c = 0; c < C; c++){
    yb[(size_t)c*HW] = (xb[(size_t)c*HW] - mu)*inv*rdv(g,c,bf) + rdv(b,c,bf);
  }
}

// ---------------- generic scalar 1x1 conv (proven; small NP cases) ----------------
__global__ void conv1x1_k(const float* __restrict__ in1, long in1_bs, int C1,
                          const float* __restrict__ in2, long in2_bs, int C2,
                          const void* __restrict__ w, const void* __restrict__ bias,
                          const float* __restrict__ res,
                          void* __restrict__ out, int to_out, int O, int NP, int act,
                          const float* __restrict__ flagp){
  bool bf = *flagp > 0.5f;
  int p = blockIdx.x*blockDim.x + threadIdx.x;
  if (p >= NP) return;
  int o = blockIdx.y, bb = blockIdx.z;
  size_t wrow = (size_t)o*(C1 + C2);
  float acc = bias ? rdv(bias, o, bf) : 0.f;
  const float* i1 = in1 + (size_t)bb*in1_bs + p;
  for (int c = 0; c < C1; c++) acc += rdv(w, wrow + c, bf) * i1[(size_t)c*NP];
  if (in2){
    const float* i2 = in2 + (size_t)bb*in2_bs + p;
    for (int c = 0; c < C2; c++) acc += rdv(w, wrow + C1 + c, bf) * i2[(size_t)c*NP];
  }
  if (act == 1) acc = gelu_f(acc);
  if (res) acc += res[((size_t)bb*O + o)*NP + p];
  size_t oi = ((size_t)bb*O + o)*NP + p;
  if (to_out){
    if (bf) ((bf16*)out)[oi] = __float2bfloat16(acc);
    else    ((float*)out)[oi] = acc;
  } else {
    ((float*)out)[oi] = acc;
  }
}

// ---------------- NEW: LDS-tiled conv GEMM: 64 out-ch x 64 pixels per block ----------------
// Requires O % 64 == 0, NP % 64 == 0, (C1+C2) % 128 == 0, C1 % 128 == 0 when C2 > 0.
// Weights via FLAG/rdv (THE proven-safe path). Each thread: 4o x 4p register tile.
__global__ __launch_bounds__(256) void convtile_k(
    const float* __restrict__ in1, long in1_bs, int C1,
    const float* __restrict__ in2, long in2_bs, int C2,
    const void* __restrict__ w, const void* __restrict__ bias,
    const float* __restrict__ res, void* __restrict__ out, int to_out,
    int O, int NP, int act, const float* __restrict__ flagp)
{
  __shared__ __align__(16) float Xs[128*64];   // Xs[c*64 + j]
  __shared__ __align__(16) float Wt[128*64];   // Wt[c*64 + i] (transposed weights)
  bool bf = *flagp > 0.5f;
  int tid = threadIdx.x;
  int p0 = blockIdx.x*64, o0 = blockIdx.y*64, bb = blockIdx.z;
  int CW = C1 + C2;
  int to = (tid >> 4)*4;        // out-ch offset in tile: 0..60
  int tp = (tid & 15)*4;        // pixel offset in tile:  0..60
  float a[4][4];
  #pragma unroll
  for (int k = 0; k < 4; k++)
    #pragma unroll
    for (int j = 0; j < 4; j++) a[k][j] = 0.f;
  for (int cc = 0; cc < CW; cc += 128){
    for (int idx = tid; idx < 128*64; idx += 256){
      int c = idx >> 6, j = idx & 63;
      int gc = cc + c;
      float v;
      if (gc < C1) v = in1[(size_t)bb*in1_bs + (size_t)gc*NP + p0 + j];
      else         v = in2[(size_t)bb*in2_bs + (size_t)(gc - C1)*NP + p0 + j];
      Xs[idx] = v;
    }
    for (int idx = tid; idx < 128*64; idx += 256){
      int c = idx >> 6, i = idx & 63;
      Wt[idx] = rdv(w, (size_t)(o0 + i)*CW + cc + c, bf);
    }
    __syncthreads();
    for (int c = 0; c < 128; c++){
      float4 wv = *(const float4*)&Wt[c*64 + to];
      float4 xv = *(const float4*)&Xs[c*64 + tp];
      a[0][0] += wv.x*xv.x; a[0][1] += wv.x*xv.y; a[0][2] += wv.x*xv.z; a[0][3] += wv.x*xv.w;
      a[1][0] += wv.y*xv.x; a[1][1] += wv.y*xv.y; a[1][2] += wv.y*xv.z; a[1][3] += wv.y*xv.w;
      a[2][0] += wv.z*xv.x; a[2][1] += wv.z*xv.y; a[2][2] += wv.z*xv.z; a[2][3] += wv.z*xv.w;
      a[3][0] += wv.w*xv.x; a[3][1] += wv.w*xv.y; a[3][2] += wv.w*xv.z; a[3][3] += wv.w*xv.w;
    }
    __syncthreads();
  }
  #pragma unroll
  for (int k = 0; k < 4; k++){
    int o = o0 + to + k;
    size_t orow = ((size_t)bb*O + o)*NP + p0 + tp;
    float bv = bias ? rdv(bias, o, bf) : 0.f;
    float v0 = a[k][0] + bv, v1 = a[k][1] + bv, v2 = a[k][2] + bv, v3 = a[k][3] + bv;
    if (act == 1){ v0 = gelu_f(v0); v1 = gelu_f(v1); v2 = gelu_f(v2); v3 = gelu_f(v3); }
    if (res){
      float4 r = *(const float4*)&res[orow];
      v0 += r.x; v1 += r.y; v2 += r.z; v3 += r.w;
    }
    if (to_out && bf){
      bf16* ob = (bf16*)out + orow;
      ob[0] = __float2bfloat16(v0); ob[1] = __float2bfloat16(v1);
      ob[2] = __float2bfloat16(v2); ob[3] = __float2bfloat16(v3);
    } else {
      float4 v; v.x = v0; v.y = v1; v.z = v2; v.w = v3;
      *(float4*)((float*)out + orow) = v;
    }
  }
}

// ---------------- flat cosine attention (proven R14-R16; local attn) ----------------
__global__ __launch_bounds__(256) void flat_attn_k(
    const float* __restrict__ Q, long qbs, int qoff,
    const float* __restrict__ KV, long kbs, int koff, int voff,
    float* __restrict__ Out, long obs, int NQ, int NK, float scale)
{
  __shared__ __align__(16) float Ks[4*CT*KP];
  __shared__ __align__(16) float Vs[4*CT*KP];
  __shared__ float Kn[4*CT];
  int t = threadIdx.x, lane = t & 63, wv = t >> 6;
  int h = blockIdx.y, bb = blockIdx.z;
  int qi = blockIdx.x*64 + lane;
  float qn[16]; float s = 0.f;
  #pragma unroll
  for (int d = 0; d < 16; d++){
    qn[d] = Q[(size_t)bb*qbs + (size_t)(qoff + h*16 + d)*NQ + qi];
    s += qn[d]*qn[d];
  }
  float inv = scale / fmaxf(sqrtf(s), 1e-12f);
  #pragma unroll
  for (int d = 0; d < 16; d++) qn[d] *= inv;
  float acc[16]; float l = 0.f;
  #pragma unroll
  for (int d = 0; d < 16; d++) acc[d] = 0.f;
  int chunk = NK >> 2;
  const float* kvb = KV + (size_t)bb*kbs;
  for (int t0 = 0; t0 < chunk; t0 += CT){
    for (int i = t; i < 4*CT*16; i += 256){
      int w2 = i >> 10;
      int r  = i & 1023;
      int pos = r & 63, d = r >> 6;
      size_t g = (size_t)(h*16 + d)*NK + (size_t)w2*chunk + t0 + pos;
      Ks[w2*CT*KP + pos*KP + d] = kvb[(size_t)koff*NK + g];
      Vs[w2*CT*KP + pos*KP + d] = kvb[(size_t)voff*NK + g];
    }
    __syncthreads();
    {
      float ss = 0.f;
      #pragma unroll
      for (int d = 0; d < 16; d++){ float v = Ks[wv*CT*KP + lane*KP + d]; ss += v*v; }
      Kn[wv*CT + lane] = 1.f / fmaxf(sqrtf(ss), 1e-12f);
    }
    __syncthreads();
    const float* ks = &Ks[wv*CT*KP];
    const float* vs = &Vs[wv*CT*KP];
    const float* kn = &Kn[wv*CT];
    for (int pos = 0; pos < CT; pos++){
      float4 a  = *(const float4*)&ks[pos*KP];
      float4 b4 = *(const float4*)&ks[pos*KP + 4];
      float4 c4 = *(const float4*)&ks[pos*KP + 8];
      float4 d4 = *(const float4*)&ks[pos*KP + 12];
      float dot = qn[0]*a.x  + qn[1]*a.y  + qn[2]*a.z  + qn[3]*a.w
                + qn[4]*b4.x + qn[5]*b4.y + qn[6]*b4.z + qn[7]*b4.w
                + qn[8]*c4.x + qn[9]*c4.y + qn[10]*c4.z+ qn[11]*c4.w
                + qn[12]*d4.x+ qn[13]*d4.y+ qn[14]*d4.z+ qn[15]*d4.w;
      float pp = __expf(dot * kn[pos]);
      l += pp;
      float4 va = *(const float4*)&vs[pos*KP];
      float4 vb = *(const float4*)&vs[pos*KP + 4];
      float4 vc = *(const float4*)&vs[pos*KP + 8];
      float4 vd = *(const float4*)&vs[pos*KP + 12];
      acc[0] += pp*va.x; acc[1] += pp*va.y; acc[2] += pp*va.z; acc[3] += pp*va.w;
      acc[4] += pp*vb.x; acc[5] += pp*vb.y; acc[6] += pp*vb.z; acc[7] += pp*vb.w;
      acc[8] += pp*vc.x; acc[9] += pp*vc.y; acc[10]+= pp*vc.z; acc[11]+= pp*vc.w;
      acc[12]+= pp*vd.x; acc[13]+= pp*vd.y; acc[14]+= pp*vd.z; acc[15]+= pp*vd.w;
    }
    __syncthreads();
  }
  #pragma unroll
  for (int d = 0; d < 16; d++) Ks[(wv*64 + lane)*17 + d] = acc[d];
  Ks[(wv*64 + lane)*17 + 16] = l;
  __syncthreads();
  if (wv == 0){
    float lt = 0.f; float at[16];
    #pragma unroll
    for (int d = 0; d < 16; d++) at[d] = 0.f;
    #pragma unroll
    for (int w2 = 0; w2 < 4; w2++){
      const float* ps = &Ks[(w2*64 + lane)*17];
      lt += ps[16];
      #pragma unroll
      for (int d = 0; d < 16; d++) at[d] += ps[d];
    }
    float li = 1.f / fmaxf(lt, 1e-30f);
    #pragma unroll
    for (int d = 0; d < 16; d++)
      Out[(size_t)bb*obs + (size_t)(h*16 + d)*NQ + qi] = at[d]*li;
  }
}

// ---------------- cosine attention (proven; global attn NK=144) ----------------
__global__ void cosattn_k(const float* __restrict__ Q, long qbs, int qoff,
                          const float* __restrict__ KV, long kbs, int koff, int voff,
                          float* __restrict__ Out, long obs,
                          int NQ, int NK, float scale){
  __shared__ float Ks[HD*TK];
  __shared__ float Vs[HD*TK];
  __shared__ float KnI[TK];
  int tid = threadIdx.x;
  int h  = blockIdx.y, bb = blockIdx.z;
  int qi = blockIdx.x*blockDim.x + tid;
  bool qv = qi < NQ;
  float qn[HD], acc[HD];
  float m = -INFINITY, l = 0.f;
  if (qv){
    float s = 0.f;
    #pragma unroll
    for (int d = 0; d < HD; d++){
      qn[d] = Q[(size_t)bb*qbs + (size_t)(qoff + h*HD + d)*NQ + qi];
      s += qn[d]*qn[d];
    }
    float inv = scale / fmaxf(sqrtf(s), 1e-12f);
    #pragma unroll
    for (int d = 0; d < HD; d++){ qn[d] *= inv; acc[d] = 0.f; }
  }
  for (int k0 = 0; k0 < NK; k0 += TK){
    int lim = min(TK, NK - k0);
    for (int i = tid; i < HD*TK; i += blockDim.x){
      int pos = i % TK, d = i / TK;
      if (pos < lim){
        Ks[d*TK + pos] = KV[(size_t)bb*kbs + (size_t)(koff + h*HD + d)*NK + k0 + pos];
        Vs[d*TK + pos] = KV[(size_t)bb*kbs + (size_t)(voff + h*HD + d)*NK + k0 + pos];
      }
    }
    __syncthreads();
    if (tid < lim){
      float s = 0.f;
      #pragma unroll
      for (int d = 0; d < HD; d++){ float v = Ks[d*TK + tid]; s += v*v; }
      KnI[tid] = 1.f / fmaxf(sqrtf(s), 1e-12f);
    }
    __syncthreads();
    if (qv){
      for (int pos = 0; pos < lim; pos++){
        float dot = 0.f;
        #pragma unroll
        for (int d = 0; d < HD; d++) dot += qn[d]*Ks[d*TK + pos];
        float logit = dot * KnI[pos];
        float mn = fmaxf(m, logit);
        float r  = __expf(m - mn);
        float pp = __expf(logit - mn);
        l = l*r + pp;
        #pragma unroll
        for (int d = 0; d < HD; d++) acc[d] = acc[d]*r + pp*Vs[d*TK + pos];
        m = mn;
      }
    }
    __syncthreads();
  }
  if (qv){
    float li = 1.f / fmaxf(l, 1e-30f);
    #pragma unroll
    for (int d = 0; d < HD; d++)
      Out[(size_t)bb*obs + (size_t)(h*HD + d)*NQ + qi] = acc[d]*li;
  }
}

// ---------------- attn4, no-max (proven; xw attention NK=16) ----------------
__global__ __launch_bounds__(256) void attn4_k(
    const float* __restrict__ Q, long qbs, int qoff,
    const float* __restrict__ KV, long kbs, int koff, int voff,
    float* __restrict__ Out, long obs, int NQ, int NK, float scale)
{
  __shared__ __align__(16) float Ks[TK*KP];
  __shared__ __align__(16) float Vs[TK*KP];
  __shared__ float KnI[TK];
  int tid = threadIdx.x;
  int sub = tid & 3;
  int h = blockIdx.y, bb = blockIdx.z;
  int qi = blockIdx.x*64 + (tid >> 2);
  bool qv = qi < NQ;
  float qn[4] = {0,0,0,0}, acc[4] = {0,0,0,0};
  float l = 0.f;
  if (qv){
    float s = 0.f;
    #pragma unroll
    for (int j = 0; j < 4; j++){
      qn[j] = Q[(size_t)bb*qbs + (size_t)(qoff + h*16 + sub*4 + j)*NQ + qi];
      s += qn[j]*qn[j];
    }
    s += __shfl_xor(s, 1); s += __shfl_xor(s, 2);
    float inv = scale / fmaxf(sqrtf(s), 1e-12f);
    #pragma unroll
    for (int j = 0; j < 4; j++) qn[j] *= inv;
  }
  for (int k0 = 0; k0 < NK; k0 += TK){
    int lim = min(TK, NK - k0);
    for (int i = tid; i < 16*TK; i += 256){
      int pos = i & (TK-1), d = i >> 7;
      if (pos < lim){
        Ks[pos*KP + d] = KV[(size_t)bb*kbs + (size_t)(koff + h*16 + d)*NK + k0 + pos];
        Vs[pos*KP + d] = KV[(size_t)bb*kbs + (size_t)(voff + h*16 + d)*NK + k0 + pos];
      }
    }
    __syncthreads();
    if (tid < lim){
      float s = 0.f;
      #pragma unroll
      for (int d = 0; d < 16; d++){ float v = Ks[tid*KP + d]; s += v*v; }
      KnI[tid] = 1.f / fmaxf(sqrtf(s), 1e-12f);
    }
    __syncthreads();
    for (int pos = 0; pos < lim; pos++){
      float4 k4 = *(const float4*)&Ks[pos*KP + sub*4];
      float dd = qn[0]*k4.x + qn[1]*k4.y + qn[2]*k4.z + qn[3]*k4.w;
      dd += __shfl_xor(dd, 1); dd += __shfl_xor(dd, 2);
      float pp = __expf(dd * KnI[pos]);
      l += pp;
      float4 v4 = *(const float4*)&Vs[pos*KP + sub*4];
      acc[0] += pp*v4.x;
      acc[1] += pp*v4.y;
      acc[2] += pp*v4.z;
      acc[3] += pp*v4.w;
    }
    __syncthreads();
  }
  if (qv){
    float li = 1.f / fmaxf(l, 1e-30f);
    #pragma unroll
    for (int j = 0; j < 4; j++)
      Out[(size_t)bb*obs + (size_t)(h*16 + sub*4 + j)*NQ + qi] = acc[j]*li;
  }
}

// ---------------- latent-read attention, split-K partials (proven) ----------------
__global__ void latpart_k(const float* __restrict__ ql, const float* __restrict__ kvx,
                          long kbs, float* __restrict__ part, int NK, int S){
  int s = blockIdx.x, h = blockIdx.y, bb = blockIdx.z;
  int q = threadIdx.x;
  if (q >= 16) return;
  float qn[16]; float ss = 0.f;
  #pragma unroll
  for (int d = 0; d < 16; d++){
    qn[d] = ql[(size_t)bb*2048 + (size_t)(h*16+d)*16 + q];
    ss += qn[d]*qn[d];
  }
  float inv = 0.25f / fmaxf(sqrtf(ss), 1e-12f);
  #pragma unroll
  for (int d = 0; d < 16; d++) qn[d] *= inv;
  float m = MINIT, l = 0.f, acc[16];
  #pragma unroll
  for (int d = 0; d < 16; d++) acc[d] = 0.f;
  int chunk = NK / S;
  int k0 = s*chunk, k1 = k0 + chunk;
  const float* kb = kvx + (size_t)bb*kbs;
  for (int pos = k0; pos < k1; pos++){
    float kd[16]; float ks = 0.f;
    #pragma unroll
    for (int d = 0; d < 16; d++){
      kd[d] = kb[(size_t)(h*16+d)*NK + pos];
      ks += kd[d]*kd[d];
    }
    float kin = 1.f / fmaxf(sqrtf(ks), 1e-12f);
    float dot = 0.f;
    #pragma unroll
    for (int d = 0; d < 16; d++) dot += qn[d]*kd[d];
    float logit = dot * kin;
    float mn = fmaxf(m, logit);
    float r  = __expf(m - mn);
    float pp = __expf(logit - mn);
    l = l*r + pp; m = mn;
    #pragma unroll
    for (int d = 0; d < 16; d++)
      acc[d] = acc[d]*r + pp*kb[(size_t)(128 + h*16+d)*NK + pos];
  }
  size_t idx = (size_t)((((bb*8 + h)*16 + q)*S) + s)*18;
  part[idx] = m; part[idx+1] = l;
  #pragma unroll
  for (int d = 0; d < 16; d++) part[idx+2+d] = acc[d];
}

__global__ void latcomb_k(const float* __restrict__ part, float* __restrict__ latr, int S){
  int t = threadIdx.x;
  int q = t & 15, h = (t >> 4) & 7, bb = t >> 7;
  size_t base = (size_t)(((bb*8 + h)*16 + q)*S)*18;
  float M = MINIT;
  for (int s = 0; s < S; s++) M = fmaxf(M, part[base + (size_t)s*18]);
  float L = 0.f, acc[16];
  #pragma unroll
  for (int d = 0; d < 16; d++) acc[d] = 0.f;
  for (int s = 0; s < S; s++){
    const float* ps = part + base + (size_t)s*18;
    float w = __expf(ps[0] - M);
    L += ps[1]*w;
    #pragma unroll
    for (int d = 0; d < 16; d++) acc[d] += ps[2+d]*w;
  }
  float li = 1.f / fmaxf(L, 1e-30f);
  #pragma unroll
  for (int d = 0; d < 16; d++)
    latr[(size_t)bb*2048 + (size_t)(h*16+d)*16 + q] = acc[d]*li;
}

// ---------------- 4x4 mean pool (proven) ----------------
__global__ void pool4_k(const float* __restrict__ xn, float* __restrict__ xc){
  int i = blockIdx.x*blockDim.x + threadIdx.x;
  if (i >= 2*128*144) return;
  int pc = i % 144; int bc = i / 144;
  int hc = pc / 12, wc = pc % 12;
  const float* s = xn + (size_t)bc*2304 + hc*4*48 + wc*4;
  float acc = 0.f;
  #pragma unroll
  for (int r = 0; r < 4; r++)
    #pragma unroll
    for (int c2 = 0; c2 < 4; c2++) acc += s[r*48 + c2];
  xc[i] = acc * 0.0625f;
}

// ---------------- bilinear upsample 12->48 (proven) ----------------
__global__ void ups_k(const float* __restrict__ g, float* __restrict__ out){
  int i = blockIdx.x*blockDim.x + threadIdx.x;
  if (i >= 2*128*2304) return;
  int p = i % 2304; int bc = i / 2304;
  int h = p / 48, w = p % 48;
  float sh = h*0.25f - 0.375f;
  float sw = w*0.25f - 0.375f;
  float fh0 = floorf(sh), fw0 = floorf(sw);
  float fh = sh - fh0, fw = sw - fw0;
  int h0 = (int)fh0, w0 = (int)fw0;
  int h0c = min(11, max(0, h0)),   h1c = min(11, max(0, h0+1));
  int w0c = min(11, max(0, w0)),   w1c = min(11, max(0, w0+1));
  const float* s = g + (size_t)bc*144;
  float v00 = s[h0c*12 + w0c], v01 = s[h0c*12 + w1c];
  float v10 = s[h1c*12 + w0c], v11 = s[h1c*12 + w1c];
  out[i] = (1.f-fh)*((1.f-fw)*v00 + fw*v01) + fh*((1.f-fw)*v10 + fw*v11);
}

extern "C" void kernel_launch(void* const* d_in, const int* in_sizes, int n_in,
                              void* d_out, int out_size, void* d_ws, size_t ws_size,
                              hipStream_t stream){
  const int B = 2, C = 128, HW = 2304;
  const void* x_in        = d_in[0];
  const void* g1          = d_in[1];
  const void* b1          = d_in[2];
  const void* loc_qkv_w   = d_in[3];
  const void* loc_proj_w  = d_in[4];
  const void* loc_proj_b  = d_in[5];
  const void* glob_qkv_w  = d_in[6];
  const void* glob_proj_w = d_in[7];
  const void* glob_proj_b = d_in[8];
  const void* fuse_w1     = d_in[9];
  const void* fuse_b1     = d_in[10];
  const void* fuse_w2     = d_in[11];
  const void* fuse_b2     = d_in[12];
  const void* glat        = d_in[13];
  const void* blat        = d_in[14];
  const void* latents     = d_in[15];
  const void* qlat_w      = d_in[16];
  const void* kvx_w       = d_in[17];
  const void* qx_w        = d_in[18];
  const void* kvlat_w     = d_in[19];
  const void* lat_proj_w  = d_in[20];
  const void* lat_proj_b  = d_in[21];
  const void* g2          = d_in[22];
  const void* b2          = d_in[23];
  const void* ffn_w1      = d_in[24];
  const void* ffn_b1      = d_in[25];
  const void* ffn_w2      = d_in[26];
  const void* ffn_b2      = d_in[27];

  // ---- workspace layout VERBATIM (R8..R16) ----
  float* ws = (float*)d_ws;
  float* P  = ws + 0;
  float* N  = ws + 589824;
  float* A  = ws + 1179648;
  float* Q  = ws + 1769472;
  float* FLAG = ws + 4128768;

  float* qkv   = Q;                 // 1,769,472
  float* L     = Q + 1769472;       // 589,824
  float* xc    = Q;
  float* qkvc  = Q + 36864;
  float* gatt  = Q + 147456;
  float* gproj = Q + 184320;
  float* kvx   = Q;                 // 1,179,648
  float* latf  = Q + 1179648;
  float* qlat  = Q + 1181696;
  float* latr  = Q + 1185792;
  float* kvlat = Q + 1189888;
  float* part  = Q + 1198080;       // 221,184 (S=48) fits: ends 1,419,264 < 2,359,296
  float* ffh   = Q;                 // 2,359,296

  dim3 blk(256);

  detect_k<<<1, 64, 0, stream>>>(x_in, FLAG);
  cvt_k<<<2304, blk, 0, stream>>>(x_in, P, 589824, FLAG);

  // ---- BioAttentionFusion branch ----
  ln2d_k<<<dim3(9,B), blk, 0, stream>>>(P, g1, b1, N, C, HW, FLAG);
  convtile_k<<<dim3(36,6,B), blk, 0, stream>>>(N,(long)C*HW,C, nullptr,0,0, loc_qkv_w,nullptr,nullptr, qkv,0,384,HW,0, FLAG);
  flat_attn_k<<<dim3(36,8,B), blk, 0, stream>>>(qkv,(long)384*HW,0, qkv,(long)384*HW,128,256, A,(long)C*HW, HW,HW,0.25f);
  convtile_k<<<dim3(36,2,B), blk, 0, stream>>>(A,(long)C*HW,C, nullptr,0,0, loc_proj_w,loc_proj_b,nullptr, L,0,C,HW,0, FLAG);
  pool4_k<<<144, blk, 0, stream>>>(N, xc);
  conv1x1_k<<<dim3(1,384,B), blk, 0, stream>>>(xc,(long)C*144,C, nullptr,0,0, glob_qkv_w,nullptr,nullptr, qkvc,0,384,144,0, FLAG);
  cosattn_k<<<dim3(1,8,B), blk, 0, stream>>>(qkvc,(long)384*144,0, qkvc,(long)384*144,128,256, gatt,(long)C*144, 144,144,0.25f);
  conv1x1_k<<<dim3(1,128,B), blk, 0, stream>>>(gatt,(long)C*144,C, nullptr,0,0, glob_proj_w,glob_proj_b,nullptr, gproj,0,C,144,0, FLAG);
  ups_k<<<2304, blk, 0, stream>>>(gproj, A);                                          // A = upsampled global
  convtile_k<<<dim3(36,2,B), blk, 0, stream>>>(L,(long)C*HW,C, A,(long)C*HW,C, fuse_w1,fuse_b1,nullptr, N,0,C,HW,1, FLAG);  // N = gelu(fuse1)
  convtile_k<<<dim3(36,2,B), blk, 0, stream>>>(N,(long)C*HW,C, nullptr,0,0, fuse_w2,fuse_b2,P, P,0,C,HW,0, FLAG);           // P = x + f

  // ---- LatentMixer branch ----
  ln2d_k<<<dim3(9,B), blk, 0, stream>>>(P, glat, blat, N, C, HW, FLAG);
  convtile_k<<<dim3(36,4,B), blk, 0, stream>>>(N,(long)C*HW,C, nullptr,0,0, kvx_w,nullptr,nullptr, kvx,0,256,HW,0, FLAG);
  convtile_k<<<dim3(36,2,B), blk, 0, stream>>>(N,(long)C*HW,C, nullptr,0,0, qx_w,nullptr,nullptr, A,0,C,HW,0, FLAG);        // A = qx
  cvt_k<<<8, blk, 0, stream>>>(latents, latf, 2048, FLAG);
  conv1x1_k<<<dim3(1,128,B), blk, 0, stream>>>(latf,0L,C, nullptr,0,0, qlat_w,nullptr,nullptr, qlat,0,C,16,0, FLAG);
  latpart_k<<<dim3(48,8,B), 64, 0, stream>>>(qlat, kvx, (long)256*HW, part, HW, 48);
  latcomb_k<<<1, blk, 0, stream>>>(part, latr, 48);
  conv1x1_k<<<dim3(1,256,B), blk, 0, stream>>>(latr,(long)C*16,C, nullptr,0,0, kvlat_w,nullptr,nullptr, kvlat,0,256,16,0, FLAG);
  attn4_k<<<dim3(36,8,B), blk, 0, stream>>>(A,(long)C*HW,0, kvlat,(long)256*16,0,128, N,(long)C*HW, HW,16,0.25f);           // N = xw
  convtile_k<<<dim3(36,2,B), blk, 0, stream>>>(N,(long)C*HW,C, nullptr,0,0, lat_proj_w,lat_proj_b,P, P,0,C,HW,0, FLAG);     // P = x2

  // ---- FFN branch ----
  ln2d_k<<<dim3(9,B), blk, 0, stream>>>(P, g2, b2, N, C, HW, FLAG);
  convtile_k<<<dim3(36,8,B), blk, 0, stream>>>(N,(long)C*HW,C, nullptr,0,0, ffn_w1,ffn_b1,nullptr, ffh,0,512,HW,1, FLAG);
  convtile_k<<<dim3(36,2,B), blk, 0, stream>>>(ffh,(long)512*HW,512, nullptr,0,0, ffn_w2,ffn_b2,P, d_out,1,C,HW,0, FLAG);
}

// Round 18
// 814.211 us; speedup vs baseline: 4.1533x; 1.1812x over previous
//
#include <hip/hip_runtime.h>
#include <hip/hip_bf16.h>

typedef __hip_bfloat16 bf16;

#define HD 16
#define TK 128
#define KP 20            // attn LDS pitch: 16 dims + 4 pad, keeps float4 16B-aligned
#define CT 64            // flat_attn tile positions per wave-chunk
#define MINIT (-1e30f)

__device__ __forceinline__ float b2f(bf16 v){ return __bfloat162float(v); }
__device__ __forceinline__ float gelu_f(float x){ return 0.5f*x*(1.0f+erff(x*0.70710678118654752f)); }
__device__ __forceinline__ float rdv(const void* p, size_t i, bool bf){
  return bf ? b2f(((const bf16*)p)[i]) : ((const float*)p)[i];
}

// ---------------- dtype detector (proven) ----------------
__global__ void detect_k(const void* __restrict__ x, float* __restrict__ flag){
  if (threadIdx.x == 0 && blockIdx.x == 0){
    const float* xf = (const float*)x;
    const bf16*  xb = (const bf16*)x;
    double sF = 0.0, sB = 0.0;
    for (int i = 0; i < 512; i++){ float v = fabsf(xf[i]);     if (!(v < 1e30f)) v = 1e30f; sF += v; }
    for (int i = 0; i < 1024; i++){ float v = fabsf(b2f(xb[i])); if (!(v < 1e30f)) v = 1e30f; sB += v; }
    float mF = (float)(sF/512.0), mB = (float)(sB/1024.0);
    float dF = fabsf(logf(fmaxf(mF, 1e-30f)));
    float dB = fabsf(logf(fmaxf(mB, 1e-30f)));
    *flag = (dB <= dF) ? 1.0f : 0.0f;
  }
}

// ---------------- input -> fp32 convert (proven) ----------------
__global__ void cvt_k(const void* __restrict__ in, float* __restrict__ out, int n,
                      const float* __restrict__ flagp){
  bool bf = *flagp > 0.5f;
  int i = blockIdx.x*blockDim.x + threadIdx.x;
  if (i < n) out[i] = rdv(in, i, bf);
}

// ---------------- NEW: wave-split LayerNorm, 64 pixels/block, 4 waves x 32 channels ----------------
// C must be 128. Param reads via FLAG/rdv (the proven-safe path).
__global__ __launch_bounds__(256) void ln2dw_k(
    const float* __restrict__ x, const void* __restrict__ g,
    const void* __restrict__ b, float* __restrict__ y,
    int C, int HW, const float* __restrict__ flagp)
{
  __shared__ float redS[4][64];
  __shared__ float redQ[4][64];
  bool bf = *flagp > 0.5f;
  int t = threadIdx.x, pix = t & 63, sub = t >> 6;
  int p  = blockIdx.x*64 + pix;
  int bb = blockIdx.y;
  const float* xb = x + (size_t)bb*C*HW + p;
  float xv[32];
  float s = 0.f, s2 = 0.f;
  #pragma unroll
  for (int i = 0; i < 32; i++){
    float v = xb[(size_t)(sub*32 + i)*HW];
    xv[i] = v; s += v; s2 += v*v;
  }
  redS[sub][pix] = s; redQ[sub][pix] = s2;
  __syncthreads();
  float st = redS[0][pix] + redS[1][pix] + redS[2][pix] + redS[3][pix];
  float qt = redQ[0][pix] + redQ[1][pix] + redQ[2][pix] + redQ[3][pix];
  float mu  = st / (float)C;
  float var = fmaxf(qt / (float)C - mu*mu, 0.f);
  float inv = rsqrtf(var + 1e-5f);
  float* yb = y + (size_t)bb*C*HW + p;
  #pragma unroll
  for (int i = 0; i < 32; i++){
    int c = sub*32 + i;
    yb[(size_t)c*HW] = (xv[i] - mu)*inv*rdv(g, c, bf) + rdv(b, c, bf);
  }
}

// ---------------- generic scalar 1x1 conv (proven; small NP cases) ----------------
__global__ void conv1x1_k(const float* __restrict__ in1, long in1_bs, int C1,
                          const float* __restrict__ in2, long in2_bs, int C2,
                          const void* __restrict__ w, const void* __restrict__ bias,
                          const float* __restrict__ res,
                          void* __restrict__ out, int to_out, int O, int NP, int act,
                          const float* __restrict__ flagp){
  bool bf = *flagp > 0.5f;
  int p = blockIdx.x*blockDim.x + threadIdx.x;
  if (p >= NP) return;
  int o = blockIdx.y, bb = blockIdx.z;
  size_t wrow = (size_t)o*(C1 + C2);
  float acc = bias ? rdv(bias, o, bf) : 0.f;
  const float* i1 = in1 + (size_t)bb*in1_bs + p;
  for (int c = 0; c < C1; c++) acc += rdv(w, wrow + c, bf) * i1[(size_t)c*NP];
  if (in2){
    const float* i2 = in2 + (size_t)bb*in2_bs + p;
    for (int c = 0; c < C2; c++) acc += rdv(w, wrow + C1 + c, bf) * i2[(size_t)c*NP];
  }
  if (act == 1) acc = gelu_f(acc);
  if (res) acc += res[((size_t)bb*O + o)*NP + p];
  size_t oi = ((size_t)bb*O + o)*NP + p;
  if (to_out){
    if (bf) ((bf16*)out)[oi] = __float2bfloat16(acc);
    else    ((float*)out)[oi] = acc;
  } else {
    ((float*)out)[oi] = acc;
  }
}

// ---------------- LDS-tiled conv GEMM (proven R17): 64 out-ch x 64 pixels per block ----------------
__global__ __launch_bounds__(256) void convtile_k(
    const float* __restrict__ in1, long in1_bs, int C1,
    const float* __restrict__ in2, long in2_bs, int C2,
    const void* __restrict__ w, const void* __restrict__ bias,
    const float* __restrict__ res, void* __restrict__ out, int to_out,
    int O, int NP, int act, const float* __restrict__ flagp)
{
  __shared__ __align__(16) float Xs[128*64];
  __shared__ __align__(16) float Wt[128*64];
  bool bf = *flagp > 0.5f;
  int tid = threadIdx.x;
  int p0 = blockIdx.x*64, o0 = blockIdx.y*64, bb = blockIdx.z;
  int CW = C1 + C2;
  int to = (tid >> 4)*4;
  int tp = (tid & 15)*4;
  float a[4][4];
  #pragma unroll
  for (int k = 0; k < 4; k++)
    #pragma unroll
    for (int j = 0; j < 4; j++) a[k][j] = 0.f;
  for (int cc = 0; cc < CW; cc += 128){
    for (int idx = tid; idx < 128*64; idx += 256){
      int c = idx >> 6, j = idx & 63;
      int gc = cc + c;
      float v;
      if (gc < C1) v = in1[(size_t)bb*in1_bs + (size_t)gc*NP + p0 + j];
      else         v = in2[(size_t)bb*in2_bs + (size_t)(gc - C1)*NP + p0 + j];
      Xs[idx] = v;
    }
    for (int idx = tid; idx < 128*64; idx += 256){
      int c = idx >> 6, i = idx & 63;
      Wt[idx] = rdv(w, (size_t)(o0 + i)*CW + cc + c, bf);
    }
    __syncthreads();
    for (int c = 0; c < 128; c++){
      float4 wv = *(const float4*)&Wt[c*64 + to];
      float4 xv = *(const float4*)&Xs[c*64 + tp];
      a[0][0] += wv.x*xv.x; a[0][1] += wv.x*xv.y; a[0][2] += wv.x*xv.z; a[0][3] += wv.x*xv.w;
      a[1][0] += wv.y*xv.x; a[1][1] += wv.y*xv.y; a[1][2] += wv.y*xv.z; a[1][3] += wv.y*xv.w;
      a[2][0] += wv.z*xv.x; a[2][1] += wv.z*xv.y; a[2][2] += wv.z*xv.z; a[2][3] += wv.z*xv.w;
      a[3][0] += wv.w*xv.x; a[3][1] += wv.w*xv.y; a[3][2] += wv.w*xv.z; a[3][3] += wv.w*xv.w;
    }
    __syncthreads();
  }
  #pragma unroll
  for (int k = 0; k < 4; k++){
    int o = o0 + to + k;
    size_t orow = ((size_t)bb*O + o)*NP + p0 + tp;
    float bv = bias ? rdv(bias, o, bf) : 0.f;
    float v0 = a[k][0] + bv, v1 = a[k][1] + bv, v2 = a[k][2] + bv, v3 = a[k][3] + bv;
    if (act == 1){ v0 = gelu_f(v0); v1 = gelu_f(v1); v2 = gelu_f(v2); v3 = gelu_f(v3); }
    if (res){
      float4 r = *(const float4*)&res[orow];
      v0 += r.x; v1 += r.y; v2 += r.z; v3 += r.w;
    }
    if (to_out && bf){
      bf16* ob = (bf16*)out + orow;
      ob[0] = __float2bfloat16(v0); ob[1] = __float2bfloat16(v1);
      ob[2] = __float2bfloat16(v2); ob[3] = __float2bfloat16(v3);
    } else {
      float4 v; v.x = v0; v.y = v1; v.z = v2; v.w = v3;
      *(float4*)((float*)out + orow) = v;
    }
  }
}

// ---------------- NEW: flat cosine attention, 2 queries per lane ----------------
// 128 queries/block (lane q and q+64); 4 waves split NK 4 ways; no-max softmax.
// NQ % 128 == 0, NK % 256 == 0, (NK/4) % CT == 0. Local attn: NQ=NK=2304.
__global__ __launch_bounds__(256) void flat_attn2_k(
    const float* __restrict__ Q, long qbs, int qoff,
    const float* __restrict__ KV, long kbs, int koff, int voff,
    float* __restrict__ Out, long obs, int NQ, int NK, float scale)
{
  __shared__ __align__(16) float Ks[4*CT*KP];   // 5120 floats
  __shared__ __align__(16) float Vs[4*CT*KP];
  __shared__ float Kn[4*CT];
  int t = threadIdx.x, lane = t & 63, wv = t >> 6;
  int h = blockIdx.y, bb = blockIdx.z;
  int qi0 = blockIdx.x*128 + lane;
  int qi1 = qi0 + 64;
  float qn0[16], qn1[16];
  float s0 = 0.f, s1 = 0.f;
  #pragma unroll
  for (int d = 0; d < 16; d++){
    size_t rowb = (size_t)bb*qbs + (size_t)(qoff + h*16 + d)*NQ;
    qn0[d] = Q[rowb + qi0];
    qn1[d] = Q[rowb + qi1];
    s0 += qn0[d]*qn0[d];
    s1 += qn1[d]*qn1[d];
  }
  float inv0 = scale / fmaxf(sqrtf(s0), 1e-12f);
  float inv1 = scale / fmaxf(sqrtf(s1), 1e-12f);
  #pragma unroll
  for (int d = 0; d < 16; d++){ qn0[d] *= inv0; qn1[d] *= inv1; }
  float acc0[16], acc1[16]; float l0 = 0.f, l1 = 0.f;
  #pragma unroll
  for (int d = 0; d < 16; d++){ acc0[d] = 0.f; acc1[d] = 0.f; }
  int chunk = NK >> 2;
  const float* kvb = KV + (size_t)bb*kbs;
  for (int t0 = 0; t0 < chunk; t0 += CT){
    for (int i = t; i < 4*CT*16; i += 256){
      int w2 = i >> 10;
      int r  = i & 1023;
      int pos = r & 63, d = r >> 6;
      size_t g = (size_t)(h*16 + d)*NK + (size_t)w2*chunk + t0 + pos;
      Ks[w2*CT*KP + pos*KP + d] = kvb[(size_t)koff*NK + g];
      Vs[w2*CT*KP + pos*KP + d] = kvb[(size_t)voff*NK + g];
    }
    __syncthreads();
    {
      float ss = 0.f;
      #pragma unroll
      for (int d = 0; d < 16; d++){ float v = Ks[wv*CT*KP + lane*KP + d]; ss += v*v; }
      Kn[wv*CT + lane] = 1.f / fmaxf(sqrtf(ss), 1e-12f);
    }
    __syncthreads();
    const float* ks = &Ks[wv*CT*KP];
    const float* vs = &Vs[wv*CT*KP];
    const float* kn = &Kn[wv*CT];
    for (int pos = 0; pos < CT; pos++){
      float4 a  = *(const float4*)&ks[pos*KP];
      float4 b4 = *(const float4*)&ks[pos*KP + 4];
      float4 c4 = *(const float4*)&ks[pos*KP + 8];
      float4 d4 = *(const float4*)&ks[pos*KP + 12];
      float dot0 = qn0[0]*a.x  + qn0[1]*a.y  + qn0[2]*a.z  + qn0[3]*a.w
                 + qn0[4]*b4.x + qn0[5]*b4.y + qn0[6]*b4.z + qn0[7]*b4.w
                 + qn0[8]*c4.x + qn0[9]*c4.y + qn0[10]*c4.z+ qn0[11]*c4.w
                 + qn0[12]*d4.x+ qn0[13]*d4.y+ qn0[14]*d4.z+ qn0[15]*d4.w;
      float dot1 = qn1[0]*a.x  + qn1[1]*a.y  + qn1[2]*a.z  + qn1[3]*a.w
                 + qn1[4]*b4.x + qn1[5]*b4.y + qn1[6]*b4.z + qn1[7]*b4.w
                 + qn1[8]*c4.x + qn1[9]*c4.y + qn1[10]*c4.z+ qn1[11]*c4.w
                 + qn1[12]*d4.x+ qn1[13]*d4.y+ qn1[14]*d4.z+ qn1[15]*d4.w;
      float kin = kn[pos];
      float pp0 = __expf(dot0 * kin);   // |logit| <= scale: no max needed
      float pp1 = __expf(dot1 * kin);
      l0 += pp0; l1 += pp1;
      float4 va = *(const float4*)&vs[pos*KP];
      float4 vb = *(const float4*)&vs[pos*KP + 4];
      float4 vc = *(const float4*)&vs[pos*KP + 8];
      float4 vd = *(const float4*)&vs[pos*KP + 12];
      acc0[0] += pp0*va.x; acc0[1] += pp0*va.y; acc0[2] += pp0*va.z; acc0[3] += pp0*va.w;
      acc0[4] += pp0*vb.x; acc0[5] += pp0*vb.y; acc0[6] += pp0*vb.z; acc0[7] += pp0*vb.w;
      acc0[8] += pp0*vc.x; acc0[9] += pp0*vc.y; acc0[10]+= pp0*vc.z; acc0[11]+= pp0*vc.w;
      acc0[12]+= pp0*vd.x; acc0[13]+= pp0*vd.y; acc0[14]+= pp0*vd.z; acc0[15]+= pp0*vd.w;
      acc1[0] += pp1*va.x; acc1[1] += pp1*va.y; acc1[2] += pp1*va.z; acc1[3] += pp1*va.w;
      acc1[4] += pp1*vb.x; acc1[5] += pp1*vb.y; acc1[6] += pp1*vb.z; acc1[7] += pp1*vb.w;
      acc1[8] += pp1*vc.x; acc1[9] += pp1*vc.y; acc1[10]+= pp1*vc.z; acc1[11]+= pp1*vc.w;
      acc1[12]+= pp1*vd.x; acc1[13]+= pp1*vd.y; acc1[14]+= pp1*vd.z; acc1[15]+= pp1*vd.w;
    }
    __syncthreads();
  }
  // combine: q0 partials in Ks slab, q1 partials in Vs slab (max idx 4351 < 5120)
  #pragma unroll
  for (int d = 0; d < 16; d++){
    Ks[(wv*64 + lane)*17 + d] = acc0[d];
    Vs[(wv*64 + lane)*17 + d] = acc1[d];
  }
  Ks[(wv*64 + lane)*17 + 16] = l0;
  Vs[(wv*64 + lane)*17 + 16] = l1;
  __syncthreads();
  if (wv == 0){
    float lt0 = 0.f, lt1 = 0.f;
    float at0[16], at1[16];
    #pragma unroll
    for (int d = 0; d < 16; d++){ at0[d] = 0.f; at1[d] = 0.f; }
    #pragma unroll
    for (int w2 = 0; w2 < 4; w2++){
      const float* p0 = &Ks[(w2*64 + lane)*17];
      const float* p1 = &Vs[(w2*64 + lane)*17];
      lt0 += p0[16]; lt1 += p1[16];
      #pragma unroll
      for (int d = 0; d < 16; d++){ at0[d] += p0[d]; at1[d] += p1[d]; }
    }
    float li0 = 1.f / fmaxf(lt0, 1e-30f);
    float li1 = 1.f / fmaxf(lt1, 1e-30f);
    #pragma unroll
    for (int d = 0; d < 16; d++){
      size_t rowb = (size_t)bb*obs + (size_t)(h*16 + d)*NQ;
      Out[rowb + qi0] = at0[d]*li0;
      Out[rowb + qi1] = at1[d]*li1;
    }
  }
}

// ---------------- attn4, no-max (proven; global attn NK=144 and xw attention NK=16) ----------------
__global__ __launch_bounds__(256) void attn4_k(
    const float* __restrict__ Q, long qbs, int qoff,
    const float* __restrict__ KV, long kbs, int koff, int voff,
    float* __restrict__ Out, long obs, int NQ, int NK, float scale)
{
  __shared__ __align__(16) float Ks[TK*KP];
  __shared__ __align__(16) float Vs[TK*KP];
  __shared__ float KnI[TK];
  int tid = threadIdx.x;
  int sub = tid & 3;
  int h = blockIdx.y, bb = blockIdx.z;
  int qi = blockIdx.x*64 + (tid >> 2);
  bool qv = qi < NQ;
  float qn[4] = {0,0,0,0}, acc[4] = {0,0,0,0};
  float l = 0.f;
  if (qv){
    float s = 0.f;
    #pragma unroll
    for (int j = 0; j < 4; j++){
      qn[j] = Q[(size_t)bb*qbs + (size_t)(qoff + h*16 + sub*4 + j)*NQ + qi];
      s += qn[j]*qn[j];
    }
    s += __shfl_xor(s, 1); s += __shfl_xor(s, 2);
    float inv = scale / fmaxf(sqrtf(s), 1e-12f);
    #pragma unroll
    for (int j = 0; j < 4; j++) qn[j] *= inv;
  }
  for (int k0 = 0; k0 < NK; k0 += TK){
    int lim = min(TK, NK - k0);
    for (int i = tid; i < 16*TK; i += 256){
      int pos = i & (TK-1), d = i >> 7;
      if (pos < lim){
        Ks[pos*KP + d] = KV[(size_t)bb*kbs + (size_t)(koff + h*16 + d)*NK + k0 + pos];
        Vs[pos*KP + d] = KV[(size_t)bb*kbs + (size_t)(voff + h*16 + d)*NK + k0 + pos];
      }
    }
    __syncthreads();
    if (tid < lim){
      float s = 0.f;
      #pragma unroll
      for (int d = 0; d < 16; d++){ float v = Ks[tid*KP + d]; s += v*v; }
      KnI[tid] = 1.f / fmaxf(sqrtf(s), 1e-12f);
    }
    __syncthreads();
    for (int pos = 0; pos < lim; pos++){
      float4 k4 = *(const float4*)&Ks[pos*KP + sub*4];
      float dd = qn[0]*k4.x + qn[1]*k4.y + qn[2]*k4.z + qn[3]*k4.w;
      dd += __shfl_xor(dd, 1); dd += __shfl_xor(dd, 2);
      float pp = __expf(dd * KnI[pos]);
      l += pp;
      float4 v4 = *(const float4*)&Vs[pos*KP + sub*4];
      acc[0] += pp*v4.x;
      acc[1] += pp*v4.y;
      acc[2] += pp*v4.z;
      acc[3] += pp*v4.w;
    }
    __syncthreads();
  }
  if (qv){
    float li = 1.f / fmaxf(l, 1e-30f);
    #pragma unroll
    for (int j = 0; j < 4; j++)
      Out[(size_t)bb*obs + (size_t)(h*16 + sub*4 + j)*NQ + qi] = acc[j]*li;
  }
}

// ---------------- latent-read attention, split-K partials (proven) ----------------
__global__ void latpart_k(const float* __restrict__ ql, const float* __restrict__ kvx,
                          long kbs, float* __restrict__ part, int NK, int S){
  int s = blockIdx.x, h = blockIdx.y, bb = blockIdx.z;
  int q = threadIdx.x;
  if (q >= 16) return;
  float qn[16]; float ss = 0.f;
  #pragma unroll
  for (int d = 0; d < 16; d++){
    qn[d] = ql[(size_t)bb*2048 + (size_t)(h*16+d)*16 + q];
    ss += qn[d]*qn[d];
  }
  float inv = 0.25f / fmaxf(sqrtf(ss), 1e-12f);
  #pragma unroll
  for (int d = 0; d < 16; d++) qn[d] *= inv;
  float m = MINIT, l = 0.f, acc[16];
  #pragma unroll
  for (int d = 0; d < 16; d++) acc[d] = 0.f;
  int chunk = NK / S;
  int k0 = s*chunk, k1 = k0 + chunk;
  const float* kb = kvx + (size_t)bb*kbs;
  for (int pos = k0; pos < k1; pos++){
    float kd[16]; float ks = 0.f;
    #pragma unroll
    for (int d = 0; d < 16; d++){
      kd[d] = kb[(size_t)(h*16+d)*NK + pos];
      ks += kd[d]*kd[d];
    }
    float kin = 1.f / fmaxf(sqrtf(ks), 1e-12f);
    float dot = 0.f;
    #pragma unroll
    for (int d = 0; d < 16; d++) dot += qn[d]*kd[d];
    float logit = dot * kin;
    float mn = fmaxf(m, logit);
    float r  = __expf(m - mn);
    float pp = __expf(logit - mn);
    l = l*r + pp; m = mn;
    #pragma unroll
    for (int d = 0; d < 16; d++)
      acc[d] = acc[d]*r + pp*kb[(size_t)(128 + h*16+d)*NK + pos];
  }
  size_t idx = (size_t)((((bb*8 + h)*16 + q)*S) + s)*18;
  part[idx] = m; part[idx+1] = l;
  #pragma unroll
  for (int d = 0; d < 16; d++) part[idx+2+d] = acc[d];
}

__global__ void latcomb_k(const float* __restrict__ part, float* __restrict__ latr, int S){
  int t = threadIdx.x;
  int q = t & 15, h = (t >> 4) & 7, bb = t >> 7;
  size_t base = (size_t)(((bb*8 + h)*16 + q)*S)*18;
  float M = MINIT;
  for (int s = 0; s < S; s++) M = fmaxf(M, part[base + (size_t)s*18]);
  float L = 0.f, acc[16];
  #pragma unroll
  for (int d = 0; d < 16; d++) acc[d] = 0.f;
  for (int s = 0; s < S; s++){
    const float* ps = part + base + (size_t)s*18;
    float w = __expf(ps[0] - M);
    L += ps[1]*w;
    #pragma unroll
    for (int d = 0; d < 16; d++) acc[d] += ps[2+d]*w;
  }
  float li = 1.f / fmaxf(L, 1e-30f);
  #pragma unroll
  for (int d = 0; d < 16; d++)
    latr[(size_t)bb*2048 + (size_t)(h*16+d)*16 + q] = acc[d]*li;
}

// ---------------- 4x4 mean pool (proven) ----------------
__global__ void pool4_k(const float* __restrict__ xn, float* __restrict__ xc){
  int i = blockIdx.x*blockDim.x + threadIdx.x;
  if (i >= 2*128*144) return;
  int pc = i % 144; int bc = i / 144;
  int hc = pc / 12, wc = pc % 12;
  const float* s = xn + (size_t)bc*2304 + hc*4*48 + wc*4;
  float acc = 0.f;
  #pragma unroll
  for (int r = 0; r < 4; r++)
    #pragma unroll
    for (int c2 = 0; c2 < 4; c2++) acc += s[r*48 + c2];
  xc[i] = acc * 0.0625f;
}

// ---------------- bilinear upsample 12->48 (proven) ----------------
__global__ void ups_k(const float* __restrict__ g, float* __restrict__ out){
  int i = blockIdx.x*blockDim.x + threadIdx.x;
  if (i >= 2*128*2304) return;
  int p = i % 2304; int bc = i / 2304;
  int h = p / 48, w = p % 48;
  float sh = h*0.25f - 0.375f;
  float sw = w*0.25f - 0.375f;
  float fh0 = floorf(sh), fw0 = floorf(sw);
  float fh = sh - fh0, fw = sw - fw0;
  int h0 = (int)fh0, w0 = (int)fw0;
  int h0c = min(11, max(0, h0)),   h1c = min(11, max(0, h0+1));
  int w0c = min(11, max(0, w0)),   w1c = min(11, max(0, w0+1));
  const float* s = g + (size_t)bc*144;
  float v00 = s[h0c*12 + w0c], v01 = s[h0c*12 + w1c];
  float v10 = s[h1c*12 + w0c], v11 = s[h1c*12 + w1c];
  out[i] = (1.f-fh)*((1.f-fw)*v00 + fw*v01) + fh*((1.f-fw)*v10 + fw*v11);
}

extern "C" void kernel_launch(void* const* d_in, const int* in_sizes, int n_in,
                              void* d_out, int out_size, void* d_ws, size_t ws_size,
                              hipStream_t stream){
  const int B = 2, C = 128, HW = 2304;
  const void* x_in        = d_in[0];
  const void* g1          = d_in[1];
  const void* b1          = d_in[2];
  const void* loc_qkv_w   = d_in[3];
  const void* loc_proj_w  = d_in[4];
  const void* loc_proj_b  = d_in[5];
  const void* glob_qkv_w  = d_in[6];
  const void* glob_proj_w = d_in[7];
  const void* glob_proj_b = d_in[8];
  const void* fuse_w1     = d_in[9];
  const void* fuse_b1     = d_in[10];
  const void* fuse_w2     = d_in[11];
  const void* fuse_b2     = d_in[12];
  const void* glat        = d_in[13];
  const void* blat        = d_in[14];
  const void* latents     = d_in[15];
  const void* qlat_w      = d_in[16];
  const void* kvx_w       = d_in[17];
  const void* qx_w        = d_in[18];
  const void* kvlat_w     = d_in[19];
  const void* lat_proj_w  = d_in[20];
  const void* lat_proj_b  = d_in[21];
  const void* g2          = d_in[22];
  const void* b2          = d_in[23];
  const void* ffn_w1      = d_in[24];
  const void* ffn_b1      = d_in[25];
  const void* ffn_w2      = d_in[26];
  const void* ffn_b2      = d_in[27];

  // ---- workspace layout VERBATIM (R8..R17) ----
  float* ws = (float*)d_ws;
  float* P  = ws + 0;
  float* N  = ws + 589824;
  float* A  = ws + 1179648;
  float* Q  = ws + 1769472;
  float* FLAG = ws + 4128768;

  float* qkv   = Q;                 // 1,769,472
  float* L     = Q + 1769472;       // 589,824
  float* xc    = Q;
  float* qkvc  = Q + 36864;
  float* gatt  = Q + 147456;
  float* gproj = Q + 184320;
  float* kvx   = Q;                 // 1,179,648
  float* latf  = Q + 1179648;
  float* qlat  = Q + 1181696;
  float* latr  = Q + 1185792;
  float* kvlat = Q + 1189888;
  float* part  = Q + 1198080;       // 221,184 (S=48)
  float* ffh   = Q;                 // 2,359,296

  dim3 blk(256);

  detect_k<<<1, 64, 0, stream>>>(x_in, FLAG);
  cvt_k<<<2304, blk, 0, stream>>>(x_in, P, 589824, FLAG);

  // ---- BioAttentionFusion branch ----
  ln2dw_k<<<dim3(36,B), blk, 0, stream>>>(P, g1, b1, N, C, HW, FLAG);
  convtile_k<<<dim3(36,6,B), blk, 0, stream>>>(N,(long)C*HW,C, nullptr,0,0, loc_qkv_w,nullptr,nullptr, qkv,0,384,HW,0, FLAG);
  flat_attn2_k<<<dim3(18,8,B), blk, 0, stream>>>(qkv,(long)384*HW,0, qkv,(long)384*HW,128,256, A,(long)C*HW, HW,HW,0.25f);
  convtile_k<<<dim3(36,2,B), blk, 0, stream>>>(A,(long)C*HW,C, nullptr,0,0, loc_proj_w,loc_proj_b,nullptr, L,0,C,HW,0, FLAG);
  pool4_k<<<144, blk, 0, stream>>>(N, xc);
  conv1x1_k<<<dim3(1,384,B), blk, 0, stream>>>(xc,(long)C*144,C, nullptr,0,0, glob_qkv_w,nullptr,nullptr, qkvc,0,384,144,0, FLAG);
  attn4_k<<<dim3(3,8,B), blk, 0, stream>>>(qkvc,(long)384*144,0, qkvc,(long)384*144,128,256, gatt,(long)C*144, 144,144,0.25f);
  conv1x1_k<<<dim3(1,128,B), blk, 0, stream>>>(gatt,(long)C*144,C, nullptr,0,0, glob_proj_w,glob_proj_b,nullptr, gproj,0,C,144,0, FLAG);
  ups_k<<<2304, blk, 0, stream>>>(gproj, A);                                          // A = upsampled global
  convtile_k<<<dim3(36,2,B), blk, 0, stream>>>(L,(long)C*HW,C, A,(long)C*HW,C, fuse_w1,fuse_b1,nullptr, N,0,C,HW,1, FLAG);  // N = gelu(fuse1)
  convtile_k<<<dim3(36,2,B), blk, 0, stream>>>(N,(long)C*HW,C, nullptr,0,0, fuse_w2,fuse_b2,P, P,0,C,HW,0, FLAG);           // P = x + f

  // ---- LatentMixer branch ----
  ln2dw_k<<<dim3(36,B), blk, 0, stream>>>(P, glat, blat, N, C, HW, FLAG);
  convtile_k<<<dim3(36,4,B), blk, 0, stream>>>(N,(long)C*HW,C, nullptr,0,0, kvx_w,nullptr,nullptr, kvx,0,256,HW,0, FLAG);
  convtile_k<<<dim3(36,2,B), blk, 0, stream>>>(N,(long)C*HW,C, nullptr,0,0, qx_w,nullptr,nullptr, A,0,C,HW,0, FLAG);        // A = qx
  cvt_k<<<8, blk, 0, stream>>>(latents, latf, 2048, FLAG);
  conv1x1_k<<<dim3(1,128,B), blk, 0, stream>>>(latf,0L,C, nullptr,0,0, qlat_w,nullptr,nullptr, qlat,0,C,16,0, FLAG);
  latpart_k<<<dim3(48,8,B), 64, 0, stream>>>(qlat, kvx, (long)256*HW, part, HW, 48);
  latcomb_k<<<1, blk, 0, stream>>>(part, latr, 48);
  conv1x1_k<<<dim3(1,256,B), blk, 0, stream>>>(latr,(long)C*16,C, nullptr,0,0, kvlat_w,nullptr,nullptr, kvlat,0,256,16,0, FLAG);
  attn4_k<<<dim3(36,8,B), blk, 0, stream>>>(A,(long)C*HW,0, kvlat,(long)256*16,0,128, N,(long)C*HW, HW,16,0.25f);           // N = xw
  convtile_k<<<dim3(36,2,B), blk, 0, stream>>>(N,(long)C*HW,C, nullptr,0,0, lat_proj_w,lat_proj_b,P, P,0,C,HW,0, FLAG);     // P = x2

  // ---- FFN branch ----
  ln2dw_k<<<dim3(36,B), blk, 0, stream>>>(P, g2, b2, N, C, HW, FLAG);
  convtile_k<<<dim3(36,8,B), blk, 0, stream>>>(N,(long)C*HW,C, nullptr,0,0, ffn_w1,ffn_b1,nullptr, ffh,0,512,HW,1, FLAG);
  convtile_k<<<dim3(36,2,B), blk, 0, stream>>>(ffh,(long)512*HW,512, nullptr,0,0, ffn_w2,ffn_b2,P, d_out,1,C,HW,0, FLAG);
}

// Round 19
// 782.085 us; speedup vs baseline: 4.3239x; 1.0411x over previous
//
#include <hip/hip_runtime.h>
#include <hip/hip_bf16.h>

typedef __hip_bfloat16 bf16;

#define HD 16
#define TK 128
#define KP 20            // attn LDS pitch: 16 dims + 4 pad, keeps float4 16B-aligned
#define CT8 32           // flat_attn8 tile positions per wave-chunk
#define MINIT (-1e30f)

__device__ __forceinline__ float b2f(bf16 v){ return __bfloat162float(v); }
__device__ __forceinline__ float gelu_f(float x){ return 0.5f*x*(1.0f+erff(x*0.70710678118654752f)); }
__device__ __forceinline__ float rdv(const void* p, size_t i, bool bf){
  return bf ? b2f(((const bf16*)p)[i]) : ((const float*)p)[i];
}

// ---------------- dtype detector (proven) ----------------
__global__ void detect_k(const void* __restrict__ x, float* __restrict__ flag){
  if (threadIdx.x == 0 && blockIdx.x == 0){
    const float* xf = (const float*)x;
    const bf16*  xb = (const bf16*)x;
    double sF = 0.0, sB = 0.0;
    for (int i = 0; i < 512; i++){ float v = fabsf(xf[i]);     if (!(v < 1e30f)) v = 1e30f; sF += v; }
    for (int i = 0; i < 1024; i++){ float v = fabsf(b2f(xb[i])); if (!(v < 1e30f)) v = 1e30f; sB += v; }
    float mF = (float)(sF/512.0), mB = (float)(sB/1024.0);
    float dF = fabsf(logf(fmaxf(mF, 1e-30f)));
    float dB = fabsf(logf(fmaxf(mB, 1e-30f)));
    *flag = (dB <= dF) ? 1.0f : 0.0f;
  }
}

// ---------------- input -> fp32 convert (proven) ----------------
__global__ void cvt_k(const void* __restrict__ in, float* __restrict__ out, int n,
                      const float* __restrict__ flagp){
  bool bf = *flagp > 0.5f;
  int i = blockIdx.x*blockDim.x + threadIdx.x;
  if (i < n) out[i] = rdv(in, i, bf);
}

// ---------------- wave-split LayerNorm (proven R18) ----------------
__global__ __launch_bounds__(256) void ln2dw_k(
    const float* __restrict__ x, const void* __restrict__ g,
    const void* __restrict__ b, float* __restrict__ y,
    int C, int HW, const float* __restrict__ flagp)
{
  __shared__ float redS[4][64];
  __shared__ float redQ[4][64];
  bool bf = *flagp > 0.5f;
  int t = threadIdx.x, pix = t & 63, sub = t >> 6;
  int p  = blockIdx.x*64 + pix;
  int bb = blockIdx.y;
  const float* xb = x + (size_t)bb*C*HW + p;
  float xv[32];
  float s = 0.f, s2 = 0.f;
  #pragma unroll
  for (int i = 0; i < 32; i++){
    float v = xb[(size_t)(sub*32 + i)*HW];
    xv[i] = v; s += v; s2 += v*v;
  }
  redS[sub][pix] = s; redQ[sub][pix] = s2;
  __syncthreads();
  float st = redS[0][pix] + redS[1][pix] + redS[2][pix] + redS[3][pix];
  float qt = redQ[0][pix] + redQ[1][pix] + redQ[2][pix] + redQ[3][pix];
  float mu  = st / (float)C;
  float var = fmaxf(qt / (float)C - mu*mu, 0.f);
  float inv = rsqrtf(var + 1e-5f);
  float* yb = y + (size_t)bb*C*HW + p;
  #pragma unroll
  for (int i = 0; i < 32; i++){
    int c = sub*32 + i;
    yb[(size_t)c*HW] = (xv[i] - mu)*inv*rdv(g, c, bf) + rdv(b, c, bf);
  }
}

// ---------------- generic scalar 1x1 conv (proven; small NP cases) ----------------
__global__ void conv1x1_k(const float* __restrict__ in1, long in1_bs, int C1,
                          const float* __restrict__ in2, long in2_bs, int C2,
                          const void* __restrict__ w, const void* __restrict__ bias,
                          const float* __restrict__ res,
                          void* __restrict__ out, int to_out, int O, int NP, int act,
                          const float* __restrict__ flagp){
  bool bf = *flagp > 0.5f;
  int p = blockIdx.x*blockDim.x + threadIdx.x;
  if (p >= NP) return;
  int o = blockIdx.y, bb = blockIdx.z;
  size_t wrow = (size_t)o*(C1 + C2);
  float acc = bias ? rdv(bias, o, bf) : 0.f;
  const float* i1 = in1 + (size_t)bb*in1_bs + p;
  for (int c = 0; c < C1; c++) acc += rdv(w, wrow + c, bf) * i1[(size_t)c*NP];
  if (in2){
    const float* i2 = in2 + (size_t)bb*in2_bs + p;
    for (int c = 0; c < C2; c++) acc += rdv(w, wrow + C1 + c, bf) * i2[(size_t)c*NP];
  }
  if (act == 1) acc = gelu_f(acc);
  if (res) acc += res[((size_t)bb*O + o)*NP + p];
  size_t oi = ((size_t)bb*O + o)*NP + p;
  if (to_out){
    if (bf) ((bf16*)out)[oi] = __float2bfloat16(acc);
    else    ((float*)out)[oi] = acc;
  } else {
    ((float*)out)[oi] = acc;
  }
}

// ---------------- LDS-tiled conv GEMM (proven R17/R18) ----------------
__global__ __launch_bounds__(256) void convtile_k(
    const float* __restrict__ in1, long in1_bs, int C1,
    const float* __restrict__ in2, long in2_bs, int C2,
    const void* __restrict__ w, const void* __restrict__ bias,
    const float* __restrict__ res, void* __restrict__ out, int to_out,
    int O, int NP, int act, const float* __restrict__ flagp)
{
  __shared__ __align__(16) float Xs[128*64];
  __shared__ __align__(16) float Wt[128*64];
  bool bf = *flagp > 0.5f;
  int tid = threadIdx.x;
  int p0 = blockIdx.x*64, o0 = blockIdx.y*64, bb = blockIdx.z;
  int CW = C1 + C2;
  int to = (tid >> 4)*4;
  int tp = (tid & 15)*4;
  float a[4][4];
  #pragma unroll
  for (int k = 0; k < 4; k++)
    #pragma unroll
    for (int j = 0; j < 4; j++) a[k][j] = 0.f;
  for (int cc = 0; cc < CW; cc += 128){
    for (int idx = tid; idx < 128*64; idx += 256){
      int c = idx >> 6, j = idx & 63;
      int gc = cc + c;
      float v;
      if (gc < C1) v = in1[(size_t)bb*in1_bs + (size_t)gc*NP + p0 + j];
      else         v = in2[(size_t)bb*in2_bs + (size_t)(gc - C1)*NP + p0 + j];
      Xs[idx] = v;
    }
    for (int idx = tid; idx < 128*64; idx += 256){
      int c = idx >> 6, i = idx & 63;
      Wt[idx] = rdv(w, (size_t)(o0 + i)*CW + cc + c, bf);
    }
    __syncthreads();
    for (int c = 0; c < 128; c++){
      float4 wv = *(const float4*)&Wt[c*64 + to];
      float4 xv = *(const float4*)&Xs[c*64 + tp];
      a[0][0] += wv.x*xv.x; a[0][1] += wv.x*xv.y; a[0][2] += wv.x*xv.z; a[0][3] += wv.x*xv.w;
      a[1][0] += wv.y*xv.x; a[1][1] += wv.y*xv.y; a[1][2] += wv.y*xv.z; a[1][3] += wv.y*xv.w;
      a[2][0] += wv.z*xv.x; a[2][1] += wv.z*xv.y; a[2][2] += wv.z*xv.z; a[2][3] += wv.z*xv.w;
      a[3][0] += wv.w*xv.x; a[3][1] += wv.w*xv.y; a[3][2] += wv.w*xv.z; a[3][3] += wv.w*xv.w;
    }
    __syncthreads();
  }
  #pragma unroll
  for (int k = 0; k < 4; k++){
    int o = o0 + to + k;
    size_t orow = ((size_t)bb*O + o)*NP + p0 + tp;
    float bv = bias ? rdv(bias, o, bf) : 0.f;
    float v0 = a[k][0] + bv, v1 = a[k][1] + bv, v2 = a[k][2] + bv, v3 = a[k][3] + bv;
    if (act == 1){ v0 = gelu_f(v0); v1 = gelu_f(v1); v2 = gelu_f(v2); v3 = gelu_f(v3); }
    if (res){
      float4 r = *(const float4*)&res[orow];
      v0 += r.x; v1 += r.y; v2 += r.z; v3 += r.w;
    }
    if (to_out && bf){
      bf16* ob = (bf16*)out + orow;
      ob[0] = __float2bfloat16(v0); ob[1] = __float2bfloat16(v1);
      ob[2] = __float2bfloat16(v2); ob[3] = __float2bfloat16(v3);
    } else {
      float4 v; v.x = v0; v.y = v1; v.z = v2; v.w = v3;
      *(float4*)((float*)out + orow) = v;
    }
  }
}

// ---------------- DELTA: flat cosine attention, 8-wave split-K, 64 queries/block ----------------
// 512 threads; wave wv owns NK/8 positions in CT8=32 tiles. No-max softmax (|logit|<=scale).
// NQ % 64 == 0, NK % 8 == 0, (NK/8) % 32 == 0. Local attn: NQ=NK=2304.
__global__ __launch_bounds__(512) void flat_attn8_k(
    const float* __restrict__ Q, long qbs, int qoff,
    const float* __restrict__ KV, long kbs, int koff, int voff,
    float* __restrict__ Out, long obs, int NQ, int NK, float scale)
{
  __shared__ __align__(16) float Ks[8*CT8*KP];   // 5120 floats
  __shared__ __align__(16) float Vs[8*CT8*KP];
  __shared__ float Kn[8*CT8];
  int t = threadIdx.x, lane = t & 63, wv = t >> 6;   // 8 waves
  int h = blockIdx.y, bb = blockIdx.z;
  int qi = blockIdx.x*64 + lane;
  float qn[16]; float s = 0.f;
  #pragma unroll
  for (int d = 0; d < 16; d++){
    qn[d] = Q[(size_t)bb*qbs + (size_t)(qoff + h*16 + d)*NQ + qi];
    s += qn[d]*qn[d];
  }
  float inv = scale / fmaxf(sqrtf(s), 1e-12f);
  #pragma unroll
  for (int d = 0; d < 16; d++) qn[d] *= inv;
  float acc[16]; float l = 0.f;
  #pragma unroll
  for (int d = 0; d < 16; d++) acc[d] = 0.f;
  int chunk = NK >> 3;
  const float* kvb = KV + (size_t)bb*kbs;
  for (int t0 = 0; t0 < chunk; t0 += CT8){
    // stage 8 per-wave tiles (8*32*16 = 4096 elems per array; 512 threads -> 8 each)
    for (int i = t; i < 8*CT8*16; i += 512){
      int w2 = i >> 9;             // 32*16 = 512 per slab
      int r  = i & 511;
      int pos = r & 31, d = r >> 5;
      size_t g = (size_t)(h*16 + d)*NK + (size_t)w2*chunk + t0 + pos;
      Ks[w2*CT8*KP + pos*KP + d] = kvb[(size_t)koff*NK + g];
      Vs[w2*CT8*KP + pos*KP + d] = kvb[(size_t)voff*NK + g];
    }
    __syncthreads();
    if (lane < CT8){
      float ss = 0.f;
      #pragma unroll
      for (int d = 0; d < 16; d++){ float v = Ks[wv*CT8*KP + lane*KP + d]; ss += v*v; }
      Kn[wv*CT8 + lane] = 1.f / fmaxf(sqrtf(ss), 1e-12f);
    }
    __syncthreads();
    const float* ks = &Ks[wv*CT8*KP];
    const float* vs = &Vs[wv*CT8*KP];
    const float* kn = &Kn[wv*CT8];
    for (int pos = 0; pos < CT8; pos++){
      float4 a  = *(const float4*)&ks[pos*KP];
      float4 b4 = *(const float4*)&ks[pos*KP + 4];
      float4 c4 = *(const float4*)&ks[pos*KP + 8];
      float4 d4 = *(const float4*)&ks[pos*KP + 12];
      float dot = qn[0]*a.x  + qn[1]*a.y  + qn[2]*a.z  + qn[3]*a.w
                + qn[4]*b4.x + qn[5]*b4.y + qn[6]*b4.z + qn[7]*b4.w
                + qn[8]*c4.x + qn[9]*c4.y + qn[10]*c4.z+ qn[11]*c4.w
                + qn[12]*d4.x+ qn[13]*d4.y+ qn[14]*d4.z+ qn[15]*d4.w;
      float pp = __expf(dot * kn[pos]);
      l += pp;
      float4 va = *(const float4*)&vs[pos*KP];
      float4 vb = *(const float4*)&vs[pos*KP + 4];
      float4 vc = *(const float4*)&vs[pos*KP + 8];
      float4 vd = *(const float4*)&vs[pos*KP + 12];
      acc[0] += pp*va.x; acc[1] += pp*va.y; acc[2] += pp*va.z; acc[3] += pp*va.w;
      acc[4] += pp*vb.x; acc[5] += pp*vb.y; acc[6] += pp*vb.z; acc[7] += pp*vb.w;
      acc[8] += pp*vc.x; acc[9] += pp*vc.y; acc[10]+= pp*vc.z; acc[11]+= pp*vc.w;
      acc[12]+= pp*vd.x; acc[13]+= pp*vd.y; acc[14]+= pp*vd.z; acc[15]+= pp*vd.w;
    }
    __syncthreads();
  }
  // combine 8 wave-partials: waves 0-3 in Ks slab, 4-7 in Vs slab (max idx 4351 < 5120)
  {
    int slot = (wv & 3)*64 + lane;
    float* slab = (wv < 4) ? Ks : Vs;
    #pragma unroll
    for (int d = 0; d < 16; d++) slab[slot*17 + d] = acc[d];
    slab[slot*17 + 16] = l;
  }
  __syncthreads();
  if (wv == 0){
    float lt = 0.f; float at[16];
    #pragma unroll
    for (int d = 0; d < 16; d++) at[d] = 0.f;
    #pragma unroll
    for (int w2 = 0; w2 < 4; w2++){
      const float* p0 = &Ks[(w2*64 + lane)*17];
      const float* p1 = &Vs[(w2*64 + lane)*17];
      lt += p0[16] + p1[16];
      #pragma unroll
      for (int d = 0; d < 16; d++) at[d] += p0[d] + p1[d];
    }
    float li = 1.f / fmaxf(lt, 1e-30f);
    #pragma unroll
    for (int d = 0; d < 16; d++)
      Out[(size_t)bb*obs + (size_t)(h*16 + d)*NQ + qi] = at[d]*li;
  }
}

// ---------------- attn4, no-max (proven; global attn NK=144 and xw attention NK=16) ----------------
__global__ __launch_bounds__(256) void attn4_k(
    const float* __restrict__ Q, long qbs, int qoff,
    const float* __restrict__ KV, long kbs, int koff, int voff,
    float* __restrict__ Out, long obs, int NQ, int NK, float scale)
{
  __shared__ __align__(16) float Ks[TK*KP];
  __shared__ __align__(16) float Vs[TK*KP];
  __shared__ float KnI[TK];
  int tid = threadIdx.x;
  int sub = tid & 3;
  int h = blockIdx.y, bb = blockIdx.z;
  int qi = blockIdx.x*64 + (tid >> 2);
  bool qv = qi < NQ;
  float qn[4] = {0,0,0,0}, acc[4] = {0,0,0,0};
  float l = 0.f;
  if (qv){
    float s = 0.f;
    #pragma unroll
    for (int j = 0; j < 4; j++){
      qn[j] = Q[(size_t)bb*qbs + (size_t)(qoff + h*16 + sub*4 + j)*NQ + qi];
      s += qn[j]*qn[j];
    }
    s += __shfl_xor(s, 1); s += __shfl_xor(s, 2);
    float inv = scale / fmaxf(sqrtf(s), 1e-12f);
    #pragma unroll
    for (int j = 0; j < 4; j++) qn[j] *= inv;
  }
  for (int k0 = 0; k0 < NK; k0 += TK){
    int lim = min(TK, NK - k0);
    for (int i = tid; i < 16*TK; i += 256){
      int pos = i & (TK-1), d = i >> 7;
      if (pos < lim){
        Ks[pos*KP + d] = KV[(size_t)bb*kbs + (size_t)(koff + h*16 + d)*NK + k0 + pos];
        Vs[pos*KP + d] = KV[(size_t)bb*kbs + (size_t)(voff + h*16 + d)*NK + k0 + pos];
      }
    }
    __syncthreads();
    if (tid < lim){
      float s = 0.f;
      #pragma unroll
      for (int d = 0; d < 16; d++){ float v = Ks[tid*KP + d]; s += v*v; }
      KnI[tid] = 1.f / fmaxf(sqrtf(s), 1e-12f);
    }
    __syncthreads();
    for (int pos = 0; pos < lim; pos++){
      float4 k4 = *(const float4*)&Ks[pos*KP + sub*4];
      float dd = qn[0]*k4.x + qn[1]*k4.y + qn[2]*k4.z + qn[3]*k4.w;
      dd += __shfl_xor(dd, 1); dd += __shfl_xor(dd, 2);
      float pp = __expf(dd * KnI[pos]);
      l += pp;
      float4 v4 = *(const float4*)&Vs[pos*KP + sub*4];
      acc[0] += pp*v4.x;
      acc[1] += pp*v4.y;
      acc[2] += pp*v4.z;
      acc[3] += pp*v4.w;
    }
    __syncthreads();
  }
  if (qv){
    float li = 1.f / fmaxf(l, 1e-30f);
    #pragma unroll
    for (int j = 0; j < 4; j++)
      Out[(size_t)bb*obs + (size_t)(h*16 + sub*4 + j)*NQ + qi] = acc[j]*li;
  }
}

// ---------------- latent-read attention, split-K partials (proven) ----------------
__global__ void latpart_k(const float* __restrict__ ql, const float* __restrict__ kvx,
                          long kbs, float* __restrict__ part, int NK, int S){
  int s = blockIdx.x, h = blockIdx.y, bb = blockIdx.z;
  int q = threadIdx.x;
  if (q >= 16) return;
  float qn[16]; float ss = 0.f;
  #pragma unroll
  for (int d = 0; d < 16; d++){
    qn[d] = ql[(size_t)bb*2048 + (size_t)(h*16+d)*16 + q];
    ss += qn[d]*qn[d];
  }
  float inv = 0.25f / fmaxf(sqrtf(ss), 1e-12f);
  #pragma unroll
  for (int d = 0; d < 16; d++) qn[d] *= inv;
  float m = MINIT, l = 0.f, acc[16];
  #pragma unroll
  for (int d = 0; d < 16; d++) acc[d] = 0.f;
  int chunk = NK / S;
  int k0 = s*chunk, k1 = k0 + chunk;
  const float* kb = kvx + (size_t)bb*kbs;
  for (int pos = k0; pos < k1; pos++){
    float kd[16]; float ks = 0.f;
    #pragma unroll
    for (int d = 0; d < 16; d++){
      kd[d] = kb[(size_t)(h*16+d)*NK + pos];
      ks += kd[d]*kd[d];
    }
    float kin = 1.f / fmaxf(sqrtf(ks), 1e-12f);
    float dot = 0.f;
    #pragma unroll
    for (int d = 0; d < 16; d++) dot += qn[d]*kd[d];
    float logit = dot * kin;
    float mn = fmaxf(m, logit);
    float r  = __expf(m - mn);
    float pp = __expf(logit - mn);
    l = l*r + pp; m = mn;
    #pragma unroll
    for (int d = 0; d < 16; d++)
      acc[d] = acc[d]*r + pp*kb[(size_t)(128 + h*16+d)*NK + pos];
  }
  size_t idx = (size_t)((((bb*8 + h)*16 + q)*S) + s)*18;
  part[idx] = m; part[idx+1] = l;
  #pragma unroll
  for (int d = 0; d < 16; d++) part[idx+2+d] = acc[d];
}

__global__ void latcomb_k(const float* __restrict__ part, float* __restrict__ latr, int S){
  int t = threadIdx.x;
  int q = t & 15, h = (t >> 4) & 7, bb = t >> 7;
  size_t base = (size_t)(((bb*8 + h)*16 + q)*S)*18;
  float M = MINIT;
  for (int s = 0; s < S; s++) M = fmaxf(M, part[base + (size_t)s*18]);
  float L = 0.f, acc[16];
  #pragma unroll
  for (int d = 0; d < 16; d++) acc[d] = 0.f;
  for (int s = 0; s < S; s++){
    const float* ps = part + base + (size_t)s*18;
    float w = __expf(ps[0] - M);
    L += ps[1]*w;
    #pragma unroll
    for (int d = 0; d < 16; d++) acc[d] += ps[2+d]*w;
  }
  float li = 1.f / fmaxf(L, 1e-30f);
  #pragma unroll
  for (int d = 0; d < 16; d++)
    latr[(size_t)bb*2048 + (size_t)(h*16+d)*16 + q] = acc[d]*li;
}

// ---------------- 4x4 mean pool (proven) ----------------
__global__ void pool4_k(const float* __restrict__ xn, float* __restrict__ xc){
  int i = blockIdx.x*blockDim.x + threadIdx.x;
  if (i >= 2*128*144) return;
  int pc = i % 144; int bc = i / 144;
  int hc = pc / 12, wc = pc % 12;
  const float* s = xn + (size_t)bc*2304 + hc*4*48 + wc*4;
  float acc = 0.f;
  #pragma unroll
  for (int r = 0; r < 4; r++)
    #pragma unroll
    for (int c2 = 0; c2 < 4; c2++) acc += s[r*48 + c2];
  xc[i] = acc * 0.0625f;
}

// ---------------- bilinear upsample 12->48 (proven) ----------------
__global__ void ups_k(const float* __restrict__ g, float* __restrict__ out){
  int i = blockIdx.x*blockDim.x + threadIdx.x;
  if (i >= 2*128*2304) return;
  int p = i % 2304; int bc = i / 2304;
  int h = p / 48, w = p % 48;
  float sh = h*0.25f - 0.375f;
  float sw = w*0.25f - 0.375f;
  float fh0 = floorf(sh), fw0 = floorf(sw);
  float fh = sh - fh0, fw = sw - fw0;
  int h0 = (int)fh0, w0 = (int)fw0;
  int h0c = min(11, max(0, h0)),   h1c = min(11, max(0, h0+1));
  int w0c = min(11, max(0, w0)),   w1c = min(11, max(0, w0+1));
  const float* s = g + (size_t)bc*144;
  float v00 = s[h0c*12 + w0c], v01 = s[h0c*12 + w1c];
  float v10 = s[h1c*12 + w0c], v11 = s[h1c*12 + w1c];
  out[i] = (1.f-fh)*((1.f-fw)*v00 + fw*v01) + fh*((1.f-fw)*v10 + fw*v11);
}

extern "C" void kernel_launch(void* const* d_in, const int* in_sizes, int n_in,
                              void* d_out, int out_size, void* d_ws, size_t ws_size,
                              hipStream_t stream){
  const int B = 2, C = 128, HW = 2304;
  const void* x_in        = d_in[0];
  const void* g1          = d_in[1];
  const void* b1          = d_in[2];
  const void* loc_qkv_w   = d_in[3];
  const void* loc_proj_w  = d_in[4];
  const void* loc_proj_b  = d_in[5];
  const void* glob_qkv_w  = d_in[6];
  const void* glob_proj_w = d_in[7];
  const void* glob_proj_b = d_in[8];
  const void* fuse_w1     = d_in[9];
  const void* fuse_b1     = d_in[10];
  const void* fuse_w2     = d_in[11];
  const void* fuse_b2     = d_in[12];
  const void* glat        = d_in[13];
  const void* blat        = d_in[14];
  const void* latents     = d_in[15];
  const void* qlat_w      = d_in[16];
  const void* kvx_w       = d_in[17];
  const void* qx_w        = d_in[18];
  const void* kvlat_w     = d_in[19];
  const void* lat_proj_w  = d_in[20];
  const void* lat_proj_b  = d_in[21];
  const void* g2          = d_in[22];
  const void* b2          = d_in[23];
  const void* ffn_w1      = d_in[24];
  const void* ffn_b1      = d_in[25];
  const void* ffn_w2      = d_in[26];
  const void* ffn_b2      = d_in[27];

  // ---- workspace layout VERBATIM (R8..R18) ----
  float* ws = (float*)d_ws;
  float* P  = ws + 0;
  float* N  = ws + 589824;
  float* A  = ws + 1179648;
  float* Q  = ws + 1769472;
  float* FLAG = ws + 4128768;

  float* qkv   = Q;                 // 1,769,472
  float* L     = Q + 1769472;       // 589,824
  float* xc    = Q;
  float* qkvc  = Q + 36864;
  float* gatt  = Q + 147456;
  float* gproj = Q + 184320;
  float* kvx   = Q;                 // 1,179,648
  float* latf  = Q + 1179648;
  float* qlat  = Q + 1181696;
  float* latr  = Q + 1185792;
  float* kvlat = Q + 1189888;
  float* part  = Q + 1198080;       // 221,184 (S=48)
  float* ffh   = Q;                 // 2,359,296

  dim3 blk(256);
  dim3 blk512(512);

  detect_k<<<1, 64, 0, stream>>>(x_in, FLAG);
  cvt_k<<<2304, blk, 0, stream>>>(x_in, P, 589824, FLAG);

  // ---- BioAttentionFusion branch ----
  ln2dw_k<<<dim3(36,B), blk, 0, stream>>>(P, g1, b1, N, C, HW, FLAG);
  convtile_k<<<dim3(36,6,B), blk, 0, stream>>>(N,(long)C*HW,C, nullptr,0,0, loc_qkv_w,nullptr,nullptr, qkv,0,384,HW,0, FLAG);
  flat_attn8_k<<<dim3(36,8,B), blk512, 0, stream>>>(qkv,(long)384*HW,0, qkv,(long)384*HW,128,256, A,(long)C*HW, HW,HW,0.25f);
  convtile_k<<<dim3(36,2,B), blk, 0, stream>>>(A,(long)C*HW,C, nullptr,0,0, loc_proj_w,loc_proj_b,nullptr, L,0,C,HW,0, FLAG);
  pool4_k<<<144, blk, 0, stream>>>(N, xc);
  conv1x1_k<<<dim3(1,384,B), blk, 0, stream>>>(xc,(long)C*144,C, nullptr,0,0, glob_qkv_w,nullptr,nullptr, qkvc,0,384,144,0, FLAG);
  attn4_k<<<dim3(3,8,B), blk, 0, stream>>>(qkvc,(long)384*144,0, qkvc,(long)384*144,128,256, gatt,(long)C*144, 144,144,0.25f);
  conv1x1_k<<<dim3(1,128,B), blk, 0, stream>>>(gatt,(long)C*144,C, nullptr,0,0, glob_proj_w,glob_proj_b,nullptr, gproj,0,C,144,0, FLAG);
  ups_k<<<2304, blk, 0, stream>>>(gproj, A);                                          // A = upsampled global
  convtile_k<<<dim3(36,2,B), blk, 0, stream>>>(L,(long)C*HW,C, A,(long)C*HW,C, fuse_w1,fuse_b1,nullptr, N,0,C,HW,1, FLAG);  // N = gelu(fuse1)
  convtile_k<<<dim3(36,2,B), blk, 0, stream>>>(N,(long)C*HW,C, nullptr,0,0, fuse_w2,fuse_b2,P, P,0,C,HW,0, FLAG);           // P = x + f

  // ---- LatentMixer branch ----
  ln2dw_k<<<dim3(36,B), blk, 0, stream>>>(P, glat, blat, N, C, HW, FLAG);
  convtile_k<<<dim3(36,4,B), blk, 0, stream>>>(N,(long)C*HW,C, nullptr,0,0, kvx_w,nullptr,nullptr, kvx,0,256,HW,0, FLAG);
  convtile_k<<<dim3(36,2,B), blk, 0, stream>>>(N,(long)C*HW,C, nullptr,0,0, qx_w,nullptr,nullptr, A,0,C,HW,0, FLAG);        // A = qx
  cvt_k<<<8, blk, 0, stream>>>(latents, latf, 2048, FLAG);
  conv1x1_k<<<dim3(1,128,B), blk, 0, stream>>>(latf,0L,C, nullptr,0,0, qlat_w,nullptr,nullptr, qlat,0,C,16,0, FLAG);
  latpart_k<<<dim3(48,8,B), 64, 0, stream>>>(qlat, kvx, (long)256*HW, part, HW, 48);
  latcomb_k<<<1, blk, 0, stream>>>(part, latr, 48);
  conv1x1_k<<<dim3(1,256,B), blk, 0, stream>>>(latr,(long)C*16,C, nullptr,0,0, kvlat_w,nullptr,nullptr, kvlat,0,256,16,0, FLAG);
  attn4_k<<<dim3(36,8,B), blk, 0, stream>>>(A,(long)C*HW,0, kvlat,(long)256*16,0,128, N,(long)C*HW, HW,16,0.25f);           // N = xw
  convtile_k<<<dim3(36,2,B), blk, 0, stream>>>(N,(long)C*HW,C, nullptr,0,0, lat_proj_w,lat_proj_b,P, P,0,C,HW,0, FLAG);     // P = x2

  // ---- FFN branch ----
  ln2dw_k<<<dim3(36,B), blk, 0, stream>>>(P, g2, b2, N, C, HW, FLAG);
  convtile_k<<<dim3(36,8,B), blk, 0, stream>>>(N,(long)C*HW,C, nullptr,0,0, ffn_w1,ffn_b1,nullptr, ffh,0,512,HW,1, FLAG);
  convtile_k<<<dim3(36,2,B), blk, 0, stream>>>(ffh,(long)512*HW,512, nullptr,0,0, ffn_w2,ffn_b2,P, d_out,1,C,HW,0, FLAG);
}